// Round 15
// baseline (177.878 us; speedup 1.0000x reference)
//
#include <hip/hip_runtime.h>
#include <math.h>

// KME attention. B=2 S=1024 M=8 D=64 H=8 NF=64
// Round 15:
//  - k_flash: 320-thread blocks (4 PV waves + 1 dedicated producer wave).
//    Scores = Kh·Qh only (K-lo dropped, err ~2e-4); K hi staged by producer
//    wave alone (8KB/chunk dbuf, producer-local vmcnt); LDS = K16K+P8K.
//    One barrier+lgkmcnt per chunk; consumers never issue vmcnt.
//  - k_proj_rff: lo-plane outputs dropped (qrl/krl unread since R14).
//
// ws layout (bytes), 80 MiB total (qrl/krl/vtlo slots now unused):
//   qrh  @ 0MB   4MB  ushort [bh][s][128]          (natural)
//   krh  @ 8MB   4MB  swizzled-chunk layout [bh][ch=32][8192B]
//   vthi @16MB  16MB  [bh][ch=32][half=2][c=512][32B], inner=c*32+part2*16
//   ao   @48MB  32MB  f32 [b][s][m][512]

#define B_ 2
#define S_ 1024
#define H_ 8

typedef __attribute__((ext_vector_type(8))) short short8;
typedef __attribute__((ext_vector_type(16))) float f32x16;
union U4B8 { uint4 u; short8 v; };

#define SBAR() __builtin_amdgcn_s_barrier()
#define SCHED0() __builtin_amdgcn_sched_barrier(0)
#define MEMFENCE() asm volatile("" ::: "memory")

__device__ inline unsigned cvt_pk_bf16(float a, float b) {
  unsigned r;
  asm("v_cvt_pk_bf16_f32 %0, %1, %2" : "=v"(r) : "v"(a), "v"(b));
  return r;
}
__device__ inline void split8(const float* v, unsigned* hw, unsigned* lw) {
#pragma unroll
  for (int p = 0; p < 4; ++p) {
    const float a = v[2 * p], b = v[2 * p + 1];
    const unsigned h = cvt_pk_bf16(a, b);
    const float ra = a - __uint_as_float(h << 16);
    const float rb = b - __uint_as_float(h & 0xffff0000u);
    hw[p] = h;
    lw[p] = cvt_pk_bf16(ra, rb);
  }
}

// ---------------------------------------------------------------------------
// MFMA projection + RoPE + RFF encode; hi-plane outputs only.
// ---------------------------------------------------------------------------
__global__ __launch_bounds__(256, 2) void k_proj_rff(
    const float* __restrict__ q_atoms, const float* __restrict__ q_logw,
    const float* __restrict__ k_atoms, const float* __restrict__ k_logw,
    const float* __restrict__ Wq, const float* __restrict__ Wk,
    const float* __restrict__ freqb, const float* __restrict__ logbw,
    const float* __restrict__ cosT, const float* __restrict__ sinT,
    char* __restrict__ qoh, char* __restrict__ koh)
{
  const int sblk = blockIdx.x * 64;
  const int h = blockIdx.y, z = blockIdx.z;
  const int qk = z >> 1, b = z & 1;
  const float* atoms = qk ? k_atoms : q_atoms;
  const float* logw  = qk ? k_logw : q_logw;
  const float* W     = qk ? Wk : Wq;
  char* oh = qk ? koh : qoh;

  const int tid = threadIdx.x;
  const int w = tid >> 6, lane = tid & 63;
  const int lrow = lane & 31, lhi = lane >> 5;

  __shared__ float Cs[64 * 65];
  __shared__ float Sn[64 * 65];
  __shared__ float Wm[64 * 8];
  __shared__ __align__(16) char FT[2][4][2][1024];
  __shared__ __align__(16) char Ob[4][1024];

  for (int i = tid; i < 4096; i += 256) {
    const int sl = i >> 6, d = i & 63;
    Cs[sl * 65 + d] = cosT[(sblk + sl) * 64 + d];
    Sn[sl * 65 + d] = sinT[(sblk + sl) * 64 + d];
  }
  if (tid < 64) {
    const float* lw = logw + (size_t)(b * S_ + sblk + tid) * 8;
    float mx = lw[0];
    for (int m = 1; m < 8; ++m) mx = fmaxf(mx, lw[m]);
    float e[8], sum = 0.f;
    for (int m = 0; m < 8; ++m) { e[m] = __expf(lw[m] - mx); sum += e[m]; }
    const float inv = 1.0f / sum;
    for (int m = 0; m < 8; ++m) Wm[tid * 8 + m] = e[m] * inv;
  }
  const float fscale = __expf(-logbw[h]);
  {
    const int ftw = w & 1;
#pragma unroll
    for (int kk = 0; kk < 2; ++kk) {
      const int ks2 = (w >> 1) + kk * 2;
      float v[8];
#pragma unroll
      for (int j = 0; j < 8; ++j)
        v[j] = freqb[h * 4096 + (ks2 * 16 + lhi * 8 + j) * 64 + ftw * 32 + lrow] * fscale;
      unsigned hw[4], lw2[4];
      split8(v, hw, lw2);
      *(uint4*)&FT[ftw][ks2][0][lane * 16] = make_uint4(hw[0], hw[1], hw[2], hw[3]);
      *(uint4*)&FT[ftw][ks2][1][lane * 16] = make_uint4(lw2[0], lw2[1], lw2[2], lw2[3]);
    }
  }
  unsigned wAh[2][4][4], wAl[2][4][4];
#pragma unroll
  for (int wt = 0; wt < 2; ++wt)
#pragma unroll
    for (int ks = 0; ks < 4; ++ks) {
      const float* wp = W + h * 4096 + (wt * 32 + lrow) * 64 + ks * 16 + lhi * 8;
      float v[8];
      const float4 a = *(const float4*)wp;
      const float4 b2 = *(const float4*)(wp + 4);
      v[0] = a.x; v[1] = a.y; v[2] = a.z; v[3] = a.w;
      v[4] = b2.x; v[5] = b2.y; v[6] = b2.z; v[7] = b2.w;
      split8(v, wAh[wt][ks], wAl[wt][ks]);
    }
  __syncthreads();

  const int bh = b * H_ + h;
  char* obh = &Ob[w][0];

  for (int it = 0; it < 4; ++it) {
    const int t = w * 4 + it;
    const float* arow = atoms + ((size_t)(b * S_ + sblk) * 8 + t * 32 + lrow) * 64;
    unsigned aBh[4][4], aBl[4][4];
#pragma unroll
    for (int ks = 0; ks < 4; ++ks) {
      float v[8];
      const float4 a = *(const float4*)(arow + ks * 16 + lhi * 8);
      const float4 b2 = *(const float4*)(arow + ks * 16 + lhi * 8 + 4);
      v[0] = a.x; v[1] = a.y; v[2] = a.z; v[3] = a.w;
      v[4] = b2.x; v[5] = b2.y; v[6] = b2.z; v[7] = b2.w;
      split8(v, aBh[ks], aBl[ks]);
    }

    f32x16 y0, y1;
#pragma unroll
    for (int r = 0; r < 16; ++r) { y0[r] = 0.f; y1[r] = 0.f; }
    __builtin_amdgcn_s_setprio(1);
#pragma unroll
    for (int ks = 0; ks < 4; ++ks) {
      U4B8 a0h, a0l, a1h, a1l, bh2, bl2;
      a0h.u = make_uint4(wAh[0][ks][0], wAh[0][ks][1], wAh[0][ks][2], wAh[0][ks][3]);
      a0l.u = make_uint4(wAl[0][ks][0], wAl[0][ks][1], wAl[0][ks][2], wAl[0][ks][3]);
      a1h.u = make_uint4(wAh[1][ks][0], wAh[1][ks][1], wAh[1][ks][2], wAh[1][ks][3]);
      a1l.u = make_uint4(wAl[1][ks][0], wAl[1][ks][1], wAl[1][ks][2], wAl[1][ks][3]);
      bh2.u = make_uint4(aBh[ks][0], aBh[ks][1], aBh[ks][2], aBh[ks][3]);
      bl2.u = make_uint4(aBl[ks][0], aBl[ks][1], aBl[ks][2], aBl[ks][3]);
      y0 = __builtin_amdgcn_mfma_f32_32x32x16_bf16(a0h.v, bh2.v, y0, 0, 0, 0);
      y1 = __builtin_amdgcn_mfma_f32_32x32x16_bf16(a1h.v, bh2.v, y1, 0, 0, 0);
      y0 = __builtin_amdgcn_mfma_f32_32x32x16_bf16(a0l.v, bh2.v, y0, 0, 0, 0);
      y1 = __builtin_amdgcn_mfma_f32_32x32x16_bf16(a1l.v, bh2.v, y1, 0, 0, 0);
      y0 = __builtin_amdgcn_mfma_f32_32x32x16_bf16(a0h.v, bl2.v, y0, 0, 0, 0);
      y1 = __builtin_amdgcn_mfma_f32_32x32x16_bf16(a1h.v, bl2.v, y1, 0, 0, 0);
    }
    __builtin_amdgcn_s_setprio(0);

    const int sloc = t * 4 + (lrow >> 3);
    const int sld = sloc * 65;
    float yr0[16], yr1[16];
#pragma unroll
    for (int r = 0; r < 16; ++r) {
      const int dd = (r & 3) + 8 * (r >> 2) + 4 * lhi;
      const float c0 = Cs[sld + dd],      s0v = Sn[sld + dd];
      const float c1 = Cs[sld + dd + 32], s1v = Sn[sld + dd + 32];
      yr0[r] = y0[r] * c0 - y1[r] * s0v;
      yr1[r] = y1[r] * c1 + y0[r] * s1v;
    }

    unsigned Bh[4][4], Bl[4][4];
    {
      const float* src[2] = { yr0, yr1 };
#pragma unroll
      for (int st = 0; st < 2; ++st) {
#pragma unroll
        for (int half = 0; half < 2; ++half) {
          const int ks2 = st * 2 + half;
          const float* q = src[st] + half * 8;
          unsigned ph[4], pl[4];
          split8(q, ph, pl);
          {
            const unsigned t0 = lhi ? ph[0] : ph[2];
            const unsigned r0 = (unsigned)__shfl_xor((int)t0, 32);
            const unsigned t1 = lhi ? ph[1] : ph[3];
            const unsigned r1 = (unsigned)__shfl_xor((int)t1, 32);
            Bh[ks2][0] = lhi ? r0 : ph[0];
            Bh[ks2][1] = lhi ? r1 : ph[1];
            Bh[ks2][2] = lhi ? ph[2] : r0;
            Bh[ks2][3] = lhi ? ph[3] : r1;
          }
          {
            const unsigned t0 = lhi ? pl[0] : pl[2];
            const unsigned r0 = (unsigned)__shfl_xor((int)t0, 32);
            const unsigned t1 = lhi ? pl[1] : pl[3];
            const unsigned r1 = (unsigned)__shfl_xor((int)t1, 32);
            Bl[ks2][0] = lhi ? r0 : pl[0];
            Bl[ks2][1] = lhi ? r1 : pl[1];
            Bl[ks2][2] = lhi ? pl[2] : r0;
            Bl[ks2][3] = lhi ? pl[3] : r1;
          }
        }
      }
    }

    f32x16 d0, d1;
#pragma unroll
    for (int r = 0; r < 16; ++r) { d0[r] = 0.f; d1[r] = 0.f; }
    __builtin_amdgcn_s_setprio(1);
#pragma unroll
    for (int ks2 = 0; ks2 < 4; ++ks2) {
      U4B8 a0h, a0l, a1h, a1l, bh2, bl2;
      a0h.u = *(const uint4*)&FT[0][ks2][0][lane * 16];
      a0l.u = *(const uint4*)&FT[0][ks2][1][lane * 16];
      a1h.u = *(const uint4*)&FT[1][ks2][0][lane * 16];
      a1l.u = *(const uint4*)&FT[1][ks2][1][lane * 16];
      bh2.u = make_uint4(Bh[ks2][0], Bh[ks2][1], Bh[ks2][2], Bh[ks2][3]);
      bl2.u = make_uint4(Bl[ks2][0], Bl[ks2][1], Bl[ks2][2], Bl[ks2][3]);
      d0 = __builtin_amdgcn_mfma_f32_32x32x16_bf16(a0h.v, bh2.v, d0, 0, 0, 0);
      d1 = __builtin_amdgcn_mfma_f32_32x32x16_bf16(a1h.v, bh2.v, d1, 0, 0, 0);
      d0 = __builtin_amdgcn_mfma_f32_32x32x16_bf16(a0l.v, bh2.v, d0, 0, 0, 0);
      d1 = __builtin_amdgcn_mfma_f32_32x32x16_bf16(a1l.v, bh2.v, d1, 0, 0, 0);
      d0 = __builtin_amdgcn_mfma_f32_32x32x16_bf16(a0h.v, bl2.v, d0, 0, 0, 0);
      d1 = __builtin_amdgcn_mfma_f32_32x32x16_bf16(a1h.v, bl2.v, d1, 0, 0, 0);
    }
    __builtin_amdgcn_s_setprio(0);

    const float wt = Wm[sloc * 8 + (lrow & 7)];
    float oc[32], os[32];
#pragma unroll
    for (int r = 0; r < 32; ++r) {
      const float pr = (r < 16) ? d0[r] : d1[r - 16];
      float sv, cv;
      __sincosf(pr, &sv, &cv);
      oc[r] = wt * cv;
      os[r] = wt * sv;
    }
#pragma unroll
    for (int r = 0; r < 32; ++r) {
      oc[r] += __shfl_xor(oc[r], 1); os[r] += __shfl_xor(os[r], 1);
      oc[r] += __shfl_xor(oc[r], 2); os[r] += __shfl_xor(os[r], 2);
      oc[r] += __shfl_xor(oc[r], 4); os[r] += __shfl_xor(os[r], 4);
    }

    const int m = lrow & 7, srel = lrow >> 3;
#pragma unroll
    for (int rr2 = 0; rr2 < 4; ++rr2) {
      const int r = m * 4 + rr2;
      const int f = (r & 3) + 8 * ((r >> 2) & 3) + 4 * lhi + ((r >> 4) << 5);
      *(unsigned short*)(obh + srel * 256 + f * 2) =
          (unsigned short)cvt_pk_bf16(oc[r] * 0.125f, 0.f);
      *(unsigned short*)(obh + srel * 256 + 128 + f * 2) =
          (unsigned short)cvt_pk_bf16(os[r] * 0.125f, 0.f);
    }
    const uint4 vh = *(const uint4*)(obh + lane * 16);
    const int srow = sblk + t * 4 + (lane >> 4);
    if (!qk) {
      const size_t off = ((size_t)bh * S_ + srow) * 256 + (lane & 15) * 16;
      *(uint4*)(oh + off) = vh;
    } else {
      const int klr = srow & 31, ch = srow >> 5;
      const unsigned inner = (unsigned)(((klr << 8) + (lane & 15) * 16) ^ ((klr & 7) << 4));
      const size_t off = (size_t)bh * 262144 + (size_t)ch * 8192 + inner;
      *(uint4*)(oh + off) = vh;
    }
  }
}

// ---------------------------------------------------------------------------
// V projection, MFMA; hi plane only (unchanged from R14).
// ---------------------------------------------------------------------------
__global__ __launch_bounds__(256) void k_proj_v(
    const float* __restrict__ atoms, const float* __restrict__ W,
    char* __restrict__ vthi)
{
  const int sblk = blockIdx.x * 64;
  const int h = blockIdx.y, b = blockIdx.z;
  const int tid = threadIdx.x;
  const int w = tid >> 6, lane = tid & 63;
  const int lrow = lane & 31, lhi = lane >> 5;

  __shared__ __align__(16) float T[4][8 * 520];

  unsigned wAh[2][4][4], wAl[2][4][4];
#pragma unroll
  for (int wt = 0; wt < 2; ++wt)
#pragma unroll
    for (int ks = 0; ks < 4; ++ks) {
      const float* wp = W + h * 4096 + (wt * 32 + lrow) * 64 + ks * 16 + lhi * 8;
      float v[8];
      const float4 a = *(const float4*)wp;
      const float4 b2 = *(const float4*)(wp + 4);
      v[0] = a.x; v[1] = a.y; v[2] = a.z; v[3] = a.w;
      v[4] = b2.x; v[5] = b2.y; v[6] = b2.z; v[7] = b2.w;
      split8(v, wAh[wt][ks], wAl[wt][ks]);
    }

  const int bh = b * H_ + h;
  float* Tw = &T[w][0];

  for (int p = 0; p < 2; ++p) {
#pragma unroll
    for (int half8 = 0; half8 < 2; ++half8) {
      const int t = w * 4 + p * 2 + half8;
      const float* arow = atoms + ((size_t)(b * S_ + sblk) * 8 + t * 32 + lrow) * 64;
      unsigned aBh[4][4], aBl[4][4];
#pragma unroll
      for (int ks = 0; ks < 4; ++ks) {
        float v[8];
        const float4 a = *(const float4*)(arow + ks * 16 + lhi * 8);
        const float4 b2 = *(const float4*)(arow + ks * 16 + lhi * 8 + 4);
        v[0] = a.x; v[1] = a.y; v[2] = a.z; v[3] = a.w;
        v[4] = b2.x; v[5] = b2.y; v[6] = b2.z; v[7] = b2.w;
        split8(v, aBh[ks], aBl[ks]);
      }

      f32x16 y0, y1;
#pragma unroll
      for (int r = 0; r < 16; ++r) { y0[r] = 0.f; y1[r] = 0.f; }
      __builtin_amdgcn_s_setprio(1);
#pragma unroll
      for (int ks = 0; ks < 4; ++ks) {
        U4B8 a0h, a0l, a1h, a1l, bh2, bl2;
        a0h.u = make_uint4(wAh[0][ks][0], wAh[0][ks][1], wAh[0][ks][2], wAh[0][ks][3]);
        a0l.u = make_uint4(wAl[0][ks][0], wAl[0][ks][1], wAl[0][ks][2], wAl[0][ks][3]);
        a1h.u = make_uint4(wAh[1][ks][0], wAh[1][ks][1], wAh[1][ks][2], wAh[1][ks][3]);
        a1l.u = make_uint4(wAl[1][ks][0], wAl[1][ks][1], wAl[1][ks][2], wAl[1][ks][3]);
        bh2.u = make_uint4(aBh[ks][0], aBh[ks][1], aBh[ks][2], aBh[ks][3]);
        bl2.u = make_uint4(aBl[ks][0], aBl[ks][1], aBl[ks][2], aBl[ks][3]);
        y0 = __builtin_amdgcn_mfma_f32_32x32x16_bf16(a0h.v, bh2.v, y0, 0, 0, 0);
        y1 = __builtin_amdgcn_mfma_f32_32x32x16_bf16(a1h.v, bh2.v, y1, 0, 0, 0);
        y0 = __builtin_amdgcn_mfma_f32_32x32x16_bf16(a0l.v, bh2.v, y0, 0, 0, 0);
        y1 = __builtin_amdgcn_mfma_f32_32x32x16_bf16(a1l.v, bh2.v, y1, 0, 0, 0);
        y0 = __builtin_amdgcn_mfma_f32_32x32x16_bf16(a0h.v, bl2.v, y0, 0, 0, 0);
        y1 = __builtin_amdgcn_mfma_f32_32x32x16_bf16(a1h.v, bl2.v, y1, 0, 0, 0);
      }
      __builtin_amdgcn_s_setprio(0);

      const int s_in = half8 * 4 + (lrow >> 3);
      const int m = lrow & 7;
#pragma unroll
      for (int r = 0; r < 16; ++r) {
        const int dd = (r & 3) + 8 * (r >> 2) + 4 * lhi;
        Tw[s_in * 520 + m * 64 + dd] = y0[r];
        Tw[s_in * 520 + m * 64 + dd + 32] = y1[r];
      }
    }
    const int s0 = sblk + w * 16 + p * 8;
    const int ch = s0 >> 5, half = (s0 >> 4) & 1, part2 = (s0 >> 3) & 1;
    const size_t base = (size_t)bh * 1048576 + (size_t)ch * 32768 + half * 16384;
#pragma unroll
    for (int j = 0; j < 8; ++j) {
      const int c = j * 64 + lane;
      float v[8];
#pragma unroll
      for (int s = 0; s < 8; ++s) v[s] = Tw[s * 520 + c];
      unsigned hw[4];
#pragma unroll
      for (int pq = 0; pq < 4; ++pq)
        hw[pq] = cvt_pk_bf16(v[2 * pq], v[2 * pq + 1]);
      const unsigned inner = (unsigned)(c * 32 + part2 * 16);
      *(uint4*)(vthi + base + inner) = make_uint4(hw[0], hw[1], hw[2], hw[3]);
    }
  }
}

// ---------------------------------------------------------------------------
// MFMA flash attention. 512 blocks x 320 threads: 4 PV waves (128 cols each)
// + producer wave w4 (scores = Kh·Qh, P=exp(s), publish). K hi staged by the
// producer wave only (8KB/chunk, dbuf, producer-local vmcnt, 2 chunks ahead).
// One barrier + lgkmcnt(0) per chunk. V hi in consumer regs (dbuf).
// ---------------------------------------------------------------------------
__global__ __launch_bounds__(320, 2) void k_flash(
    const unsigned short* __restrict__ qrh,
    const char* __restrict__ krh,
    const char* __restrict__ vthi,
    float* __restrict__ ao)
{
  __shared__ __align__(16) char Ksm[16384];     // K hi dbuf [2][8192]
  __shared__ __align__(16) char PAsm[2][4096];
  __shared__ float Slinv[32];

  const int tid = threadIdx.x;
  const int w = tid >> 6, lane = tid & 63;
  const int lrow = lane & 31, lhi = lane >> 5;
  const bool prod = (w == 4);

  const int phys = blockIdx.x;
  const int x = phys & 7, j = phys >> 3;        // x = XCD
  const int bh = (x << 1) | (j >> 5);
  const int qb = j & 31;
  const int b = bh >> 3, h = bh & 7;
  const int qbase = qb * 32;

  uint4 qfh[8];
  if (prod) {
    const size_t rowb = ((size_t)bh * S_ + qbase + lrow) * 128;
#pragma unroll
    for (int fs = 0; fs < 8; ++fs)
      qfh[fs] = *(const uint4*)(qrh + rowb + fs * 16 + lhi * 8);
  }

  const char* vh_c = vthi + (size_t)bh * 1048576;
  const char* kh_c = krh + (size_t)bh * 262144;

  // producer-only K DMA: chunk -> Ksm[ch&1]
  auto issue_k = [&](int ch) {
    char* dst = Ksm + (ch & 1) * 8192;
    const size_t g = (size_t)ch * 8192;
#pragma unroll
    for (int i = 0; i < 8; ++i)
      __builtin_amdgcn_global_load_lds(kh_c + g + i * 1024 + lane * 16, dst + i * 1024, 16, 0, 0);
  };

  const unsigned vbase = (unsigned)((w * 128 + lrow) * 32 + lhi * 16);
  uint4 vAh[4], vBh[4];
  auto load_vA = [&](int ch) {
    const size_t g = (size_t)ch * 32768 + vbase;
#pragma unroll
    for (int cf = 0; cf < 4; ++cf)
      vAh[cf] = *(const uint4*)(vh_c + g + cf * 1024);
  };
  auto load_vB = [&](int ch) {
    const size_t g = (size_t)ch * 32768 + 16384 + vbase;
#pragma unroll
    for (int cf = 0; cf < 4; ++cf)
      vBh[cf] = *(const uint4*)(vh_c + g + cf * 1024);
  };

  f32x16 acc[4];
#pragma unroll
  for (int i = 0; i < 4; ++i)
#pragma unroll
    for (int r = 0; r < 16; ++r) acc[i][r] = 0.f;
  float l_run = 0.f;

  // Producer: scores(chp) = Kh·Qh from Ksm[chp&1]; P = exp(s); publish.
  auto produce = [&](int chp) {
    const char* kb = Ksm + (chp & 1) * 8192;
    f32x16 s0, s1;
#pragma unroll
    for (int r = 0; r < 16; ++r) { s0[r] = 0.f; s1[r] = 0.f; }
    __builtin_amdgcn_s_setprio(1);
#pragma unroll
    for (int fs = 0; fs < 8; ++fs) {
      const unsigned kaddr = (unsigned)((lrow * 256 + fs * 32 + lhi * 16) ^ ((lrow & 7) << 4));
      U4B8 khf, qh;
      khf.u = *(const uint4*)(kb + kaddr);
      qh.u = qfh[fs];
      if (fs & 1) s1 = __builtin_amdgcn_mfma_f32_32x32x16_bf16(khf.v, qh.v, s1, 0, 0, 0);
      else        s0 = __builtin_amdgcn_mfma_f32_32x32x16_bf16(khf.v, qh.v, s0, 0, 0, 0);
    }
    __builtin_amdgcn_s_setprio(0);
    float p[16];
#pragma unroll
    for (int r = 0; r < 16; ++r) p[r] = __expf(s0[r] + s1[r]);
    float rs = 0.f;
#pragma unroll
    for (int r = 0; r < 16; ++r) rs += p[r];
    rs += __shfl_xor(rs, 32);
    l_run += rs;

    unsigned wh[8], wl[8];
#pragma unroll
    for (int i = 0; i < 8; ++i) {
      const float a = p[2 * i], c2 = p[2 * i + 1];
      const unsigned hword = cvt_pk_bf16(a, c2);
      const float ra = a - __uint_as_float(hword << 16);
      const float rc = c2 - __uint_as_float(hword & 0xffff0000u);
      wh[i] = hword;
      wl[i] = cvt_pk_bf16(ra, rc);
    }
    auto mix = [&](unsigned &lo_w, unsigned &hi_w) {
      const unsigned t = lhi ? lo_w : hi_w;
      const unsigned r = (unsigned)__shfl_xor((int)t, 32);
      lo_w = lhi ? r : lo_w;
      hi_w = lhi ? hi_w : r;
    };
    mix(wh[0], wh[2]); mix(wh[1], wh[3]); mix(wh[4], wh[6]); mix(wh[5], wh[7]);
    mix(wl[0], wl[2]); mix(wl[1], wl[3]); mix(wl[4], wl[6]); mix(wl[5], wl[7]);

    char* pb = &PAsm[chp & 1][0];
    *(uint4*)(pb + 0 * 1024 + lane * 16) = make_uint4(wh[0], wh[1], wh[2], wh[3]);
    *(uint4*)(pb + 1 * 1024 + lane * 16) = make_uint4(wh[4], wh[5], wh[6], wh[7]);
    *(uint4*)(pb + 2 * 1024 + lane * 16) = make_uint4(wl[0], wl[1], wl[2], wl[3]);
    *(uint4*)(pb + 3 * 1024 + lane * 16) = make_uint4(wl[4], wl[5], wl[6], wl[7]);
  };

  // ---- prologue ----
  if (prod) {
    issue_k(0);
    issue_k(1);
    asm volatile("s_waitcnt vmcnt(8)" ::: "memory");   // K(0) landed
    produce(0);
  } else {
    load_vA(0);
    load_vB(0);
  }
  asm volatile("s_waitcnt lgkmcnt(0)" ::: "memory");
  SCHED0(); SBAR(); MEMFENCE();

  for (int ch = 0; ch < 32; ++ch) {
    if (prod) {
      if (ch < 30) { SCHED0(); issue_k(ch + 2); SCHED0(); }
      if (ch < 31) {
        if (ch < 30) { asm volatile("s_waitcnt vmcnt(8)" ::: "memory"); }
        else         { asm volatile("s_waitcnt vmcnt(0)" ::: "memory"); }
        produce(ch + 1);
      }
    } else {
      U4B8 pah0, pah1, pal0, pal1;
      {
        const char* pb = &PAsm[ch & 1][0];
        pah0.u = *(const uint4*)(pb + 0 * 1024 + lane * 16);
        pah1.u = *(const uint4*)(pb + 1 * 1024 + lane * 16);
        pal0.u = *(const uint4*)(pb + 2 * 1024 + lane * 16);
        pal1.u = *(const uint4*)(pb + 3 * 1024 + lane * 16);
      }
      __builtin_amdgcn_s_setprio(1);
#pragma unroll
      for (int cf = 0; cf < 4; ++cf) {
        U4B8 vh;
        vh.u = vAh[cf];
        acc[cf] = __builtin_amdgcn_mfma_f32_32x32x16_bf16(pah0.v, vh.v, acc[cf], 0, 0, 0);
        acc[cf] = __builtin_amdgcn_mfma_f32_32x32x16_bf16(pal0.v, vh.v, acc[cf], 0, 0, 0);
      }
      __builtin_amdgcn_s_setprio(0);
      if (ch < 31) load_vA(ch + 1);
      __builtin_amdgcn_s_setprio(1);
#pragma unroll
      for (int cf = 0; cf < 4; ++cf) {
        U4B8 vh;
        vh.u = vBh[cf];
        acc[cf] = __builtin_amdgcn_mfma_f32_32x32x16_bf16(pah1.v, vh.v, acc[cf], 0, 0, 0);
        acc[cf] = __builtin_amdgcn_mfma_f32_32x32x16_bf16(pal1.v, vh.v, acc[cf], 0, 0, 0);
      }
      __builtin_amdgcn_s_setprio(0);
      if (ch < 31) load_vB(ch + 1);
    }
    asm volatile("s_waitcnt lgkmcnt(0)" ::: "memory");
    SCHED0(); SBAR(); MEMFENCE();
  }

  // ---- epilogue ----
  if (prod && lane < 32) Slinv[lrow] = 1.0f / l_run;
  asm volatile("s_waitcnt lgkmcnt(0)" ::: "memory");
  SBAR(); MEMFENCE();
  if (!prod) {
    float lr[16];
#pragma unroll
    for (int r = 0; r < 16; ++r)
      lr[r] = Slinv[(r & 3) + 8 * (r >> 2) + 4 * lhi];
#pragma unroll
    for (int cf = 0; cf < 4; ++cf) {
      const int c = w * 128 + cf * 32 + lrow;
      const int m = c >> 6, dd = c & 63;
#pragma unroll
      for (int r = 0; r < 16; ++r) {
        const int qr = (r & 3) + 8 * (r >> 2) + 4 * lhi;
        const int srow = qbase + qr;
        const size_t off = (((size_t)(b * S_ + srow)) * 8 + m) * 512 + h * 64 + dd;
        ao[off] = acc[cf][r] * lr[r];
      }
    }
  }
}

// ---------------------------------------------------------------------------
// k_out MFMA (unchanged from R10).
// ---------------------------------------------------------------------------
__global__ __launch_bounds__(256) void k_out(
    const float* __restrict__ ao, const float* __restrict__ Wo,
    const float* __restrict__ Ww, const float* __restrict__ qlw,
    float* __restrict__ out)
{
  const int tid = threadIdx.x;
  const int w = tid >> 6, lane = tid & 63;
  const int lrow = lane & 31, lhi = lane >> 5;
  const int Rblk = blockIdx.x * 128;

  __shared__ __align__(16) char WoF[4][2][2][1024];
  __shared__ __align__(16) float Os[128 * 68];

  f32x16 acc[2];
#pragma unroll
  for (int i = 0; i < 2; ++i)
#pragma unroll
    for (int r = 0; r < 16; ++r) acc[i][r] = 0.f;

  const float* brow = ao + (size_t)(Rblk + w * 32 + lrow) * 512;

  for (int chunk = 0; chunk < 8; ++chunk) {
    __syncthreads();
#pragma unroll
    for (int dt = 0; dt < 2; ++dt) {
      const float* wp = Wo + (size_t)(dt * 32 + lrow) * 512 + (chunk * 4 + w) * 16 + lhi * 8;
      float v[8];
      const float4 a = *(const float4*)wp;
      const float4 b2 = *(const float4*)(wp + 4);
      v[0] = a.x; v[1] = a.y; v[2] = a.z; v[3] = a.w;
      v[4] = b2.x; v[5] = b2.y; v[6] = b2.z; v[7] = b2.w;
      unsigned hw[4], lw2[4];
      split8(v, hw, lw2);
      *(uint4*)&WoF[w][dt][0][lane * 16] = make_uint4(hw[0], hw[1], hw[2], hw[3]);
      *(uint4*)&WoF[w][dt][1][lane * 16] = make_uint4(lw2[0], lw2[1], lw2[2], lw2[3]);
    }
    __syncthreads();

#pragma unroll
    for (int kl = 0; kl < 4; ++kl) {
      float v[8];
      const float4 a = *(const float4*)(brow + (chunk * 4 + kl) * 16 + lhi * 8);
      const float4 b2 = *(const float4*)(brow + (chunk * 4 + kl) * 16 + lhi * 8 + 4);
      v[0] = a.x; v[1] = a.y; v[2] = a.z; v[3] = a.w;
      v[4] = b2.x; v[5] = b2.y; v[6] = b2.z; v[7] = b2.w;
      unsigned bhw[4], blw[4];
      split8(v, bhw, blw);
      U4B8 bh2, bl2;
      bh2.u = make_uint4(bhw[0], bhw[1], bhw[2], bhw[3]);
      bl2.u = make_uint4(blw[0], blw[1], blw[2], blw[3]);
      __builtin_amdgcn_s_setprio(1);
#pragma unroll
      for (int dt = 0; dt < 2; ++dt) {
        U4B8 ah, al;
        ah.u = *(const uint4*)&WoF[kl][dt][0][lane * 16];
        al.u = *(const uint4*)&WoF[kl][dt][1][lane * 16];
        acc[dt] = __builtin_amdgcn_mfma_f32_32x32x16_bf16(ah.v, bh2.v, acc[dt], 0, 0, 0);
        acc[dt] = __builtin_amdgcn_mfma_f32_32x32x16_bf16(al.v, bh2.v, acc[dt], 0, 0, 0);
        acc[dt] = __builtin_amdgcn_mfma_f32_32x32x16_bf16(ah.v, bl2.v, acc[dt], 0, 0, 0);
      }
      __builtin_amdgcn_s_setprio(0);
    }
  }

  __syncthreads();
#pragma unroll
  for (int dt = 0; dt < 2; ++dt)
#pragma unroll
    for (int r = 0; r < 16; ++r) {
      const int d = dt * 32 + (r & 3) + 8 * (r >> 2) + 4 * lhi;
      Os[(w * 32 + lrow) * 68 + d] = acc[dt][r];
    }
  __syncthreads();

#pragma unroll
  for (int jj = 0; jj < 8; ++jj) {
    const int i = tid + 256 * jj;
    const int r = i >> 4, c4 = (i & 15) * 4;
    const float4 v = *(const float4*)&Os[r * 68 + c4];
    *(float4*)&out[(size_t)(Rblk + r) * 64 + c4] = v;
  }

#pragma unroll
  for (int gi = 0; gi < 4; ++gi) {
    const int g = w * 4 + gi;
    float mean = 0.f;
#pragma unroll
    for (int m = 0; m < 8; ++m) mean += Os[(g * 8 + m) * 68 + lane];
    mean *= 0.125f;
    float dsel = 0.f;
#pragma unroll
    for (int mw = 0; mw < 8; ++mw) {
      float part = mean * Ww[mw * 64 + lane];
      part += __shfl_xor(part, 1);
      part += __shfl_xor(part, 2);
      part += __shfl_xor(part, 4);
      part += __shfl_xor(part, 8);
      part += __shfl_xor(part, 16);
      part += __shfl_xor(part, 32);
      if (lane == mw) dsel = part;
    }
    if (lane < 8) {
      const int idx = Rblk + g * 8 + lane;
      out[1048576 + idx] = qlw[idx] + dsel;
    }
  }
}

// ---------------------------------------------------------------------------
extern "C" void kernel_launch(void* const* d_in, const int* in_sizes, int n_in,
                              void* d_out, int out_size, void* d_ws, size_t ws_size,
                              hipStream_t stream)
{
  const float* q_atoms = (const float*)d_in[0];
  const float* q_logw  = (const float*)d_in[1];
  const float* k_atoms = (const float*)d_in[2];
  const float* k_logw  = (const float*)d_in[3];
  const float* v_atoms = (const float*)d_in[4];
  const float* cosT  = (const float*)d_in[6];
  const float* sinT  = (const float*)d_in[7];
  const float* Wq    = (const float*)d_in[8];
  const float* Wk    = (const float*)d_in[9];
  const float* Wv    = (const float*)d_in[10];
  const float* Wo    = (const float*)d_in[11];
  const float* Ww    = (const float*)d_in[12];
  const float* logbw = (const float*)d_in[13];
  const float* rffb  = (const float*)d_in[14];
  float* out = (float*)d_out;

  char* wsb = (char*)d_ws;
  char* qrh = wsb;
  char* krh = wsb + (8u << 20);
  char* vthi = wsb + (16u << 20);
  float* ao = (float*)(wsb + (48u << 20));

  const dim3 blk(256);
  k_proj_rff<<<dim3(16, 8, 4), blk, 0, stream>>>(q_atoms, q_logw, k_atoms, k_logw,
                                                 Wq, Wk, rffb, logbw, cosT, sinT,
                                                 qrh, krh);
  k_proj_v  <<<dim3(16, 8, 2), blk, 0, stream>>>(v_atoms, Wv, vthi);
  k_flash   <<<dim3(512), dim3(320), 0, stream>>>((const unsigned short*)qrh,
                                                  krh, vthi, ao);
  k_out     <<<dim3(128), blk, 0, stream>>>(ao, Wo, Ww, q_logw, out);
}

// Round 16
// 136.382 us; speedup vs baseline: 1.3043x; 1.3043x over previous
//
#include <hip/hip_runtime.h>
#include <math.h>

// KME attention. B=2 S=1024 M=8 D=64 H=8 NF=64
// Round 16 = R14 structure + R15 numerics:
//  - k_flash: 512x256, producer wave pw (also PVs), all waves stage K,
//    P-pipeline 1 chunk ahead (R14's 76us schedule); K HI-PLANE ONLY
//    (scores = Kh·Qh, 8 MFMAs; K LDS 16KB; vmcnt 10/8/8).
//  - proj_rff / proj_v: hi-only outputs (validated R15). k_out unchanged.
//
// ws layout (bytes), 80 MiB total:
//   qrh  @ 0MB   4MB  ushort [bh][s][128]          (natural)
//   krh  @ 8MB   4MB  swizzled-chunk layout [bh][ch=32][8192B]
//   vthi @16MB  16MB  [bh][ch=32][half=2][c=512][32B], inner=c*32+part2*16
//   ao   @48MB  32MB  f32 [b][s][m][512]

#define B_ 2
#define S_ 1024
#define H_ 8

typedef __attribute__((ext_vector_type(8))) short short8;
typedef __attribute__((ext_vector_type(16))) float f32x16;
union U4B8 { uint4 u; short8 v; };

#define SBAR() __builtin_amdgcn_s_barrier()
#define SCHED0() __builtin_amdgcn_sched_barrier(0)
#define MEMFENCE() asm volatile("" ::: "memory")

__device__ inline unsigned cvt_pk_bf16(float a, float b) {
  unsigned r;
  asm("v_cvt_pk_bf16_f32 %0, %1, %2" : "=v"(r) : "v"(a), "v"(b));
  return r;
}
__device__ inline void split8(const float* v, unsigned* hw, unsigned* lw) {
#pragma unroll
  for (int p = 0; p < 4; ++p) {
    const float a = v[2 * p], b = v[2 * p + 1];
    const unsigned h = cvt_pk_bf16(a, b);
    const float ra = a - __uint_as_float(h << 16);
    const float rb = b - __uint_as_float(h & 0xffff0000u);
    hw[p] = h;
    lw[p] = cvt_pk_bf16(ra, rb);
  }
}

// ---------------------------------------------------------------------------
// MFMA projection + RoPE + RFF encode; hi-plane outputs only (R15).
// ---------------------------------------------------------------------------
__global__ __launch_bounds__(256, 2) void k_proj_rff(
    const float* __restrict__ q_atoms, const float* __restrict__ q_logw,
    const float* __restrict__ k_atoms, const float* __restrict__ k_logw,
    const float* __restrict__ Wq, const float* __restrict__ Wk,
    const float* __restrict__ freqb, const float* __restrict__ logbw,
    const float* __restrict__ cosT, const float* __restrict__ sinT,
    char* __restrict__ qoh, char* __restrict__ koh)
{
  const int sblk = blockIdx.x * 64;
  const int h = blockIdx.y, z = blockIdx.z;
  const int qk = z >> 1, b = z & 1;
  const float* atoms = qk ? k_atoms : q_atoms;
  const float* logw  = qk ? k_logw : q_logw;
  const float* W     = qk ? Wk : Wq;
  char* oh = qk ? koh : qoh;

  const int tid = threadIdx.x;
  const int w = tid >> 6, lane = tid & 63;
  const int lrow = lane & 31, lhi = lane >> 5;

  __shared__ float Cs[64 * 65];
  __shared__ float Sn[64 * 65];
  __shared__ float Wm[64 * 8];
  __shared__ __align__(16) char FT[2][4][2][1024];
  __shared__ __align__(16) char Ob[4][1024];

  for (int i = tid; i < 4096; i += 256) {
    const int sl = i >> 6, d = i & 63;
    Cs[sl * 65 + d] = cosT[(sblk + sl) * 64 + d];
    Sn[sl * 65 + d] = sinT[(sblk + sl) * 64 + d];
  }
  if (tid < 64) {
    const float* lw = logw + (size_t)(b * S_ + sblk + tid) * 8;
    float mx = lw[0];
    for (int m = 1; m < 8; ++m) mx = fmaxf(mx, lw[m]);
    float e[8], sum = 0.f;
    for (int m = 0; m < 8; ++m) { e[m] = __expf(lw[m] - mx); sum += e[m]; }
    const float inv = 1.0f / sum;
    for (int m = 0; m < 8; ++m) Wm[tid * 8 + m] = e[m] * inv;
  }
  const float fscale = __expf(-logbw[h]);
  {
    const int ftw = w & 1;
#pragma unroll
    for (int kk = 0; kk < 2; ++kk) {
      const int ks2 = (w >> 1) + kk * 2;
      float v[8];
#pragma unroll
      for (int j = 0; j < 8; ++j)
        v[j] = freqb[h * 4096 + (ks2 * 16 + lhi * 8 + j) * 64 + ftw * 32 + lrow] * fscale;
      unsigned hw[4], lw2[4];
      split8(v, hw, lw2);
      *(uint4*)&FT[ftw][ks2][0][lane * 16] = make_uint4(hw[0], hw[1], hw[2], hw[3]);
      *(uint4*)&FT[ftw][ks2][1][lane * 16] = make_uint4(lw2[0], lw2[1], lw2[2], lw2[3]);
    }
  }
  unsigned wAh[2][4][4], wAl[2][4][4];
#pragma unroll
  for (int wt = 0; wt < 2; ++wt)
#pragma unroll
    for (int ks = 0; ks < 4; ++ks) {
      const float* wp = W + h * 4096 + (wt * 32 + lrow) * 64 + ks * 16 + lhi * 8;
      float v[8];
      const float4 a = *(const float4*)wp;
      const float4 b2 = *(const float4*)(wp + 4);
      v[0] = a.x; v[1] = a.y; v[2] = a.z; v[3] = a.w;
      v[4] = b2.x; v[5] = b2.y; v[6] = b2.z; v[7] = b2.w;
      split8(v, wAh[wt][ks], wAl[wt][ks]);
    }
  __syncthreads();

  const int bh = b * H_ + h;
  char* obh = &Ob[w][0];

  for (int it = 0; it < 4; ++it) {
    const int t = w * 4 + it;
    const float* arow = atoms + ((size_t)(b * S_ + sblk) * 8 + t * 32 + lrow) * 64;
    unsigned aBh[4][4], aBl[4][4];
#pragma unroll
    for (int ks = 0; ks < 4; ++ks) {
      float v[8];
      const float4 a = *(const float4*)(arow + ks * 16 + lhi * 8);
      const float4 b2 = *(const float4*)(arow + ks * 16 + lhi * 8 + 4);
      v[0] = a.x; v[1] = a.y; v[2] = a.z; v[3] = a.w;
      v[4] = b2.x; v[5] = b2.y; v[6] = b2.z; v[7] = b2.w;
      split8(v, aBh[ks], aBl[ks]);
    }

    f32x16 y0, y1;
#pragma unroll
    for (int r = 0; r < 16; ++r) { y0[r] = 0.f; y1[r] = 0.f; }
    __builtin_amdgcn_s_setprio(1);
#pragma unroll
    for (int ks = 0; ks < 4; ++ks) {
      U4B8 a0h, a0l, a1h, a1l, bh2, bl2;
      a0h.u = make_uint4(wAh[0][ks][0], wAh[0][ks][1], wAh[0][ks][2], wAh[0][ks][3]);
      a0l.u = make_uint4(wAl[0][ks][0], wAl[0][ks][1], wAl[0][ks][2], wAl[0][ks][3]);
      a1h.u = make_uint4(wAh[1][ks][0], wAh[1][ks][1], wAh[1][ks][2], wAh[1][ks][3]);
      a1l.u = make_uint4(wAl[1][ks][0], wAl[1][ks][1], wAl[1][ks][2], wAl[1][ks][3]);
      bh2.u = make_uint4(aBh[ks][0], aBh[ks][1], aBh[ks][2], aBh[ks][3]);
      bl2.u = make_uint4(aBl[ks][0], aBl[ks][1], aBl[ks][2], aBl[ks][3]);
      y0 = __builtin_amdgcn_mfma_f32_32x32x16_bf16(a0h.v, bh2.v, y0, 0, 0, 0);
      y1 = __builtin_amdgcn_mfma_f32_32x32x16_bf16(a1h.v, bh2.v, y1, 0, 0, 0);
      y0 = __builtin_amdgcn_mfma_f32_32x32x16_bf16(a0l.v, bh2.v, y0, 0, 0, 0);
      y1 = __builtin_amdgcn_mfma_f32_32x32x16_bf16(a1l.v, bh2.v, y1, 0, 0, 0);
      y0 = __builtin_amdgcn_mfma_f32_32x32x16_bf16(a0h.v, bl2.v, y0, 0, 0, 0);
      y1 = __builtin_amdgcn_mfma_f32_32x32x16_bf16(a1h.v, bl2.v, y1, 0, 0, 0);
    }
    __builtin_amdgcn_s_setprio(0);

    const int sloc = t * 4 + (lrow >> 3);
    const int sld = sloc * 65;
    float yr0[16], yr1[16];
#pragma unroll
    for (int r = 0; r < 16; ++r) {
      const int dd = (r & 3) + 8 * (r >> 2) + 4 * lhi;
      const float c0 = Cs[sld + dd],      s0v = Sn[sld + dd];
      const float c1 = Cs[sld + dd + 32], s1v = Sn[sld + dd + 32];
      yr0[r] = y0[r] * c0 - y1[r] * s0v;
      yr1[r] = y1[r] * c1 + y0[r] * s1v;
    }

    unsigned Bh[4][4], Bl[4][4];
    {
      const float* src[2] = { yr0, yr1 };
#pragma unroll
      for (int st = 0; st < 2; ++st) {
#pragma unroll
        for (int half = 0; half < 2; ++half) {
          const int ks2 = st * 2 + half;
          const float* q = src[st] + half * 8;
          unsigned ph[4], pl[4];
          split8(q, ph, pl);
          {
            const unsigned t0 = lhi ? ph[0] : ph[2];
            const unsigned r0 = (unsigned)__shfl_xor((int)t0, 32);
            const unsigned t1 = lhi ? ph[1] : ph[3];
            const unsigned r1 = (unsigned)__shfl_xor((int)t1, 32);
            Bh[ks2][0] = lhi ? r0 : ph[0];
            Bh[ks2][1] = lhi ? r1 : ph[1];
            Bh[ks2][2] = lhi ? ph[2] : r0;
            Bh[ks2][3] = lhi ? ph[3] : r1;
          }
          {
            const unsigned t0 = lhi ? pl[0] : pl[2];
            const unsigned r0 = (unsigned)__shfl_xor((int)t0, 32);
            const unsigned t1 = lhi ? pl[1] : pl[3];
            const unsigned r1 = (unsigned)__shfl_xor((int)t1, 32);
            Bl[ks2][0] = lhi ? r0 : pl[0];
            Bl[ks2][1] = lhi ? r1 : pl[1];
            Bl[ks2][2] = lhi ? pl[2] : r0;
            Bl[ks2][3] = lhi ? pl[3] : r1;
          }
        }
      }
    }

    f32x16 d0, d1;
#pragma unroll
    for (int r = 0; r < 16; ++r) { d0[r] = 0.f; d1[r] = 0.f; }
    __builtin_amdgcn_s_setprio(1);
#pragma unroll
    for (int ks2 = 0; ks2 < 4; ++ks2) {
      U4B8 a0h, a0l, a1h, a1l, bh2, bl2;
      a0h.u = *(const uint4*)&FT[0][ks2][0][lane * 16];
      a0l.u = *(const uint4*)&FT[0][ks2][1][lane * 16];
      a1h.u = *(const uint4*)&FT[1][ks2][0][lane * 16];
      a1l.u = *(const uint4*)&FT[1][ks2][1][lane * 16];
      bh2.u = make_uint4(Bh[ks2][0], Bh[ks2][1], Bh[ks2][2], Bh[ks2][3]);
      bl2.u = make_uint4(Bl[ks2][0], Bl[ks2][1], Bl[ks2][2], Bl[ks2][3]);
      d0 = __builtin_amdgcn_mfma_f32_32x32x16_bf16(a0h.v, bh2.v, d0, 0, 0, 0);
      d1 = __builtin_amdgcn_mfma_f32_32x32x16_bf16(a1h.v, bh2.v, d1, 0, 0, 0);
      d0 = __builtin_amdgcn_mfma_f32_32x32x16_bf16(a0l.v, bh2.v, d0, 0, 0, 0);
      d1 = __builtin_amdgcn_mfma_f32_32x32x16_bf16(a1l.v, bh2.v, d1, 0, 0, 0);
      d0 = __builtin_amdgcn_mfma_f32_32x32x16_bf16(a0h.v, bl2.v, d0, 0, 0, 0);
      d1 = __builtin_amdgcn_mfma_f32_32x32x16_bf16(a1h.v, bl2.v, d1, 0, 0, 0);
    }
    __builtin_amdgcn_s_setprio(0);

    const float wt = Wm[sloc * 8 + (lrow & 7)];
    float oc[32], os[32];
#pragma unroll
    for (int r = 0; r < 32; ++r) {
      const float pr = (r < 16) ? d0[r] : d1[r - 16];
      float sv, cv;
      __sincosf(pr, &sv, &cv);
      oc[r] = wt * cv;
      os[r] = wt * sv;
    }
#pragma unroll
    for (int r = 0; r < 32; ++r) {
      oc[r] += __shfl_xor(oc[r], 1); os[r] += __shfl_xor(os[r], 1);
      oc[r] += __shfl_xor(oc[r], 2); os[r] += __shfl_xor(os[r], 2);
      oc[r] += __shfl_xor(oc[r], 4); os[r] += __shfl_xor(os[r], 4);
    }

    const int m = lrow & 7, srel = lrow >> 3;
#pragma unroll
    for (int rr2 = 0; rr2 < 4; ++rr2) {
      const int r = m * 4 + rr2;
      const int f = (r & 3) + 8 * ((r >> 2) & 3) + 4 * lhi + ((r >> 4) << 5);
      *(unsigned short*)(obh + srel * 256 + f * 2) =
          (unsigned short)cvt_pk_bf16(oc[r] * 0.125f, 0.f);
      *(unsigned short*)(obh + srel * 256 + 128 + f * 2) =
          (unsigned short)cvt_pk_bf16(os[r] * 0.125f, 0.f);
    }
    const uint4 vh = *(const uint4*)(obh + lane * 16);
    const int srow = sblk + t * 4 + (lane >> 4);
    if (!qk) {
      const size_t off = ((size_t)bh * S_ + srow) * 256 + (lane & 15) * 16;
      *(uint4*)(oh + off) = vh;
    } else {
      const int klr = srow & 31, ch = srow >> 5;
      const unsigned inner = (unsigned)(((klr << 8) + (lane & 15) * 16) ^ ((klr & 7) << 4));
      const size_t off = (size_t)bh * 262144 + (size_t)ch * 8192 + inner;
      *(uint4*)(oh + off) = vh;
    }
  }
}

// ---------------------------------------------------------------------------
// V projection, MFMA; hi plane only (unchanged).
// ---------------------------------------------------------------------------
__global__ __launch_bounds__(256) void k_proj_v(
    const float* __restrict__ atoms, const float* __restrict__ W,
    char* __restrict__ vthi)
{
  const int sblk = blockIdx.x * 64;
  const int h = blockIdx.y, b = blockIdx.z;
  const int tid = threadIdx.x;
  const int w = tid >> 6, lane = tid & 63;
  const int lrow = lane & 31, lhi = lane >> 5;

  __shared__ __align__(16) float T[4][8 * 520];

  unsigned wAh[2][4][4], wAl[2][4][4];
#pragma unroll
  for (int wt = 0; wt < 2; ++wt)
#pragma unroll
    for (int ks = 0; ks < 4; ++ks) {
      const float* wp = W + h * 4096 + (wt * 32 + lrow) * 64 + ks * 16 + lhi * 8;
      float v[8];
      const float4 a = *(const float4*)wp;
      const float4 b2 = *(const float4*)(wp + 4);
      v[0] = a.x; v[1] = a.y; v[2] = a.z; v[3] = a.w;
      v[4] = b2.x; v[5] = b2.y; v[6] = b2.z; v[7] = b2.w;
      split8(v, wAh[wt][ks], wAl[wt][ks]);
    }

  const int bh = b * H_ + h;
  float* Tw = &T[w][0];

  for (int p = 0; p < 2; ++p) {
#pragma unroll
    for (int half8 = 0; half8 < 2; ++half8) {
      const int t = w * 4 + p * 2 + half8;
      const float* arow = atoms + ((size_t)(b * S_ + sblk) * 8 + t * 32 + lrow) * 64;
      unsigned aBh[4][4], aBl[4][4];
#pragma unroll
      for (int ks = 0; ks < 4; ++ks) {
        float v[8];
        const float4 a = *(const float4*)(arow + ks * 16 + lhi * 8);
        const float4 b2 = *(const float4*)(arow + ks * 16 + lhi * 8 + 4);
        v[0] = a.x; v[1] = a.y; v[2] = a.z; v[3] = a.w;
        v[4] = b2.x; v[5] = b2.y; v[6] = b2.z; v[7] = b2.w;
        split8(v, aBh[ks], aBl[ks]);
      }

      f32x16 y0, y1;
#pragma unroll
      for (int r = 0; r < 16; ++r) { y0[r] = 0.f; y1[r] = 0.f; }
      __builtin_amdgcn_s_setprio(1);
#pragma unroll
      for (int ks = 0; ks < 4; ++ks) {
        U4B8 a0h, a0l, a1h, a1l, bh2, bl2;
        a0h.u = make_uint4(wAh[0][ks][0], wAh[0][ks][1], wAh[0][ks][2], wAh[0][ks][3]);
        a0l.u = make_uint4(wAl[0][ks][0], wAl[0][ks][1], wAl[0][ks][2], wAl[0][ks][3]);
        a1h.u = make_uint4(wAh[1][ks][0], wAh[1][ks][1], wAh[1][ks][2], wAh[1][ks][3]);
        a1l.u = make_uint4(wAl[1][ks][0], wAl[1][ks][1], wAl[1][ks][2], wAl[1][ks][3]);
        bh2.u = make_uint4(aBh[ks][0], aBh[ks][1], aBh[ks][2], aBh[ks][3]);
        bl2.u = make_uint4(aBl[ks][0], aBl[ks][1], aBl[ks][2], aBl[ks][3]);
        y0 = __builtin_amdgcn_mfma_f32_32x32x16_bf16(a0h.v, bh2.v, y0, 0, 0, 0);
        y1 = __builtin_amdgcn_mfma_f32_32x32x16_bf16(a1h.v, bh2.v, y1, 0, 0, 0);
        y0 = __builtin_amdgcn_mfma_f32_32x32x16_bf16(a0l.v, bh2.v, y0, 0, 0, 0);
        y1 = __builtin_amdgcn_mfma_f32_32x32x16_bf16(a1l.v, bh2.v, y1, 0, 0, 0);
        y0 = __builtin_amdgcn_mfma_f32_32x32x16_bf16(a0h.v, bl2.v, y0, 0, 0, 0);
        y1 = __builtin_amdgcn_mfma_f32_32x32x16_bf16(a1h.v, bl2.v, y1, 0, 0, 0);
      }
      __builtin_amdgcn_s_setprio(0);

      const int s_in = half8 * 4 + (lrow >> 3);
      const int m = lrow & 7;
#pragma unroll
      for (int r = 0; r < 16; ++r) {
        const int dd = (r & 3) + 8 * (r >> 2) + 4 * lhi;
        Tw[s_in * 520 + m * 64 + dd] = y0[r];
        Tw[s_in * 520 + m * 64 + dd + 32] = y1[r];
      }
    }
    const int s0 = sblk + w * 16 + p * 8;
    const int ch = s0 >> 5, half = (s0 >> 4) & 1, part2 = (s0 >> 3) & 1;
    const size_t base = (size_t)bh * 1048576 + (size_t)ch * 32768 + half * 16384;
#pragma unroll
    for (int j = 0; j < 8; ++j) {
      const int c = j * 64 + lane;
      float v[8];
#pragma unroll
      for (int s = 0; s < 8; ++s) v[s] = Tw[s * 520 + c];
      unsigned hw[4];
#pragma unroll
      for (int pq = 0; pq < 4; ++pq)
        hw[pq] = cvt_pk_bf16(v[2 * pq], v[2 * pq + 1]);
      const unsigned inner = (unsigned)(c * 32 + part2 * 16);
      *(uint4*)(vthi + base + inner) = make_uint4(hw[0], hw[1], hw[2], hw[3]);
    }
  }
}

// ---------------------------------------------------------------------------
// MFMA flash attention (R14 structure, K hi-only). 512 blocks x 256 threads.
// Producer wave pw computes P(ch+1) (scores = Kh·Qh) while all 4 waves PV(ch)
// from PAsm[ch&1]. All waves stage K (hi plane, 2 loads/chunk); V hi in regs.
// ---------------------------------------------------------------------------
__global__ __launch_bounds__(256, 2) void k_flash(
    const unsigned short* __restrict__ qrh,
    const char* __restrict__ krh,
    const char* __restrict__ vthi,
    float* __restrict__ ao)
{
  __shared__ __align__(16) char Ksm[16384];     // K hi dbuf [2][8192]
  __shared__ __align__(16) char PAsm[2][4096];
  __shared__ float Slinv[32];

  const int tid = threadIdx.x;
  const int w = tid >> 6, lane = tid & 63;
  const int lrow = lane & 31, lhi = lane >> 5;

  const int phys = blockIdx.x;
  const int x = phys & 7, j = phys >> 3;          // x = XCD
  const int bh = (x << 1) | (j >> 5);
  const int qb = j & 31;
  const int b = bh >> 3, h = bh & 7;
  const int qbase = qb * 32;
  const int pw = (phys ^ (phys >> 2) ^ (phys >> 8)) & 3;
  const bool prod = (w == pw);

  uint4 qfh[8];
  if (prod) {
    const size_t rowb = ((size_t)bh * S_ + qbase + lrow) * 128;
#pragma unroll
    for (int fs = 0; fs < 8; ++fs)
      qfh[fs] = *(const uint4*)(qrh + rowb + fs * 16 + lhi * 8);
  }

  const char* vh_c = vthi + (size_t)bh * 1048576;
  const char* kh_c = krh + (size_t)bh * 262144;

  auto issue_k = [&](int ch) {                    // hi plane only, 2 loads/wave
    char* dh = Ksm + (ch & 1) * 8192;
    const size_t g = (size_t)ch * 8192;
#pragma unroll
    for (int i = 0; i < 2; ++i)
      __builtin_amdgcn_global_load_lds(kh_c + g + i * 4096 + tid * 16, dh + i * 4096 + (w << 10), 16, 0, 0);
  };

  const unsigned vbase = (unsigned)((w * 128 + lrow) * 32 + lhi * 16);
  uint4 vAh[4], vBh[4];
  auto load_vA = [&](int ch) {
    const size_t g = (size_t)ch * 32768 + vbase;
#pragma unroll
    for (int cf = 0; cf < 4; ++cf)
      vAh[cf] = *(const uint4*)(vh_c + g + cf * 1024);
  };
  auto load_vB = [&](int ch) {
    const size_t g = (size_t)ch * 32768 + 16384 + vbase;
#pragma unroll
    for (int cf = 0; cf < 4; ++cf)
      vBh[cf] = *(const uint4*)(vh_c + g + cf * 1024);
  };

  f32x16 acc[4];
#pragma unroll
  for (int i = 0; i < 4; ++i)
#pragma unroll
    for (int r = 0; r < 16; ++r) acc[i][r] = 0.f;
  float l_run = 0.f;

  auto produce = [&](int chp) {
    const char* kb = Ksm + (chp & 1) * 8192;
    f32x16 s0, s1;
#pragma unroll
    for (int r = 0; r < 16; ++r) { s0[r] = 0.f; s1[r] = 0.f; }
    __builtin_amdgcn_s_setprio(1);
#pragma unroll
    for (int fs = 0; fs < 8; ++fs) {
      const unsigned kaddr = (unsigned)((lrow * 256 + fs * 32 + lhi * 16) ^ ((lrow & 7) << 4));
      U4B8 khf, qh;
      khf.u = *(const uint4*)(kb + kaddr);
      qh.u = qfh[fs];
      if (fs & 1) s1 = __builtin_amdgcn_mfma_f32_32x32x16_bf16(khf.v, qh.v, s1, 0, 0, 0);
      else        s0 = __builtin_amdgcn_mfma_f32_32x32x16_bf16(khf.v, qh.v, s0, 0, 0, 0);
    }
    __builtin_amdgcn_s_setprio(0);
    float p[16];
#pragma unroll
    for (int r = 0; r < 16; ++r) p[r] = __expf(s0[r] + s1[r]);
    float rs = 0.f;
#pragma unroll
    for (int r = 0; r < 16; ++r) rs += p[r];
    rs += __shfl_xor(rs, 32);
    l_run += rs;

    unsigned wh[8], wl[8];
#pragma unroll
    for (int i = 0; i < 8; ++i) {
      const float a = p[2 * i], c2 = p[2 * i + 1];
      const unsigned hword = cvt_pk_bf16(a, c2);
      const float ra = a - __uint_as_float(hword << 16);
      const float rc = c2 - __uint_as_float(hword & 0xffff0000u);
      wh[i] = hword;
      wl[i] = cvt_pk_bf16(ra, rc);
    }
    auto mix = [&](unsigned &lo_w, unsigned &hi_w) {
      const unsigned t = lhi ? lo_w : hi_w;
      const unsigned r = (unsigned)__shfl_xor((int)t, 32);
      lo_w = lhi ? r : lo_w;
      hi_w = lhi ? hi_w : r;
    };
    mix(wh[0], wh[2]); mix(wh[1], wh[3]); mix(wh[4], wh[6]); mix(wh[5], wh[7]);
    mix(wl[0], wl[2]); mix(wl[1], wl[3]); mix(wl[4], wl[6]); mix(wl[5], wl[7]);

    char* pb = &PAsm[chp & 1][0];
    *(uint4*)(pb + 0 * 1024 + lane * 16) = make_uint4(wh[0], wh[1], wh[2], wh[3]);
    *(uint4*)(pb + 1 * 1024 + lane * 16) = make_uint4(wh[4], wh[5], wh[6], wh[7]);
    *(uint4*)(pb + 2 * 1024 + lane * 16) = make_uint4(wl[0], wl[1], wl[2], wl[3]);
    *(uint4*)(pb + 3 * 1024 + lane * 16) = make_uint4(wl[4], wl[5], wl[6], wl[7]);
  };

  // ---- prologue ----
  issue_k(0);                        // 2
  issue_k(1);                        // 2
  load_vA(0);                        // 4
  load_vB(0);                        // 4
  asm volatile("s_waitcnt vmcnt(10)" ::: "memory");   // K(0) landed
  SBAR(); MEMFENCE();
  if (prod) produce(0);
  asm volatile("s_waitcnt lgkmcnt(0)" ::: "memory");
  SCHED0(); SBAR(); MEMFENCE();      // P(0) visible
  asm volatile("s_waitcnt vmcnt(8)" ::: "memory");    // K(1) landed

  for (int ch = 0; ch < 32; ++ch) {
    if (ch < 30) { SCHED0(); issue_k(ch + 2); SCHED0(); }

    if (prod && ch < 31) produce(ch + 1);

    // ---- all waves: PV(ch) from PAsm[ch&1], hi-V only ----
    U4B8 pah0, pah1, pal0, pal1;
    {
      const char* pb = &PAsm[ch & 1][0];
      pah0.u = *(const uint4*)(pb + 0 * 1024 + lane * 16);
      pah1.u = *(const uint4*)(pb + 1 * 1024 + lane * 16);
      pal0.u = *(const uint4*)(pb + 2 * 1024 + lane * 16);
      pal1.u = *(const uint4*)(pb + 3 * 1024 + lane * 16);
    }

    __builtin_amdgcn_s_setprio(1);
#pragma unroll
    for (int cf = 0; cf < 4; ++cf) {
      U4B8 vh;
      vh.u = vAh[cf];
      acc[cf] = __builtin_amdgcn_mfma_f32_32x32x16_bf16(pah0.v, vh.v, acc[cf], 0, 0, 0);
      acc[cf] = __builtin_amdgcn_mfma_f32_32x32x16_bf16(pal0.v, vh.v, acc[cf], 0, 0, 0);
    }
    __builtin_amdgcn_s_setprio(0);
    if (ch < 31) load_vA(ch + 1);

    __builtin_amdgcn_s_setprio(1);
#pragma unroll
    for (int cf = 0; cf < 4; ++cf) {
      U4B8 vh;
      vh.u = vBh[cf];
      acc[cf] = __builtin_amdgcn_mfma_f32_32x32x16_bf16(pah1.v, vh.v, acc[cf], 0, 0, 0);
      acc[cf] = __builtin_amdgcn_mfma_f32_32x32x16_bf16(pal1.v, vh.v, acc[cf], 0, 0, 0);
    }
    __builtin_amdgcn_s_setprio(0);

    if (ch < 31) {
      load_vB(ch + 1);
      // outstanding: K(ch+2)x2 oldest + vA4 + vB4 -> drain K only
      SCHED0();
      asm volatile("s_waitcnt vmcnt(8)" ::: "memory");
      asm volatile("s_waitcnt lgkmcnt(0)" ::: "memory");
      SBAR(); MEMFENCE();
    }
  }

  // ---- epilogue ----
  if (prod && lane < 32) Slinv[lrow] = 1.0f / l_run;
  asm volatile("s_waitcnt lgkmcnt(0)" ::: "memory");
  SBAR(); MEMFENCE();
  float lr[16];
#pragma unroll
  for (int r = 0; r < 16; ++r)
    lr[r] = Slinv[(r & 3) + 8 * (r >> 2) + 4 * lhi];
#pragma unroll
  for (int cf = 0; cf < 4; ++cf) {
    const int c = w * 128 + cf * 32 + lrow;
    const int m = c >> 6, dd = c & 63;
#pragma unroll
    for (int r = 0; r < 16; ++r) {
      const int qr = (r & 3) + 8 * (r >> 2) + 4 * lhi;
      const int srow = qbase + qr;
      const size_t off = (((size_t)(b * S_ + srow)) * 8 + m) * 512 + h * 64 + dd;
      ao[off] = acc[cf][r] * lr[r];
    }
  }
}

// ---------------------------------------------------------------------------
// k_out MFMA (unchanged from R10).
// ---------------------------------------------------------------------------
__global__ __launch_bounds__(256) void k_out(
    const float* __restrict__ ao, const float* __restrict__ Wo,
    const float* __restrict__ Ww, const float* __restrict__ qlw,
    float* __restrict__ out)
{
  const int tid = threadIdx.x;
  const int w = tid >> 6, lane = tid & 63;
  const int lrow = lane & 31, lhi = lane >> 5;
  const int Rblk = blockIdx.x * 128;

  __shared__ __align__(16) char WoF[4][2][2][1024];
  __shared__ __align__(16) float Os[128 * 68];

  f32x16 acc[2];
#pragma unroll
  for (int i = 0; i < 2; ++i)
#pragma unroll
    for (int r = 0; r < 16; ++r) acc[i][r] = 0.f;

  const float* brow = ao + (size_t)(Rblk + w * 32 + lrow) * 512;

  for (int chunk = 0; chunk < 8; ++chunk) {
    __syncthreads();
#pragma unroll
    for (int dt = 0; dt < 2; ++dt) {
      const float* wp = Wo + (size_t)(dt * 32 + lrow) * 512 + (chunk * 4 + w) * 16 + lhi * 8;
      float v[8];
      const float4 a = *(const float4*)wp;
      const float4 b2 = *(const float4*)(wp + 4);
      v[0] = a.x; v[1] = a.y; v[2] = a.z; v[3] = a.w;
      v[4] = b2.x; v[5] = b2.y; v[6] = b2.z; v[7] = b2.w;
      unsigned hw[4], lw2[4];
      split8(v, hw, lw2);
      *(uint4*)&WoF[w][dt][0][lane * 16] = make_uint4(hw[0], hw[1], hw[2], hw[3]);
      *(uint4*)&WoF[w][dt][1][lane * 16] = make_uint4(lw2[0], lw2[1], lw2[2], lw2[3]);
    }
    __syncthreads();

#pragma unroll
    for (int kl = 0; kl < 4; ++kl) {
      float v[8];
      const float4 a = *(const float4*)(brow + (chunk * 4 + kl) * 16 + lhi * 8);
      const float4 b2 = *(const float4*)(brow + (chunk * 4 + kl) * 16 + lhi * 8 + 4);
      v[0] = a.x; v[1] = a.y; v[2] = a.z; v[3] = a.w;
      v[4] = b2.x; v[5] = b2.y; v[6] = b2.z; v[7] = b2.w;
      unsigned bhw[4], blw[4];
      split8(v, bhw, blw);
      U4B8 bh2, bl2;
      bh2.u = make_uint4(bhw[0], bhw[1], bhw[2], bhw[3]);
      bl2.u = make_uint4(blw[0], blw[1], blw[2], blw[3]);
      __builtin_amdgcn_s_setprio(1);
#pragma unroll
      for (int dt = 0; dt < 2; ++dt) {
        U4B8 ah, al;
        ah.u = *(const uint4*)&WoF[kl][dt][0][lane * 16];
        al.u = *(const uint4*)&WoF[kl][dt][1][lane * 16];
        acc[dt] = __builtin_amdgcn_mfma_f32_32x32x16_bf16(ah.v, bh2.v, acc[dt], 0, 0, 0);
        acc[dt] = __builtin_amdgcn_mfma_f32_32x32x16_bf16(al.v, bh2.v, acc[dt], 0, 0, 0);
        acc[dt] = __builtin_amdgcn_mfma_f32_32x32x16_bf16(ah.v, bl2.v, acc[dt], 0, 0, 0);
      }
      __builtin_amdgcn_s_setprio(0);
    }
  }

  __syncthreads();
#pragma unroll
  for (int dt = 0; dt < 2; ++dt)
#pragma unroll
    for (int r = 0; r < 16; ++r) {
      const int d = dt * 32 + (r & 3) + 8 * (r >> 2) + 4 * lhi;
      Os[(w * 32 + lrow) * 68 + d] = acc[dt][r];
    }
  __syncthreads();

#pragma unroll
  for (int jj = 0; jj < 8; ++jj) {
    const int i = tid + 256 * jj;
    const int r = i >> 4, c4 = (i & 15) * 4;
    const float4 v = *(const float4*)&Os[r * 68 + c4];
    *(float4*)&out[(size_t)(Rblk + r) * 64 + c4] = v;
  }

#pragma unroll
  for (int gi = 0; gi < 4; ++gi) {
    const int g = w * 4 + gi;
    float mean = 0.f;
#pragma unroll
    for (int m = 0; m < 8; ++m) mean += Os[(g * 8 + m) * 68 + lane];
    mean *= 0.125f;
    float dsel = 0.f;
#pragma unroll
    for (int mw = 0; mw < 8; ++mw) {
      float part = mean * Ww[mw * 64 + lane];
      part += __shfl_xor(part, 1);
      part += __shfl_xor(part, 2);
      part += __shfl_xor(part, 4);
      part += __shfl_xor(part, 8);
      part += __shfl_xor(part, 16);
      part += __shfl_xor(part, 32);
      if (lane == mw) dsel = part;
    }
    if (lane < 8) {
      const int idx = Rblk + g * 8 + lane;
      out[1048576 + idx] = qlw[idx] + dsel;
    }
  }
}

// ---------------------------------------------------------------------------
extern "C" void kernel_launch(void* const* d_in, const int* in_sizes, int n_in,
                              void* d_out, int out_size, void* d_ws, size_t ws_size,
                              hipStream_t stream)
{
  const float* q_atoms = (const float*)d_in[0];
  const float* q_logw  = (const float*)d_in[1];
  const float* k_atoms = (const float*)d_in[2];
  const float* k_logw  = (const float*)d_in[3];
  const float* v_atoms = (const float*)d_in[4];
  const float* cosT  = (const float*)d_in[6];
  const float* sinT  = (const float*)d_in[7];
  const float* Wq    = (const float*)d_in[8];
  const float* Wk    = (const float*)d_in[9];
  const float* Wv    = (const float*)d_in[10];
  const float* Wo    = (const float*)d_in[11];
  const float* Ww    = (const float*)d_in[12];
  const float* logbw = (const float*)d_in[13];
  const float* rffb  = (const float*)d_in[14];
  float* out = (float*)d_out;

  char* wsb = (char*)d_ws;
  char* qrh = wsb;
  char* krh = wsb + (8u << 20);
  char* vthi = wsb + (16u << 20);
  float* ao = (float*)(wsb + (48u << 20));

  const dim3 blk(256);
  k_proj_rff<<<dim3(16, 8, 4), blk, 0, stream>>>(q_atoms, q_logw, k_atoms, k_logw,
                                                 Wq, Wk, rffb, logbw, cosT, sinT,
                                                 qrh, krh);
  k_proj_v  <<<dim3(16, 8, 2), blk, 0, stream>>>(v_atoms, Wv, vthi);
  k_flash   <<<dim3(512), blk, 0, stream>>>((const unsigned short*)qrh,
                                            krh, vthi, ao);
  k_out     <<<dim3(128), blk, 0, stream>>>(ao, Wo, Ww, q_logw, out);
}

// Round 17
// 129.415 us; speedup vs baseline: 1.3745x; 1.0538x over previous
//
#include <hip/hip_runtime.h>
#include <math.h>

// KME attention. B=2 S=1024 M=8 D=64 H=8 NF=64
// Round 17:
//  - k_flash: 64-k phases (16 barriers); producer publishes RAW exp(s) f32 to
//    transposed Praw[k][q] LDS (no bf16-split/mix on the critical path);
//    consumers rebuild A-fragments locally (reads + split8). K hi 16KB/phase
//    dbuf; V regs refilled per k-slot.
//  - k_proj_rff: GEMMs 2-term split (drop W-lo / freq-lo terms, err ~2.5e-4).
//
// ws layout (bytes), 80 MiB total:
//   qrh  @ 0MB   4MB  ushort [bh][s][128]          (natural)
//   krh  @ 8MB   4MB  swizzled-chunk layout [bh][ch=32][8192B]
//   vthi @16MB  16MB  [bh][ch=32][half=2][c=512][32B], inner=c*32+part2*16
//   ao   @48MB  32MB  f32 [b][s][m][512]

#define B_ 2
#define S_ 1024
#define H_ 8

typedef __attribute__((ext_vector_type(8))) short short8;
typedef __attribute__((ext_vector_type(16))) float f32x16;
union U4B8 { uint4 u; short8 v; };

#define SBAR() __builtin_amdgcn_s_barrier()
#define SCHED0() __builtin_amdgcn_sched_barrier(0)
#define MEMFENCE() asm volatile("" ::: "memory")

__device__ inline unsigned cvt_pk_bf16(float a, float b) {
  unsigned r;
  asm("v_cvt_pk_bf16_f32 %0, %1, %2" : "=v"(r) : "v"(a), "v"(b));
  return r;
}
__device__ inline void split8(const float* v, unsigned* hw, unsigned* lw) {
#pragma unroll
  for (int p = 0; p < 4; ++p) {
    const float a = v[2 * p], b = v[2 * p + 1];
    const unsigned h = cvt_pk_bf16(a, b);
    const float ra = a - __uint_as_float(h << 16);
    const float rb = b - __uint_as_float(h & 0xffff0000u);
    hw[p] = h;
    lw[p] = cvt_pk_bf16(ra, rb);
  }
}

// ---------------------------------------------------------------------------
// MFMA projection + RoPE + RFF encode; hi-only outputs; 2-term split GEMMs.
// ---------------------------------------------------------------------------
__global__ __launch_bounds__(256, 2) void k_proj_rff(
    const float* __restrict__ q_atoms, const float* __restrict__ q_logw,
    const float* __restrict__ k_atoms, const float* __restrict__ k_logw,
    const float* __restrict__ Wq, const float* __restrict__ Wk,
    const float* __restrict__ freqb, const float* __restrict__ logbw,
    const float* __restrict__ cosT, const float* __restrict__ sinT,
    char* __restrict__ qoh, char* __restrict__ koh)
{
  const int sblk = blockIdx.x * 64;
  const int h = blockIdx.y, z = blockIdx.z;
  const int qk = z >> 1, b = z & 1;
  const float* atoms = qk ? k_atoms : q_atoms;
  const float* logw  = qk ? k_logw : q_logw;
  const float* W     = qk ? Wk : Wq;
  char* oh = qk ? koh : qoh;

  const int tid = threadIdx.x;
  const int w = tid >> 6, lane = tid & 63;
  const int lrow = lane & 31, lhi = lane >> 5;

  __shared__ float Cs[64 * 65];
  __shared__ float Sn[64 * 65];
  __shared__ float Wm[64 * 8];
  __shared__ __align__(16) char FT[2][4][2][1024];
  __shared__ __align__(16) char Ob[4][1024];

  for (int i = tid; i < 4096; i += 256) {
    const int sl = i >> 6, d = i & 63;
    Cs[sl * 65 + d] = cosT[(sblk + sl) * 64 + d];
    Sn[sl * 65 + d] = sinT[(sblk + sl) * 64 + d];
  }
  if (tid < 64) {
    const float* lw = logw + (size_t)(b * S_ + sblk + tid) * 8;
    float mx = lw[0];
    for (int m = 1; m < 8; ++m) mx = fmaxf(mx, lw[m]);
    float e[8], sum = 0.f;
    for (int m = 0; m < 8; ++m) { e[m] = __expf(lw[m] - mx); sum += e[m]; }
    const float inv = 1.0f / sum;
    for (int m = 0; m < 8; ++m) Wm[tid * 8 + m] = e[m] * inv;
  }
  const float fscale = __expf(-logbw[h]);
  {
    const int ftw = w & 1;
#pragma unroll
    for (int kk = 0; kk < 2; ++kk) {
      const int ks2 = (w >> 1) + kk * 2;
      float v[8];
#pragma unroll
      for (int j = 0; j < 8; ++j)
        v[j] = freqb[h * 4096 + (ks2 * 16 + lhi * 8 + j) * 64 + ftw * 32 + lrow] * fscale;
      unsigned hw[4], lw2[4];
      split8(v, hw, lw2);
      *(uint4*)&FT[ftw][ks2][0][lane * 16] = make_uint4(hw[0], hw[1], hw[2], hw[3]);
      *(uint4*)&FT[ftw][ks2][1][lane * 16] = make_uint4(lw2[0], lw2[1], lw2[2], lw2[3]);
    }
  }
  unsigned wAh[2][4][4], wAl[2][4][4];
#pragma unroll
  for (int wt = 0; wt < 2; ++wt)
#pragma unroll
    for (int ks = 0; ks < 4; ++ks) {
      const float* wp = W + h * 4096 + (wt * 32 + lrow) * 64 + ks * 16 + lhi * 8;
      float v[8];
      const float4 a = *(const float4*)wp;
      const float4 b2 = *(const float4*)(wp + 4);
      v[0] = a.x; v[1] = a.y; v[2] = a.z; v[3] = a.w;
      v[4] = b2.x; v[5] = b2.y; v[6] = b2.z; v[7] = b2.w;
      split8(v, wAh[wt][ks], wAl[wt][ks]);
    }
  __syncthreads();

  const int bh = b * H_ + h;
  char* obh = &Ob[w][0];

  for (int it = 0; it < 4; ++it) {
    const int t = w * 4 + it;
    const float* arow = atoms + ((size_t)(b * S_ + sblk) * 8 + t * 32 + lrow) * 64;
    unsigned aBh[4][4], aBl[4][4];
#pragma unroll
    for (int ks = 0; ks < 4; ++ks) {
      float v[8];
      const float4 a = *(const float4*)(arow + ks * 16 + lhi * 8);
      const float4 b2 = *(const float4*)(arow + ks * 16 + lhi * 8 + 4);
      v[0] = a.x; v[1] = a.y; v[2] = a.z; v[3] = a.w;
      v[4] = b2.x; v[5] = b2.y; v[6] = b2.z; v[7] = b2.w;
      split8(v, aBh[ks], aBl[ks]);
    }

    f32x16 y0, y1;
#pragma unroll
    for (int r = 0; r < 16; ++r) { y0[r] = 0.f; y1[r] = 0.f; }
    __builtin_amdgcn_s_setprio(1);
#pragma unroll
    for (int ks = 0; ks < 4; ++ks) {
      U4B8 a0h, a1h, bh2, bl2;
      a0h.u = make_uint4(wAh[0][ks][0], wAh[0][ks][1], wAh[0][ks][2], wAh[0][ks][3]);
      a1h.u = make_uint4(wAh[1][ks][0], wAh[1][ks][1], wAh[1][ks][2], wAh[1][ks][3]);
      bh2.u = make_uint4(aBh[ks][0], aBh[ks][1], aBh[ks][2], aBh[ks][3]);
      bl2.u = make_uint4(aBl[ks][0], aBl[ks][1], aBl[ks][2], aBl[ks][3]);
      y0 = __builtin_amdgcn_mfma_f32_32x32x16_bf16(a0h.v, bh2.v, y0, 0, 0, 0);
      y1 = __builtin_amdgcn_mfma_f32_32x32x16_bf16(a1h.v, bh2.v, y1, 0, 0, 0);
      y0 = __builtin_amdgcn_mfma_f32_32x32x16_bf16(a0h.v, bl2.v, y0, 0, 0, 0);
      y1 = __builtin_amdgcn_mfma_f32_32x32x16_bf16(a1h.v, bl2.v, y1, 0, 0, 0);
    }
    __builtin_amdgcn_s_setprio(0);

    const int sloc = t * 4 + (lrow >> 3);
    const int sld = sloc * 65;
    float yr0[16], yr1[16];
#pragma unroll
    for (int r = 0; r < 16; ++r) {
      const int dd = (r & 3) + 8 * (r >> 2) + 4 * lhi;
      const float c0 = Cs[sld + dd],      s0v = Sn[sld + dd];
      const float c1 = Cs[sld + dd + 32], s1v = Sn[sld + dd + 32];
      yr0[r] = y0[r] * c0 - y1[r] * s0v;
      yr1[r] = y1[r] * c1 + y0[r] * s1v;
    }

    unsigned Bh[4][4], Bl[4][4];
    {
      const float* src[2] = { yr0, yr1 };
#pragma unroll
      for (int st = 0; st < 2; ++st) {
#pragma unroll
        for (int half = 0; half < 2; ++half) {
          const int ks2 = st * 2 + half;
          const float* q = src[st] + half * 8;
          unsigned ph[4], pl[4];
          split8(q, ph, pl);
          {
            const unsigned t0 = lhi ? ph[0] : ph[2];
            const unsigned r0 = (unsigned)__shfl_xor((int)t0, 32);
            const unsigned t1 = lhi ? ph[1] : ph[3];
            const unsigned r1 = (unsigned)__shfl_xor((int)t1, 32);
            Bh[ks2][0] = lhi ? r0 : ph[0];
            Bh[ks2][1] = lhi ? r1 : ph[1];
            Bh[ks2][2] = lhi ? ph[2] : r0;
            Bh[ks2][3] = lhi ? ph[3] : r1;
          }
          {
            const unsigned t0 = lhi ? pl[0] : pl[2];
            const unsigned r0 = (unsigned)__shfl_xor((int)t0, 32);
            const unsigned t1 = lhi ? pl[1] : pl[3];
            const unsigned r1 = (unsigned)__shfl_xor((int)t1, 32);
            Bl[ks2][0] = lhi ? r0 : pl[0];
            Bl[ks2][1] = lhi ? r1 : pl[1];
            Bl[ks2][2] = lhi ? pl[2] : r0;
            Bl[ks2][3] = lhi ? pl[3] : r1;
          }
        }
      }
    }

    f32x16 d0, d1;
#pragma unroll
    for (int r = 0; r < 16; ++r) { d0[r] = 0.f; d1[r] = 0.f; }
    __builtin_amdgcn_s_setprio(1);
#pragma unroll
    for (int ks2 = 0; ks2 < 4; ++ks2) {
      U4B8 a0h, a1h, bh2, bl2;
      a0h.u = *(const uint4*)&FT[0][ks2][0][lane * 16];
      a1h.u = *(const uint4*)&FT[1][ks2][0][lane * 16];
      bh2.u = make_uint4(Bh[ks2][0], Bh[ks2][1], Bh[ks2][2], Bh[ks2][3]);
      bl2.u = make_uint4(Bl[ks2][0], Bl[ks2][1], Bl[ks2][2], Bl[ks2][3]);
      d0 = __builtin_amdgcn_mfma_f32_32x32x16_bf16(a0h.v, bh2.v, d0, 0, 0, 0);
      d1 = __builtin_amdgcn_mfma_f32_32x32x16_bf16(a1h.v, bh2.v, d1, 0, 0, 0);
      d0 = __builtin_amdgcn_mfma_f32_32x32x16_bf16(a0h.v, bl2.v, d0, 0, 0, 0);
      d1 = __builtin_amdgcn_mfma_f32_32x32x16_bf16(a1h.v, bl2.v, d1, 0, 0, 0);
    }
    __builtin_amdgcn_s_setprio(0);

    const float wt = Wm[sloc * 8 + (lrow & 7)];
    float oc[32], os[32];
#pragma unroll
    for (int r = 0; r < 32; ++r) {
      const float pr = (r < 16) ? d0[r] : d1[r - 16];
      float sv, cv;
      __sincosf(pr, &sv, &cv);
      oc[r] = wt * cv;
      os[r] = wt * sv;
    }
#pragma unroll
    for (int r = 0; r < 32; ++r) {
      oc[r] += __shfl_xor(oc[r], 1); os[r] += __shfl_xor(os[r], 1);
      oc[r] += __shfl_xor(oc[r], 2); os[r] += __shfl_xor(os[r], 2);
      oc[r] += __shfl_xor(oc[r], 4); os[r] += __shfl_xor(os[r], 4);
    }

    const int m = lrow & 7, srel = lrow >> 3;
#pragma unroll
    for (int rr2 = 0; rr2 < 4; ++rr2) {
      const int r = m * 4 + rr2;
      const int f = (r & 3) + 8 * ((r >> 2) & 3) + 4 * lhi + ((r >> 4) << 5);
      *(unsigned short*)(obh + srel * 256 + f * 2) =
          (unsigned short)cvt_pk_bf16(oc[r] * 0.125f, 0.f);
      *(unsigned short*)(obh + srel * 256 + 128 + f * 2) =
          (unsigned short)cvt_pk_bf16(os[r] * 0.125f, 0.f);
    }
    const uint4 vh = *(const uint4*)(obh + lane * 16);
    const int srow = sblk + t * 4 + (lane >> 4);
    if (!qk) {
      const size_t off = ((size_t)bh * S_ + srow) * 256 + (lane & 15) * 16;
      *(uint4*)(oh + off) = vh;
    } else {
      const int klr = srow & 31, ch = srow >> 5;
      const unsigned inner = (unsigned)(((klr << 8) + (lane & 15) * 16) ^ ((klr & 7) << 4));
      const size_t off = (size_t)bh * 262144 + (size_t)ch * 8192 + inner;
      *(uint4*)(oh + off) = vh;
    }
  }
}

// ---------------------------------------------------------------------------
// V projection, MFMA; hi plane only; 3-term split kept (V accuracy floor).
// ---------------------------------------------------------------------------
__global__ __launch_bounds__(256) void k_proj_v(
    const float* __restrict__ atoms, const float* __restrict__ W,
    char* __restrict__ vthi)
{
  const int sblk = blockIdx.x * 64;
  const int h = blockIdx.y, b = blockIdx.z;
  const int tid = threadIdx.x;
  const int w = tid >> 6, lane = tid & 63;
  const int lrow = lane & 31, lhi = lane >> 5;

  __shared__ __align__(16) float T[4][8 * 520];

  unsigned wAh[2][4][4], wAl[2][4][4];
#pragma unroll
  for (int wt = 0; wt < 2; ++wt)
#pragma unroll
    for (int ks = 0; ks < 4; ++ks) {
      const float* wp = W + h * 4096 + (wt * 32 + lrow) * 64 + ks * 16 + lhi * 8;
      float v[8];
      const float4 a = *(const float4*)wp;
      const float4 b2 = *(const float4*)(wp + 4);
      v[0] = a.x; v[1] = a.y; v[2] = a.z; v[3] = a.w;
      v[4] = b2.x; v[5] = b2.y; v[6] = b2.z; v[7] = b2.w;
      split8(v, wAh[wt][ks], wAl[wt][ks]);
    }

  const int bh = b * H_ + h;
  float* Tw = &T[w][0];

  for (int p = 0; p < 2; ++p) {
#pragma unroll
    for (int half8 = 0; half8 < 2; ++half8) {
      const int t = w * 4 + p * 2 + half8;
      const float* arow = atoms + ((size_t)(b * S_ + sblk) * 8 + t * 32 + lrow) * 64;
      unsigned aBh[4][4], aBl[4][4];
#pragma unroll
      for (int ks = 0; ks < 4; ++ks) {
        float v[8];
        const float4 a = *(const float4*)(arow + ks * 16 + lhi * 8);
        const float4 b2 = *(const float4*)(arow + ks * 16 + lhi * 8 + 4);
        v[0] = a.x; v[1] = a.y; v[2] = a.z; v[3] = a.w;
        v[4] = b2.x; v[5] = b2.y; v[6] = b2.z; v[7] = b2.w;
        split8(v, aBh[ks], aBl[ks]);
      }

      f32x16 y0, y1;
#pragma unroll
      for (int r = 0; r < 16; ++r) { y0[r] = 0.f; y1[r] = 0.f; }
      __builtin_amdgcn_s_setprio(1);
#pragma unroll
      for (int ks = 0; ks < 4; ++ks) {
        U4B8 a0h, a0l, a1h, a1l, bh2, bl2;
        a0h.u = make_uint4(wAh[0][ks][0], wAh[0][ks][1], wAh[0][ks][2], wAh[0][ks][3]);
        a0l.u = make_uint4(wAl[0][ks][0], wAl[0][ks][1], wAl[0][ks][2], wAl[0][ks][3]);
        a1h.u = make_uint4(wAh[1][ks][0], wAh[1][ks][1], wAh[1][ks][2], wAh[1][ks][3]);
        a1l.u = make_uint4(wAl[1][ks][0], wAl[1][ks][1], wAl[1][ks][2], wAl[1][ks][3]);
        bh2.u = make_uint4(aBh[ks][0], aBh[ks][1], aBh[ks][2], aBh[ks][3]);
        bl2.u = make_uint4(aBl[ks][0], aBl[ks][1], aBl[ks][2], aBl[ks][3]);
        y0 = __builtin_amdgcn_mfma_f32_32x32x16_bf16(a0h.v, bh2.v, y0, 0, 0, 0);
        y1 = __builtin_amdgcn_mfma_f32_32x32x16_bf16(a1h.v, bh2.v, y1, 0, 0, 0);
        y0 = __builtin_amdgcn_mfma_f32_32x32x16_bf16(a0l.v, bh2.v, y0, 0, 0, 0);
        y1 = __builtin_amdgcn_mfma_f32_32x32x16_bf16(a1l.v, bh2.v, y1, 0, 0, 0);
        y0 = __builtin_amdgcn_mfma_f32_32x32x16_bf16(a0h.v, bl2.v, y0, 0, 0, 0);
        y1 = __builtin_amdgcn_mfma_f32_32x32x16_bf16(a1h.v, bl2.v, y1, 0, 0, 0);
      }
      __builtin_amdgcn_s_setprio(0);

      const int s_in = half8 * 4 + (lrow >> 3);
      const int m = lrow & 7;
#pragma unroll
      for (int r = 0; r < 16; ++r) {
        const int dd = (r & 3) + 8 * (r >> 2) + 4 * lhi;
        Tw[s_in * 520 + m * 64 + dd] = y0[r];
        Tw[s_in * 520 + m * 64 + dd + 32] = y1[r];
      }
    }
    const int s0 = sblk + w * 16 + p * 8;
    const int ch = s0 >> 5, half = (s0 >> 4) & 1, part2 = (s0 >> 3) & 1;
    const size_t base = (size_t)bh * 1048576 + (size_t)ch * 32768 + half * 16384;
#pragma unroll
    for (int j = 0; j < 8; ++j) {
      const int c = j * 64 + lane;
      float v[8];
#pragma unroll
      for (int s = 0; s < 8; ++s) v[s] = Tw[s * 520 + c];
      unsigned hw[4];
#pragma unroll
      for (int pq = 0; pq < 4; ++pq)
        hw[pq] = cvt_pk_bf16(v[2 * pq], v[2 * pq + 1]);
      const unsigned inner = (unsigned)(c * 32 + part2 * 16);
      *(uint4*)(vthi + base + inner) = make_uint4(hw[0], hw[1], hw[2], hw[3]);
    }
  }
}

// ---------------------------------------------------------------------------
// MFMA flash attention: 64-k phases, raw-P publish, local fragment rebuild.
// 512 blocks x 256 threads; producer wave pw (also PVs).
// ---------------------------------------------------------------------------
__global__ __launch_bounds__(256, 2) void k_flash(
    const unsigned short* __restrict__ qrh,
    const char* __restrict__ krh,
    const char* __restrict__ vthi,
    float* __restrict__ ao)
{
  __shared__ __align__(16) char Ksm[32768];   // [phase&1][16KB]
  __shared__ float Praw[2][64][32];           // [buf][k][q]
  __shared__ float Slinv[32];

  const int tid = threadIdx.x;
  const int w = tid >> 6, lane = tid & 63;
  const int lrow = lane & 31, lhi = lane >> 5;

  const int phys = blockIdx.x;
  const int x = phys & 7, j = phys >> 3;
  const int bh = (x << 1) | (j >> 5);
  const int qb = j & 31;
  const int b = bh >> 3, h = bh & 7;
  const int qbase = qb * 32;
  const int pw = (phys ^ (phys >> 2) ^ (phys >> 8)) & 3;
  const bool prod = (w == pw);

  uint4 qfh[8];
  if (prod) {
    const size_t rowb = ((size_t)bh * S_ + qbase + lrow) * 128;
#pragma unroll
    for (int fs = 0; fs < 8; ++fs)
      qfh[fs] = *(const uint4*)(qrh + rowb + fs * 16 + lhi * 8);
  }

  const char* vh_c = vthi + (size_t)bh * 1048576;
  const char* kh_c = krh + (size_t)bh * 262144;

  auto issue_k = [&](int p) {                 // 16KB/phase, 4 loads/wave
    char* dh = Ksm + (p & 1) * 16384;
    const size_t g = (size_t)p * 16384;
#pragma unroll
    for (int i = 0; i < 4; ++i)
      __builtin_amdgcn_global_load_lds(kh_c + g + i * 4096 + tid * 16, dh + i * 4096 + (w << 10), 16, 0, 0);
  };

  const unsigned vbase = (unsigned)((w * 128 + lrow) * 32 + lhi * 16);
  uint4 v[4][4];                              // [ks][cf]
  auto load_v = [&](int p, int ks) {
    const size_t g = (size_t)(2 * p + (ks >> 1)) * 32768 + (size_t)(ks & 1) * 16384 + vbase;
#pragma unroll
    for (int cf = 0; cf < 4; ++cf)
      v[ks][cf] = *(const uint4*)(vh_c + g + cf * 1024);
  };

  f32x16 acc[4];
#pragma unroll
  for (int i = 0; i < 4; ++i)
#pragma unroll
    for (int r = 0; r < 16; ++r) acc[i][r] = 0.f;
  float l_run = 0.f;

  // Producer: two 32-k score tiles from Ksm[pp&1]; raw exp(s) -> Praw[pp&1][k][q].
  auto produce = [&](int pp) {
    const char* kb = Ksm + (pp & 1) * 16384;
    float rs = 0.f;
#pragma unroll
    for (int t = 0; t < 2; ++t) {
      const char* kt = kb + t * 8192;
      f32x16 s0, s1;
#pragma unroll
      for (int r = 0; r < 16; ++r) { s0[r] = 0.f; s1[r] = 0.f; }
      __builtin_amdgcn_s_setprio(1);
#pragma unroll
      for (int fs = 0; fs < 8; ++fs) {
        const unsigned kaddr = (unsigned)((lrow * 256 + fs * 32 + lhi * 16) ^ ((lrow & 7) << 4));
        U4B8 khf, qh;
        khf.u = *(const uint4*)(kt + kaddr);
        qh.u = qfh[fs];
        if (fs & 1) s1 = __builtin_amdgcn_mfma_f32_32x32x16_bf16(khf.v, qh.v, s1, 0, 0, 0);
        else        s0 = __builtin_amdgcn_mfma_f32_32x32x16_bf16(khf.v, qh.v, s0, 0, 0, 0);
      }
      __builtin_amdgcn_s_setprio(0);
#pragma unroll
      for (int r = 0; r < 16; ++r) {
        const float pv = __expf(s0[r] + s1[r]);
        rs += pv;
        const int k = t * 32 + (r & 3) + 8 * (r >> 2) + 4 * lhi;
        Praw[pp & 1][k][lrow] = pv;
      }
    }
    rs += __shfl_xor(rs, 32);
    l_run += rs;
  };

  // ---- prologue ----
  issue_k(0);                                 // 4
  issue_k(1);                                 // 4
#pragma unroll
  for (int ks = 0; ks < 4; ++ks) load_v(0, ks);   // 16
  asm volatile("s_waitcnt vmcnt(20)" ::: "memory");   // K(0) landed (all waves)
  SBAR(); MEMFENCE();
  if (prod) produce(0);
  asm volatile("s_waitcnt vmcnt(16)" ::: "memory");   // K(1) landed
  asm volatile("s_waitcnt lgkmcnt(0)" ::: "memory");
  SCHED0(); SBAR(); MEMFENCE();

  for (int p = 0; p < 16; ++p) {
    if (p < 14) { SCHED0(); issue_k(p + 2); SCHED0(); }
    if (prod && p < 15) produce(p + 1);

    // ---- all waves: PV(p) from Praw[p&1], per k-slot rebuild + MFMA ----
#pragma unroll
    for (int ks = 0; ks < 4; ++ks) {
      float pq[8];
#pragma unroll
      for (int jj = 0; jj < 8; ++jj)
        pq[jj] = Praw[p & 1][ks * 16 + lhi * 8 + jj][lrow];
      unsigned ph_[4], pl_[4];
      split8(pq, ph_, pl_);
      U4B8 pah, pal;
      pah.u = make_uint4(ph_[0], ph_[1], ph_[2], ph_[3]);
      pal.u = make_uint4(pl_[0], pl_[1], pl_[2], pl_[3]);
      __builtin_amdgcn_s_setprio(1);
#pragma unroll
      for (int cf = 0; cf < 4; ++cf) {
        U4B8 vv;
        vv.u = v[ks][cf];
        acc[cf] = __builtin_amdgcn_mfma_f32_32x32x16_bf16(pah.v, vv.v, acc[cf], 0, 0, 0);
        acc[cf] = __builtin_amdgcn_mfma_f32_32x32x16_bf16(pal.v, vv.v, acc[cf], 0, 0, 0);
      }
      __builtin_amdgcn_s_setprio(0);
      if (p < 15) load_v(p + 1, ks);
    }

    SCHED0();
    asm volatile("s_waitcnt vmcnt(16)" ::: "memory");   // drain K(p+2)
    asm volatile("s_waitcnt lgkmcnt(0)" ::: "memory");  // Praw(p+1) writes
    SBAR(); MEMFENCE();
  }

  // ---- epilogue ----
  if (prod && lane < 32) Slinv[lrow] = 1.0f / l_run;
  asm volatile("s_waitcnt lgkmcnt(0)" ::: "memory");
  SBAR(); MEMFENCE();
  float lr[16];
#pragma unroll
  for (int r = 0; r < 16; ++r)
    lr[r] = Slinv[(r & 3) + 8 * (r >> 2) + 4 * lhi];
#pragma unroll
  for (int cf = 0; cf < 4; ++cf) {
    const int c = w * 128 + cf * 32 + lrow;
    const int m = c >> 6, dd = c & 63;
#pragma unroll
    for (int r = 0; r < 16; ++r) {
      const int qr = (r & 3) + 8 * (r >> 2) + 4 * lhi;
      const int srow = qbase + qr;
      const size_t off = (((size_t)(b * S_ + srow)) * 8 + m) * 512 + h * 64 + dd;
      ao[off] = acc[cf][r] * lr[r];
    }
  }
}

// ---------------------------------------------------------------------------
// k_out MFMA (unchanged from R10).
// ---------------------------------------------------------------------------
__global__ __launch_bounds__(256) void k_out(
    const float* __restrict__ ao, const float* __restrict__ Wo,
    const float* __restrict__ Ww, const float* __restrict__ qlw,
    float* __restrict__ out)
{
  const int tid = threadIdx.x;
  const int w = tid >> 6, lane = tid & 63;
  const int lrow = lane & 31, lhi = lane >> 5;
  const int Rblk = blockIdx.x * 128;

  __shared__ __align__(16) char WoF[4][2][2][1024];
  __shared__ __align__(16) float Os[128 * 68];

  f32x16 acc[2];
#pragma unroll
  for (int i = 0; i < 2; ++i)
#pragma unroll
    for (int r = 0; r < 16; ++r) acc[i][r] = 0.f;

  const float* brow = ao + (size_t)(Rblk + w * 32 + lrow) * 512;

  for (int chunk = 0; chunk < 8; ++chunk) {
    __syncthreads();
#pragma unroll
    for (int dt = 0; dt < 2; ++dt) {
      const float* wp = Wo + (size_t)(dt * 32 + lrow) * 512 + (chunk * 4 + w) * 16 + lhi * 8;
      float v[8];
      const float4 a = *(const float4*)wp;
      const float4 b2 = *(const float4*)(wp + 4);
      v[0] = a.x; v[1] = a.y; v[2] = a.z; v[3] = a.w;
      v[4] = b2.x; v[5] = b2.y; v[6] = b2.z; v[7] = b2.w;
      unsigned hw[4], lw2[4];
      split8(v, hw, lw2);
      *(uint4*)&WoF[w][dt][0][lane * 16] = make_uint4(hw[0], hw[1], hw[2], hw[3]);
      *(uint4*)&WoF[w][dt][1][lane * 16] = make_uint4(lw2[0], lw2[1], lw2[2], lw2[3]);
    }
    __syncthreads();

#pragma unroll
    for (int kl = 0; kl < 4; ++kl) {
      float v[8];
      const float4 a = *(const float4*)(brow + (chunk * 4 + kl) * 16 + lhi * 8);
      const float4 b2 = *(const float4*)(brow + (chunk * 4 + kl) * 16 + lhi * 8 + 4);
      v[0] = a.x; v[1] = a.y; v[2] = a.z; v[3] = a.w;
      v[4] = b2.x; v[5] = b2.y; v[6] = b2.z; v[7] = b2.w;
      unsigned bhw[4], blw[4];
      split8(v, bhw, blw);
      U4B8 bh2, bl2;
      bh2.u = make_uint4(bhw[0], bhw[1], bhw[2], bhw[3]);
      bl2.u = make_uint4(blw[0], blw[1], blw[2], blw[3]);
      __builtin_amdgcn_s_setprio(1);
#pragma unroll
      for (int dt = 0; dt < 2; ++dt) {
        U4B8 ah, al;
        ah.u = *(const uint4*)&WoF[kl][dt][0][lane * 16];
        al.u = *(const uint4*)&WoF[kl][dt][1][lane * 16];
        acc[dt] = __builtin_amdgcn_mfma_f32_32x32x16_bf16(ah.v, bh2.v, acc[dt], 0, 0, 0);
        acc[dt] = __builtin_amdgcn_mfma_f32_32x32x16_bf16(al.v, bh2.v, acc[dt], 0, 0, 0);
        acc[dt] = __builtin_amdgcn_mfma_f32_32x32x16_bf16(ah.v, bl2.v, acc[dt], 0, 0, 0);
      }
      __builtin_amdgcn_s_setprio(0);
    }
  }

  __syncthreads();
#pragma unroll
  for (int dt = 0; dt < 2; ++dt)
#pragma unroll
    for (int r = 0; r < 16; ++r) {
      const int d = dt * 32 + (r & 3) + 8 * (r >> 2) + 4 * lhi;
      Os[(w * 32 + lrow) * 68 + d] = acc[dt][r];
    }
  __syncthreads();

#pragma unroll
  for (int jj = 0; jj < 8; ++jj) {
    const int i = tid + 256 * jj;
    const int r = i >> 4, c4 = (i & 15) * 4;
    const float4 v = *(const float4*)&Os[r * 68 + c4];
    *(float4*)&out[(size_t)(Rblk + r) * 64 + c4] = v;
  }

#pragma unroll
  for (int gi = 0; gi < 4; ++gi) {
    const int g = w * 4 + gi;
    float mean = 0.f;
#pragma unroll
    for (int m = 0; m < 8; ++m) mean += Os[(g * 8 + m) * 68 + lane];
    mean *= 0.125f;
    float dsel = 0.f;
#pragma unroll
    for (int mw = 0; mw < 8; ++mw) {
      float part = mean * Ww[mw * 64 + lane];
      part += __shfl_xor(part, 1);
      part += __shfl_xor(part, 2);
      part += __shfl_xor(part, 4);
      part += __shfl_xor(part, 8);
      part += __shfl_xor(part, 16);
      part += __shfl_xor(part, 32);
      if (lane == mw) dsel = part;
    }
    if (lane < 8) {
      const int idx = Rblk + g * 8 + lane;
      out[1048576 + idx] = qlw[idx] + dsel;
    }
  }
}

// ---------------------------------------------------------------------------
extern "C" void kernel_launch(void* const* d_in, const int* in_sizes, int n_in,
                              void* d_out, int out_size, void* d_ws, size_t ws_size,
                              hipStream_t stream)
{
  const float* q_atoms = (const float*)d_in[0];
  const float* q_logw  = (const float*)d_in[1];
  const float* k_atoms = (const float*)d_in[2];
  const float* k_logw  = (const float*)d_in[3];
  const float* v_atoms = (const float*)d_in[4];
  const float* cosT  = (const float*)d_in[6];
  const float* sinT  = (const float*)d_in[7];
  const float* Wq    = (const float*)d_in[8];
  const float* Wk    = (const float*)d_in[9];
  const float* Wv    = (const float*)d_in[10];
  const float* Wo    = (const float*)d_in[11];
  const float* Ww    = (const float*)d_in[12];
  const float* logbw = (const float*)d_in[13];
  const float* rffb  = (const float*)d_in[14];
  float* out = (float*)d_out;

  char* wsb = (char*)d_ws;
  char* qrh = wsb;
  char* krh = wsb + (8u << 20);
  char* vthi = wsb + (16u << 20);
  float* ao = (float*)(wsb + (48u << 20));

  const dim3 blk(256);
  k_proj_rff<<<dim3(16, 8, 4), blk, 0, stream>>>(q_atoms, q_logw, k_atoms, k_logw,
                                                 Wq, Wk, rffb, logbw, cosT, sinT,
                                                 qrh, krh);
  k_proj_v  <<<dim3(16, 8, 2), blk, 0, stream>>>(v_atoms, Wv, vthi);
  k_flash   <<<dim3(512), blk, 0, stream>>>((const unsigned short*)qrh,
                                            krh, vthi, ao);
  k_out     <<<dim3(128), blk, 0, stream>>>(ao, Wo, Ww, q_logw, out);
}

// Round 18
// 125.812 us; speedup vs baseline: 1.4138x; 1.0286x over previous
//
#include <hip/hip_runtime.h>
#include <math.h>

// KME attention. B=2 S=1024 M=8 D=64 H=8 NF=64
// Round 18:
//  - k_flash: DUAL producers with lookahead-2 (wave p&1 produces phase p+2
//    during phase p; Praw[4] rotating buffers; K dbuf unchanged). Producer
//    chain amortized over 2 phases -> per-phase critical path ~700 cyc.
//  - k_out: grid 256 (64 rows/block, wave=(row-tile,d-tile)) -> full GPU.
//  - proj_rff / proj_v unchanged from R17.
//
// ws layout (bytes), 80 MiB total:
//   qrh  @ 0MB   4MB  ushort [bh][s][128]          (natural)
//   krh  @ 8MB   4MB  swizzled-chunk layout [bh][ch=32][8192B]
//   vthi @16MB  16MB  [bh][ch=32][half=2][c=512][32B], inner=c*32+part2*16
//   ao   @48MB  32MB  f32 [b][s][m][512]

#define B_ 2
#define S_ 1024
#define H_ 8

typedef __attribute__((ext_vector_type(8))) short short8;
typedef __attribute__((ext_vector_type(16))) float f32x16;
union U4B8 { uint4 u; short8 v; };

#define SBAR() __builtin_amdgcn_s_barrier()
#define SCHED0() __builtin_amdgcn_sched_barrier(0)
#define MEMFENCE() asm volatile("" ::: "memory")

__device__ inline unsigned cvt_pk_bf16(float a, float b) {
  unsigned r;
  asm("v_cvt_pk_bf16_f32 %0, %1, %2" : "=v"(r) : "v"(a), "v"(b));
  return r;
}
__device__ inline void split8(const float* v, unsigned* hw, unsigned* lw) {
#pragma unroll
  for (int p = 0; p < 4; ++p) {
    const float a = v[2 * p], b = v[2 * p + 1];
    const unsigned h = cvt_pk_bf16(a, b);
    const float ra = a - __uint_as_float(h << 16);
    const float rb = b - __uint_as_float(h & 0xffff0000u);
    hw[p] = h;
    lw[p] = cvt_pk_bf16(ra, rb);
  }
}

// ---------------------------------------------------------------------------
// MFMA projection + RoPE + RFF encode; hi-only outputs; 2-term split GEMMs.
// (unchanged from R17)
// ---------------------------------------------------------------------------
__global__ __launch_bounds__(256, 2) void k_proj_rff(
    const float* __restrict__ q_atoms, const float* __restrict__ q_logw,
    const float* __restrict__ k_atoms, const float* __restrict__ k_logw,
    const float* __restrict__ Wq, const float* __restrict__ Wk,
    const float* __restrict__ freqb, const float* __restrict__ logbw,
    const float* __restrict__ cosT, const float* __restrict__ sinT,
    char* __restrict__ qoh, char* __restrict__ koh)
{
  const int sblk = blockIdx.x * 64;
  const int h = blockIdx.y, z = blockIdx.z;
  const int qk = z >> 1, b = z & 1;
  const float* atoms = qk ? k_atoms : q_atoms;
  const float* logw  = qk ? k_logw : q_logw;
  const float* W     = qk ? Wk : Wq;
  char* oh = qk ? koh : qoh;

  const int tid = threadIdx.x;
  const int w = tid >> 6, lane = tid & 63;
  const int lrow = lane & 31, lhi = lane >> 5;

  __shared__ float Cs[64 * 65];
  __shared__ float Sn[64 * 65];
  __shared__ float Wm[64 * 8];
  __shared__ __align__(16) char FT[2][4][2][1024];
  __shared__ __align__(16) char Ob[4][1024];

  for (int i = tid; i < 4096; i += 256) {
    const int sl = i >> 6, d = i & 63;
    Cs[sl * 65 + d] = cosT[(sblk + sl) * 64 + d];
    Sn[sl * 65 + d] = sinT[(sblk + sl) * 64 + d];
  }
  if (tid < 64) {
    const float* lw = logw + (size_t)(b * S_ + sblk + tid) * 8;
    float mx = lw[0];
    for (int m = 1; m < 8; ++m) mx = fmaxf(mx, lw[m]);
    float e[8], sum = 0.f;
    for (int m = 0; m < 8; ++m) { e[m] = __expf(lw[m] - mx); sum += e[m]; }
    const float inv = 1.0f / sum;
    for (int m = 0; m < 8; ++m) Wm[tid * 8 + m] = e[m] * inv;
  }
  const float fscale = __expf(-logbw[h]);
  {
    const int ftw = w & 1;
#pragma unroll
    for (int kk = 0; kk < 2; ++kk) {
      const int ks2 = (w >> 1) + kk * 2;
      float v[8];
#pragma unroll
      for (int j = 0; j < 8; ++j)
        v[j] = freqb[h * 4096 + (ks2 * 16 + lhi * 8 + j) * 64 + ftw * 32 + lrow] * fscale;
      unsigned hw[4], lw2[4];
      split8(v, hw, lw2);
      *(uint4*)&FT[ftw][ks2][0][lane * 16] = make_uint4(hw[0], hw[1], hw[2], hw[3]);
      *(uint4*)&FT[ftw][ks2][1][lane * 16] = make_uint4(lw2[0], lw2[1], lw2[2], lw2[3]);
    }
  }
  unsigned wAh[2][4][4], wAl[2][4][4];
#pragma unroll
  for (int wt = 0; wt < 2; ++wt)
#pragma unroll
    for (int ks = 0; ks < 4; ++ks) {
      const float* wp = W + h * 4096 + (wt * 32 + lrow) * 64 + ks * 16 + lhi * 8;
      float v[8];
      const float4 a = *(const float4*)wp;
      const float4 b2 = *(const float4*)(wp + 4);
      v[0] = a.x; v[1] = a.y; v[2] = a.z; v[3] = a.w;
      v[4] = b2.x; v[5] = b2.y; v[6] = b2.z; v[7] = b2.w;
      split8(v, wAh[wt][ks], wAl[wt][ks]);
    }
  __syncthreads();

  const int bh = b * H_ + h;
  char* obh = &Ob[w][0];

  for (int it = 0; it < 4; ++it) {
    const int t = w * 4 + it;
    const float* arow = atoms + ((size_t)(b * S_ + sblk) * 8 + t * 32 + lrow) * 64;
    unsigned aBh[4][4], aBl[4][4];
#pragma unroll
    for (int ks = 0; ks < 4; ++ks) {
      float v[8];
      const float4 a = *(const float4*)(arow + ks * 16 + lhi * 8);
      const float4 b2 = *(const float4*)(arow + ks * 16 + lhi * 8 + 4);
      v[0] = a.x; v[1] = a.y; v[2] = a.z; v[3] = a.w;
      v[4] = b2.x; v[5] = b2.y; v[6] = b2.z; v[7] = b2.w;
      split8(v, aBh[ks], aBl[ks]);
    }

    f32x16 y0, y1;
#pragma unroll
    for (int r = 0; r < 16; ++r) { y0[r] = 0.f; y1[r] = 0.f; }
    __builtin_amdgcn_s_setprio(1);
#pragma unroll
    for (int ks = 0; ks < 4; ++ks) {
      U4B8 a0h, a1h, bh2, bl2;
      a0h.u = make_uint4(wAh[0][ks][0], wAh[0][ks][1], wAh[0][ks][2], wAh[0][ks][3]);
      a1h.u = make_uint4(wAh[1][ks][0], wAh[1][ks][1], wAh[1][ks][2], wAh[1][ks][3]);
      bh2.u = make_uint4(aBh[ks][0], aBh[ks][1], aBh[ks][2], aBh[ks][3]);
      bl2.u = make_uint4(aBl[ks][0], aBl[ks][1], aBl[ks][2], aBl[ks][3]);
      y0 = __builtin_amdgcn_mfma_f32_32x32x16_bf16(a0h.v, bh2.v, y0, 0, 0, 0);
      y1 = __builtin_amdgcn_mfma_f32_32x32x16_bf16(a1h.v, bh2.v, y1, 0, 0, 0);
      y0 = __builtin_amdgcn_mfma_f32_32x32x16_bf16(a0h.v, bl2.v, y0, 0, 0, 0);
      y1 = __builtin_amdgcn_mfma_f32_32x32x16_bf16(a1h.v, bl2.v, y1, 0, 0, 0);
    }
    __builtin_amdgcn_s_setprio(0);

    const int sloc = t * 4 + (lrow >> 3);
    const int sld = sloc * 65;
    float yr0[16], yr1[16];
#pragma unroll
    for (int r = 0; r < 16; ++r) {
      const int dd = (r & 3) + 8 * (r >> 2) + 4 * lhi;
      const float c0 = Cs[sld + dd],      s0v = Sn[sld + dd];
      const float c1 = Cs[sld + dd + 32], s1v = Sn[sld + dd + 32];
      yr0[r] = y0[r] * c0 - y1[r] * s0v;
      yr1[r] = y1[r] * c1 + y0[r] * s1v;
    }

    unsigned Bh[4][4], Bl[4][4];
    {
      const float* src[2] = { yr0, yr1 };
#pragma unroll
      for (int st = 0; st < 2; ++st) {
#pragma unroll
        for (int half = 0; half < 2; ++half) {
          const int ks2 = st * 2 + half;
          const float* q = src[st] + half * 8;
          unsigned ph[4], pl[4];
          split8(q, ph, pl);
          {
            const unsigned t0 = lhi ? ph[0] : ph[2];
            const unsigned r0 = (unsigned)__shfl_xor((int)t0, 32);
            const unsigned t1 = lhi ? ph[1] : ph[3];
            const unsigned r1 = (unsigned)__shfl_xor((int)t1, 32);
            Bh[ks2][0] = lhi ? r0 : ph[0];
            Bh[ks2][1] = lhi ? r1 : ph[1];
            Bh[ks2][2] = lhi ? ph[2] : r0;
            Bh[ks2][3] = lhi ? ph[3] : r1;
          }
          {
            const unsigned t0 = lhi ? pl[0] : pl[2];
            const unsigned r0 = (unsigned)__shfl_xor((int)t0, 32);
            const unsigned t1 = lhi ? pl[1] : pl[3];
            const unsigned r1 = (unsigned)__shfl_xor((int)t1, 32);
            Bl[ks2][0] = lhi ? r0 : pl[0];
            Bl[ks2][1] = lhi ? r1 : pl[1];
            Bl[ks2][2] = lhi ? pl[2] : r0;
            Bl[ks2][3] = lhi ? pl[3] : r1;
          }
        }
      }
    }

    f32x16 d0, d1;
#pragma unroll
    for (int r = 0; r < 16; ++r) { d0[r] = 0.f; d1[r] = 0.f; }
    __builtin_amdgcn_s_setprio(1);
#pragma unroll
    for (int ks2 = 0; ks2 < 4; ++ks2) {
      U4B8 a0h, a1h, bh2, bl2;
      a0h.u = *(const uint4*)&FT[0][ks2][0][lane * 16];
      a1h.u = *(const uint4*)&FT[1][ks2][0][lane * 16];
      bh2.u = make_uint4(Bh[ks2][0], Bh[ks2][1], Bh[ks2][2], Bh[ks2][3]);
      bl2.u = make_uint4(Bl[ks2][0], Bl[ks2][1], Bl[ks2][2], Bl[ks2][3]);
      d0 = __builtin_amdgcn_mfma_f32_32x32x16_bf16(a0h.v, bh2.v, d0, 0, 0, 0);
      d1 = __builtin_amdgcn_mfma_f32_32x32x16_bf16(a1h.v, bh2.v, d1, 0, 0, 0);
      d0 = __builtin_amdgcn_mfma_f32_32x32x16_bf16(a0h.v, bl2.v, d0, 0, 0, 0);
      d1 = __builtin_amdgcn_mfma_f32_32x32x16_bf16(a1h.v, bl2.v, d1, 0, 0, 0);
    }
    __builtin_amdgcn_s_setprio(0);

    const float wt = Wm[sloc * 8 + (lrow & 7)];
    float oc[32], os[32];
#pragma unroll
    for (int r = 0; r < 32; ++r) {
      const float pr = (r < 16) ? d0[r] : d1[r - 16];
      float sv, cv;
      __sincosf(pr, &sv, &cv);
      oc[r] = wt * cv;
      os[r] = wt * sv;
    }
#pragma unroll
    for (int r = 0; r < 32; ++r) {
      oc[r] += __shfl_xor(oc[r], 1); os[r] += __shfl_xor(os[r], 1);
      oc[r] += __shfl_xor(oc[r], 2); os[r] += __shfl_xor(os[r], 2);
      oc[r] += __shfl_xor(oc[r], 4); os[r] += __shfl_xor(os[r], 4);
    }

    const int m = lrow & 7, srel = lrow >> 3;
#pragma unroll
    for (int rr2 = 0; rr2 < 4; ++rr2) {
      const int r = m * 4 + rr2;
      const int f = (r & 3) + 8 * ((r >> 2) & 3) + 4 * lhi + ((r >> 4) << 5);
      *(unsigned short*)(obh + srel * 256 + f * 2) =
          (unsigned short)cvt_pk_bf16(oc[r] * 0.125f, 0.f);
      *(unsigned short*)(obh + srel * 256 + 128 + f * 2) =
          (unsigned short)cvt_pk_bf16(os[r] * 0.125f, 0.f);
    }
    const uint4 vh = *(const uint4*)(obh + lane * 16);
    const int srow = sblk + t * 4 + (lane >> 4);
    if (!qk) {
      const size_t off = ((size_t)bh * S_ + srow) * 256 + (lane & 15) * 16;
      *(uint4*)(oh + off) = vh;
    } else {
      const int klr = srow & 31, ch = srow >> 5;
      const unsigned inner = (unsigned)(((klr << 8) + (lane & 15) * 16) ^ ((klr & 7) << 4));
      const size_t off = (size_t)bh * 262144 + (size_t)ch * 8192 + inner;
      *(uint4*)(oh + off) = vh;
    }
  }
}

// ---------------------------------------------------------------------------
// V projection, MFMA; hi plane only (unchanged from R17).
// ---------------------------------------------------------------------------
__global__ __launch_bounds__(256) void k_proj_v(
    const float* __restrict__ atoms, const float* __restrict__ W,
    char* __restrict__ vthi)
{
  const int sblk = blockIdx.x * 64;
  const int h = blockIdx.y, b = blockIdx.z;
  const int tid = threadIdx.x;
  const int w = tid >> 6, lane = tid & 63;
  const int lrow = lane & 31, lhi = lane >> 5;

  __shared__ __align__(16) float T[4][8 * 520];

  unsigned wAh[2][4][4], wAl[2][4][4];
#pragma unroll
  for (int wt = 0; wt < 2; ++wt)
#pragma unroll
    for (int ks = 0; ks < 4; ++ks) {
      const float* wp = W + h * 4096 + (wt * 32 + lrow) * 64 + ks * 16 + lhi * 8;
      float v[8];
      const float4 a = *(const float4*)wp;
      const float4 b2 = *(const float4*)(wp + 4);
      v[0] = a.x; v[1] = a.y; v[2] = a.z; v[3] = a.w;
      v[4] = b2.x; v[5] = b2.y; v[6] = b2.z; v[7] = b2.w;
      split8(v, wAh[wt][ks], wAl[wt][ks]);
    }

  const int bh = b * H_ + h;
  float* Tw = &T[w][0];

  for (int p = 0; p < 2; ++p) {
#pragma unroll
    for (int half8 = 0; half8 < 2; ++half8) {
      const int t = w * 4 + p * 2 + half8;
      const float* arow = atoms + ((size_t)(b * S_ + sblk) * 8 + t * 32 + lrow) * 64;
      unsigned aBh[4][4], aBl[4][4];
#pragma unroll
      for (int ks = 0; ks < 4; ++ks) {
        float v[8];
        const float4 a = *(const float4*)(arow + ks * 16 + lhi * 8);
        const float4 b2 = *(const float4*)(arow + ks * 16 + lhi * 8 + 4);
        v[0] = a.x; v[1] = a.y; v[2] = a.z; v[3] = a.w;
        v[4] = b2.x; v[5] = b2.y; v[6] = b2.z; v[7] = b2.w;
        split8(v, aBh[ks], aBl[ks]);
      }

      f32x16 y0, y1;
#pragma unroll
      for (int r = 0; r < 16; ++r) { y0[r] = 0.f; y1[r] = 0.f; }
      __builtin_amdgcn_s_setprio(1);
#pragma unroll
      for (int ks = 0; ks < 4; ++ks) {
        U4B8 a0h, a0l, a1h, a1l, bh2, bl2;
        a0h.u = make_uint4(wAh[0][ks][0], wAh[0][ks][1], wAh[0][ks][2], wAh[0][ks][3]);
        a0l.u = make_uint4(wAl[0][ks][0], wAl[0][ks][1], wAl[0][ks][2], wAl[0][ks][3]);
        a1h.u = make_uint4(wAh[1][ks][0], wAh[1][ks][1], wAh[1][ks][2], wAh[1][ks][3]);
        a1l.u = make_uint4(wAl[1][ks][0], wAl[1][ks][1], wAl[1][ks][2], wAl[1][ks][3]);
        bh2.u = make_uint4(aBh[ks][0], aBh[ks][1], aBh[ks][2], aBh[ks][3]);
        bl2.u = make_uint4(aBl[ks][0], aBl[ks][1], aBl[ks][2], aBl[ks][3]);
        y0 = __builtin_amdgcn_mfma_f32_32x32x16_bf16(a0h.v, bh2.v, y0, 0, 0, 0);
        y1 = __builtin_amdgcn_mfma_f32_32x32x16_bf16(a1h.v, bh2.v, y1, 0, 0, 0);
        y0 = __builtin_amdgcn_mfma_f32_32x32x16_bf16(a0l.v, bh2.v, y0, 0, 0, 0);
        y1 = __builtin_amdgcn_mfma_f32_32x32x16_bf16(a1l.v, bh2.v, y1, 0, 0, 0);
        y0 = __builtin_amdgcn_mfma_f32_32x32x16_bf16(a0h.v, bl2.v, y0, 0, 0, 0);
        y1 = __builtin_amdgcn_mfma_f32_32x32x16_bf16(a1h.v, bl2.v, y1, 0, 0, 0);
      }
      __builtin_amdgcn_s_setprio(0);

      const int s_in = half8 * 4 + (lrow >> 3);
      const int m = lrow & 7;
#pragma unroll
      for (int r = 0; r < 16; ++r) {
        const int dd = (r & 3) + 8 * (r >> 2) + 4 * lhi;
        Tw[s_in * 520 + m * 64 + dd] = y0[r];
        Tw[s_in * 520 + m * 64 + dd + 32] = y1[r];
      }
    }
    const int s0 = sblk + w * 16 + p * 8;
    const int ch = s0 >> 5, half = (s0 >> 4) & 1, part2 = (s0 >> 3) & 1;
    const size_t base = (size_t)bh * 1048576 + (size_t)ch * 32768 + half * 16384;
#pragma unroll
    for (int j = 0; j < 8; ++j) {
      const int c = j * 64 + lane;
      float v[8];
#pragma unroll
      for (int s = 0; s < 8; ++s) v[s] = Tw[s * 520 + c];
      unsigned hw[4];
#pragma unroll
      for (int pq = 0; pq < 4; ++pq)
        hw[pq] = cvt_pk_bf16(v[2 * pq], v[2 * pq + 1]);
      const unsigned inner = (unsigned)(c * 32 + part2 * 16);
      *(uint4*)(vthi + base + inner) = make_uint4(hw[0], hw[1], hw[2], hw[3]);
    }
  }
}

// ---------------------------------------------------------------------------
// MFMA flash attention: 64-k phases, DUAL producers lookahead-2.
// During phase p, wave (p&1) produces phase p+2 into Praw[(p+2)&3];
// all 4 waves PV(p) from Praw[p&3]. K dbuf: phase p issues K(p+3).
// ---------------------------------------------------------------------------
__global__ __launch_bounds__(256, 2) void k_flash(
    const unsigned short* __restrict__ qrh,
    const char* __restrict__ krh,
    const char* __restrict__ vthi,
    float* __restrict__ ao)
{
  __shared__ __align__(16) char Ksm[32768];   // K dbuf [2][16KB]
  __shared__ float Praw[4][64][32];           // [p&3][k][q]  32KB
  __shared__ float Slv[2][32];

  const int tid = threadIdx.x;
  const int w = tid >> 6, lane = tid & 63;
  const int lrow = lane & 31, lhi = lane >> 5;

  const int phys = blockIdx.x;
  const int x = phys & 7, j = phys >> 3;
  const int bh = (x << 1) | (j >> 5);
  const int qb = j & 31;
  const int b = bh >> 3, h = bh & 7;
  const int qbase = qb * 32;
  const bool isprod = (w < 2);                // w0 -> even target phases, w1 -> odd

  uint4 qfh[8];
  if (isprod) {
    const size_t rowb = ((size_t)bh * S_ + qbase + lrow) * 128;
#pragma unroll
    for (int fs = 0; fs < 8; ++fs)
      qfh[fs] = *(const uint4*)(qrh + rowb + fs * 16 + lhi * 8);
  }

  const char* vh_c = vthi + (size_t)bh * 1048576;
  const char* kh_c = krh + (size_t)bh * 262144;

  auto issue_k = [&](int p) {                 // K(p) -> Ksm[p&1], 4 loads/wave
    char* dh = Ksm + (p & 1) * 16384;
    const size_t g = (size_t)p * 16384;
#pragma unroll
    for (int i = 0; i < 4; ++i)
      __builtin_amdgcn_global_load_lds(kh_c + g + i * 4096 + tid * 16, dh + i * 4096 + (w << 10), 16, 0, 0);
  };

  const unsigned vbase = (unsigned)((w * 128 + lrow) * 32 + lhi * 16);
  uint4 v[4][4];                              // [ks][cf]
  auto load_v = [&](int p, int ks) {
    const size_t g = (size_t)(2 * p + (ks >> 1)) * 32768 + (size_t)(ks & 1) * 16384 + vbase;
#pragma unroll
    for (int cf = 0; cf < 4; ++cf)
      v[ks][cf] = *(const uint4*)(vh_c + g + cf * 1024);
  };

  f32x16 acc[4];
#pragma unroll
  for (int i = 0; i < 4; ++i)
#pragma unroll
    for (int r = 0; r < 16; ++r) acc[i][r] = 0.f;
  float l_run = 0.f;

  // Producer: scores for phase pp from Ksm[pp&1]; raw exp(s) -> Praw[pp&3].
  auto produce = [&](int pp) {
    const char* kb = Ksm + (pp & 1) * 16384;
    float rs = 0.f;
#pragma unroll
    for (int t = 0; t < 2; ++t) {
      const char* kt = kb + t * 8192;
      f32x16 s0, s1;
#pragma unroll
      for (int r = 0; r < 16; ++r) { s0[r] = 0.f; s1[r] = 0.f; }
      __builtin_amdgcn_s_setprio(1);
#pragma unroll
      for (int fs = 0; fs < 8; ++fs) {
        const unsigned kaddr = (unsigned)((lrow * 256 + fs * 32 + lhi * 16) ^ ((lrow & 7) << 4));
        U4B8 khf, qh;
        khf.u = *(const uint4*)(kt + kaddr);
        qh.u = qfh[fs];
        if (fs & 1) s1 = __builtin_amdgcn_mfma_f32_32x32x16_bf16(khf.v, qh.v, s1, 0, 0, 0);
        else        s0 = __builtin_amdgcn_mfma_f32_32x32x16_bf16(khf.v, qh.v, s0, 0, 0, 0);
      }
      __builtin_amdgcn_s_setprio(0);
#pragma unroll
      for (int r = 0; r < 16; ++r) {
        const float pv = __expf(s0[r] + s1[r]);
        rs += pv;
        const int k = t * 32 + (r & 3) + 8 * (r >> 2) + 4 * lhi;
        Praw[pp & 3][k][lrow] = pv;
      }
    }
    rs += __shfl_xor(rs, 32);
    l_run += rs;
  };

  // ---- prologue ----
  issue_k(0);                                 // buf0, 4 quads
  issue_k(1);                                 // buf1, 4 quads
#pragma unroll
  for (int ks = 0; ks < 4; ++ks) load_v(0, ks);   // 16 V loads
  asm volatile("s_waitcnt vmcnt(16)" ::: "memory");   // K0,K1 landed
  SBAR(); MEMFENCE();
  if (w == 0) produce(0);                     // reads buf0 -> Praw[0]
  if (w == 1) produce(1);                     // reads buf1 -> Praw[1]
  asm volatile("s_waitcnt lgkmcnt(0)" ::: "memory");
  SCHED0(); SBAR(); MEMFENCE();
  issue_k(2);                                 // buf0 (free after produce(0))

  for (int p = 0; p < 16; ++p) {
    if (p <= 12) { SCHED0(); issue_k(p + 3); SCHED0(); }

    if (p <= 13 && w == (p & 1)) {
      if (p == 0) { asm volatile("s_waitcnt vmcnt(4)" ::: "memory"); }  // K2 landed
      produce(p + 2);                          // reads Ksm[p&1], writes Praw[(p+2)&3]
    }

    // ---- all waves: PV(p) from Praw[p&3] ----
#pragma unroll
    for (int ks = 0; ks < 4; ++ks) {
      float pq[8];
#pragma unroll
      for (int jj = 0; jj < 8; ++jj)
        pq[jj] = Praw[p & 3][ks * 16 + lhi * 8 + jj][lrow];
      unsigned ph_[4], pl_[4];
      split8(pq, ph_, pl_);
      U4B8 pah, pal;
      pah.u = make_uint4(ph_[0], ph_[1], ph_[2], ph_[3]);
      pal.u = make_uint4(pl_[0], pl_[1], pl_[2], pl_[3]);
      __builtin_amdgcn_s_setprio(1);
#pragma unroll
      for (int cf = 0; cf < 4; ++cf) {
        U4B8 vv;
        vv.u = v[ks][cf];
        acc[cf] = __builtin_amdgcn_mfma_f32_32x32x16_bf16(pah.v, vv.v, acc[cf], 0, 0, 0);
        acc[cf] = __builtin_amdgcn_mfma_f32_32x32x16_bf16(pal.v, vv.v, acc[cf], 0, 0, 0);
      }
      __builtin_amdgcn_s_setprio(0);
      if (p <= 14) load_v(p + 1, ks);
    }

    SCHED0();
    asm volatile("s_waitcnt vmcnt(16)" ::: "memory");   // drain this phase's K issue
    asm volatile("s_waitcnt lgkmcnt(0)" ::: "memory");  // producer P writes
    SBAR(); MEMFENCE();
  }

  // ---- epilogue ----
  if (isprod && lane < 32) Slv[w][lrow] = l_run;
  asm volatile("s_waitcnt lgkmcnt(0)" ::: "memory");
  SBAR(); MEMFENCE();
  float lr[16];
#pragma unroll
  for (int r = 0; r < 16; ++r) {
    const int q = (r & 3) + 8 * (r >> 2) + 4 * lhi;
    lr[r] = 1.0f / (Slv[0][q] + Slv[1][q]);
  }
#pragma unroll
  for (int cf = 0; cf < 4; ++cf) {
    const int c = w * 128 + cf * 32 + lrow;
    const int m = c >> 6, dd = c & 63;
#pragma unroll
    for (int r = 0; r < 16; ++r) {
      const int qr = (r & 3) + 8 * (r >> 2) + 4 * lhi;
      const int srow = qbase + qr;
      const size_t off = (((size_t)(b * S_ + srow)) * 8 + m) * 512 + h * 64 + dd;
      ao[off] = acc[cf][r] * lr[r];
    }
  }
}

// ---------------------------------------------------------------------------
// k_out MFMA: 256 blocks x 64 rows; wave = (row-tile w&1, d-tile w>>1).
// ---------------------------------------------------------------------------
__global__ __launch_bounds__(256) void k_out(
    const float* __restrict__ ao, const float* __restrict__ Wo,
    const float* __restrict__ Ww, const float* __restrict__ qlw,
    float* __restrict__ out)
{
  const int tid = threadIdx.x;
  const int w = tid >> 6, lane = tid & 63;
  const int lrow = lane & 31, lhi = lane >> 5;
  const int Rblk = blockIdx.x * 64;
  const int rt = w & 1, dt = w >> 1;

  __shared__ __align__(16) char WoF[4][2][2][1024];
  __shared__ __align__(16) float Os[64 * 68];

  f32x16 acc;
#pragma unroll
  for (int r = 0; r < 16; ++r) acc[r] = 0.f;

  const float* brow = ao + (size_t)(Rblk + rt * 32 + lrow) * 512;

  for (int chunk = 0; chunk < 8; ++chunk) {
    __syncthreads();
#pragma unroll
    for (int dtt = 0; dtt < 2; ++dtt) {
      const float* wp = Wo + (size_t)(dtt * 32 + lrow) * 512 + (chunk * 4 + w) * 16 + lhi * 8;
      float v[8];
      const float4 a = *(const float4*)wp;
      const float4 b2 = *(const float4*)(wp + 4);
      v[0] = a.x; v[1] = a.y; v[2] = a.z; v[3] = a.w;
      v[4] = b2.x; v[5] = b2.y; v[6] = b2.z; v[7] = b2.w;
      unsigned hw[4], lw2[4];
      split8(v, hw, lw2);
      *(uint4*)&WoF[w][dtt][0][lane * 16] = make_uint4(hw[0], hw[1], hw[2], hw[3]);
      *(uint4*)&WoF[w][dtt][1][lane * 16] = make_uint4(lw2[0], lw2[1], lw2[2], lw2[3]);
    }
    __syncthreads();

#pragma unroll
    for (int kl = 0; kl < 4; ++kl) {
      float v[8];
      const float4 a = *(const float4*)(brow + (chunk * 4 + kl) * 16 + lhi * 8);
      const float4 b2 = *(const float4*)(brow + (chunk * 4 + kl) * 16 + lhi * 8 + 4);
      v[0] = a.x; v[1] = a.y; v[2] = a.z; v[3] = a.w;
      v[4] = b2.x; v[5] = b2.y; v[6] = b2.z; v[7] = b2.w;
      unsigned bhw[4], blw[4];
      split8(v, bhw, blw);
      U4B8 bh2, bl2;
      bh2.u = make_uint4(bhw[0], bhw[1], bhw[2], bhw[3]);
      bl2.u = make_uint4(blw[0], blw[1], blw[2], blw[3]);
      U4B8 ah, al;
      ah.u = *(const uint4*)&WoF[kl][dt][0][lane * 16];
      al.u = *(const uint4*)&WoF[kl][dt][1][lane * 16];
      __builtin_amdgcn_s_setprio(1);
      acc = __builtin_amdgcn_mfma_f32_32x32x16_bf16(ah.v, bh2.v, acc, 0, 0, 0);
      acc = __builtin_amdgcn_mfma_f32_32x32x16_bf16(al.v, bh2.v, acc, 0, 0, 0);
      acc = __builtin_amdgcn_mfma_f32_32x32x16_bf16(ah.v, bl2.v, acc, 0, 0, 0);
      __builtin_amdgcn_s_setprio(0);
    }
  }

  __syncthreads();
#pragma unroll
  for (int r = 0; r < 16; ++r) {
    const int d = dt * 32 + (r & 3) + 8 * (r >> 2) + 4 * lhi;
    Os[(rt * 32 + lrow) * 68 + d] = acc[r];
  }
  __syncthreads();

#pragma unroll
  for (int jj = 0; jj < 4; ++jj) {
    const int i = tid + 256 * jj;
    const int r = i >> 4, c4 = (i & 15) * 4;
    const float4 vv = *(const float4*)&Os[r * 68 + c4];
    *(float4*)&out[(size_t)(Rblk + r) * 64 + c4] = vv;
  }

#pragma unroll
  for (int gi = 0; gi < 2; ++gi) {
    const int g = w * 2 + gi;
    float mean = 0.f;
#pragma unroll
    for (int m = 0; m < 8; ++m) mean += Os[(g * 8 + m) * 68 + lane];
    mean *= 0.125f;
    float dsel = 0.f;
#pragma unroll
    for (int mw = 0; mw < 8; ++mw) {
      float part = mean * Ww[mw * 64 + lane];
      part += __shfl_xor(part, 1);
      part += __shfl_xor(part, 2);
      part += __shfl_xor(part, 4);
      part += __shfl_xor(part, 8);
      part += __shfl_xor(part, 16);
      part += __shfl_xor(part, 32);
      if (lane == mw) dsel = part;
    }
    if (lane < 8) {
      const int idx = Rblk + g * 8 + lane;
      out[1048576 + idx] = qlw[idx] + dsel;
    }
  }
}

// ---------------------------------------------------------------------------
extern "C" void kernel_launch(void* const* d_in, const int* in_sizes, int n_in,
                              void* d_out, int out_size, void* d_ws, size_t ws_size,
                              hipStream_t stream)
{
  const float* q_atoms = (const float*)d_in[0];
  const float* q_logw  = (const float*)d_in[1];
  const float* k_atoms = (const float*)d_in[2];
  const float* k_logw  = (const float*)d_in[3];
  const float* v_atoms = (const float*)d_in[4];
  const float* cosT  = (const float*)d_in[6];
  const float* sinT  = (const float*)d_in[7];
  const float* Wq    = (const float*)d_in[8];
  const float* Wk    = (const float*)d_in[9];
  const float* Wv    = (const float*)d_in[10];
  const float* Wo    = (const float*)d_in[11];
  const float* Ww    = (const float*)d_in[12];
  const float* logbw = (const float*)d_in[13];
  const float* rffb  = (const float*)d_in[14];
  float* out = (float*)d_out;

  char* wsb = (char*)d_ws;
  char* qrh = wsb;
  char* krh = wsb + (8u << 20);
  char* vthi = wsb + (16u << 20);
  float* ao = (float*)(wsb + (48u << 20));

  const dim3 blk(256);
  k_proj_rff<<<dim3(16, 8, 4), blk, 0, stream>>>(q_atoms, q_logw, k_atoms, k_logw,
                                                 Wq, Wk, rffb, logbw, cosT, sinT,
                                                 qrh, krh);
  k_proj_v  <<<dim3(16, 8, 2), blk, 0, stream>>>(v_atoms, Wv, vthi);
  k_flash   <<<dim3(512), blk, 0, stream>>>((const unsigned short*)qrh,
                                            krh, vthi, ao);
  k_out     <<<dim3(256), blk, 0, stream>>>(ao, Wo, Ww, q_logw, out);
}

// Round 19
// 116.123 us; speedup vs baseline: 1.5318x; 1.0834x over previous
//
#include <hip/hip_runtime.h>
#include <math.h>

// KME attention. B=2 S=1024 M=8 D=64 H=8 NF=64
// Round 19 (on R18): PV single-term — P quantized to bf16 hi only (l_run
// stays exact f32 -> normalized-weight error ~2e-4, negligible vs the
// 7.8e-3 V-quant floor). PV MFMAs halved (64/phase/block). All else = R18.
//
// ws layout (bytes), 80 MiB total:
//   qrh  @ 0MB   4MB  ushort [bh][s][128]          (natural)
//   krh  @ 8MB   4MB  swizzled-chunk layout [bh][ch=32][8192B]
//   vthi @16MB  16MB  [bh][ch=32][half=2][c=512][32B], inner=c*32+part2*16
//   ao   @48MB  32MB  f32 [b][s][m][512]

#define B_ 2
#define S_ 1024
#define H_ 8

typedef __attribute__((ext_vector_type(8))) short short8;
typedef __attribute__((ext_vector_type(16))) float f32x16;
union U4B8 { uint4 u; short8 v; };

#define SBAR() __builtin_amdgcn_s_barrier()
#define SCHED0() __builtin_amdgcn_sched_barrier(0)
#define MEMFENCE() asm volatile("" ::: "memory")

__device__ inline unsigned cvt_pk_bf16(float a, float b) {
  unsigned r;
  asm("v_cvt_pk_bf16_f32 %0, %1, %2" : "=v"(r) : "v"(a), "v"(b));
  return r;
}
__device__ inline void split8(const float* v, unsigned* hw, unsigned* lw) {
#pragma unroll
  for (int p = 0; p < 4; ++p) {
    const float a = v[2 * p], b = v[2 * p + 1];
    const unsigned h = cvt_pk_bf16(a, b);
    const float ra = a - __uint_as_float(h << 16);
    const float rb = b - __uint_as_float(h & 0xffff0000u);
    hw[p] = h;
    lw[p] = cvt_pk_bf16(ra, rb);
  }
}

// ---------------------------------------------------------------------------
// MFMA projection + RoPE + RFF encode; hi-only outputs; 2-term split GEMMs.
// (unchanged from R17/R18)
// ---------------------------------------------------------------------------
__global__ __launch_bounds__(256, 2) void k_proj_rff(
    const float* __restrict__ q_atoms, const float* __restrict__ q_logw,
    const float* __restrict__ k_atoms, const float* __restrict__ k_logw,
    const float* __restrict__ Wq, const float* __restrict__ Wk,
    const float* __restrict__ freqb, const float* __restrict__ logbw,
    const float* __restrict__ cosT, const float* __restrict__ sinT,
    char* __restrict__ qoh, char* __restrict__ koh)
{
  const int sblk = blockIdx.x * 64;
  const int h = blockIdx.y, z = blockIdx.z;
  const int qk = z >> 1, b = z & 1;
  const float* atoms = qk ? k_atoms : q_atoms;
  const float* logw  = qk ? k_logw : q_logw;
  const float* W     = qk ? Wk : Wq;
  char* oh = qk ? koh : qoh;

  const int tid = threadIdx.x;
  const int w = tid >> 6, lane = tid & 63;
  const int lrow = lane & 31, lhi = lane >> 5;

  __shared__ float Cs[64 * 65];
  __shared__ float Sn[64 * 65];
  __shared__ float Wm[64 * 8];
  __shared__ __align__(16) char FT[2][4][2][1024];
  __shared__ __align__(16) char Ob[4][1024];

  for (int i = tid; i < 4096; i += 256) {
    const int sl = i >> 6, d = i & 63;
    Cs[sl * 65 + d] = cosT[(sblk + sl) * 64 + d];
    Sn[sl * 65 + d] = sinT[(sblk + sl) * 64 + d];
  }
  if (tid < 64) {
    const float* lw = logw + (size_t)(b * S_ + sblk + tid) * 8;
    float mx = lw[0];
    for (int m = 1; m < 8; ++m) mx = fmaxf(mx, lw[m]);
    float e[8], sum = 0.f;
    for (int m = 0; m < 8; ++m) { e[m] = __expf(lw[m] - mx); sum += e[m]; }
    const float inv = 1.0f / sum;
    for (int m = 0; m < 8; ++m) Wm[tid * 8 + m] = e[m] * inv;
  }
  const float fscale = __expf(-logbw[h]);
  {
    const int ftw = w & 1;
#pragma unroll
    for (int kk = 0; kk < 2; ++kk) {
      const int ks2 = (w >> 1) + kk * 2;
      float v[8];
#pragma unroll
      for (int j = 0; j < 8; ++j)
        v[j] = freqb[h * 4096 + (ks2 * 16 + lhi * 8 + j) * 64 + ftw * 32 + lrow] * fscale;
      unsigned hw[4], lw2[4];
      split8(v, hw, lw2);
      *(uint4*)&FT[ftw][ks2][0][lane * 16] = make_uint4(hw[0], hw[1], hw[2], hw[3]);
      *(uint4*)&FT[ftw][ks2][1][lane * 16] = make_uint4(lw2[0], lw2[1], lw2[2], lw2[3]);
    }
  }
  unsigned wAh[2][4][4], wAl[2][4][4];
#pragma unroll
  for (int wt = 0; wt < 2; ++wt)
#pragma unroll
    for (int ks = 0; ks < 4; ++ks) {
      const float* wp = W + h * 4096 + (wt * 32 + lrow) * 64 + ks * 16 + lhi * 8;
      float v[8];
      const float4 a = *(const float4*)wp;
      const float4 b2 = *(const float4*)(wp + 4);
      v[0] = a.x; v[1] = a.y; v[2] = a.z; v[3] = a.w;
      v[4] = b2.x; v[5] = b2.y; v[6] = b2.z; v[7] = b2.w;
      split8(v, wAh[wt][ks], wAl[wt][ks]);
    }
  __syncthreads();

  const int bh = b * H_ + h;
  char* obh = &Ob[w][0];

  for (int it = 0; it < 4; ++it) {
    const int t = w * 4 + it;
    const float* arow = atoms + ((size_t)(b * S_ + sblk) * 8 + t * 32 + lrow) * 64;
    unsigned aBh[4][4], aBl[4][4];
#pragma unroll
    for (int ks = 0; ks < 4; ++ks) {
      float v[8];
      const float4 a = *(const float4*)(arow + ks * 16 + lhi * 8);
      const float4 b2 = *(const float4*)(arow + ks * 16 + lhi * 8 + 4);
      v[0] = a.x; v[1] = a.y; v[2] = a.z; v[3] = a.w;
      v[4] = b2.x; v[5] = b2.y; v[6] = b2.z; v[7] = b2.w;
      split8(v, aBh[ks], aBl[ks]);
    }

    f32x16 y0, y1;
#pragma unroll
    for (int r = 0; r < 16; ++r) { y0[r] = 0.f; y1[r] = 0.f; }
    __builtin_amdgcn_s_setprio(1);
#pragma unroll
    for (int ks = 0; ks < 4; ++ks) {
      U4B8 a0h, a1h, bh2, bl2;
      a0h.u = make_uint4(wAh[0][ks][0], wAh[0][ks][1], wAh[0][ks][2], wAh[0][ks][3]);
      a1h.u = make_uint4(wAh[1][ks][0], wAh[1][ks][1], wAh[1][ks][2], wAh[1][ks][3]);
      bh2.u = make_uint4(aBh[ks][0], aBh[ks][1], aBh[ks][2], aBh[ks][3]);
      bl2.u = make_uint4(aBl[ks][0], aBl[ks][1], aBl[ks][2], aBl[ks][3]);
      y0 = __builtin_amdgcn_mfma_f32_32x32x16_bf16(a0h.v, bh2.v, y0, 0, 0, 0);
      y1 = __builtin_amdgcn_mfma_f32_32x32x16_bf16(a1h.v, bh2.v, y1, 0, 0, 0);
      y0 = __builtin_amdgcn_mfma_f32_32x32x16_bf16(a0h.v, bl2.v, y0, 0, 0, 0);
      y1 = __builtin_amdgcn_mfma_f32_32x32x16_bf16(a1h.v, bl2.v, y1, 0, 0, 0);
    }
    __builtin_amdgcn_s_setprio(0);

    const int sloc = t * 4 + (lrow >> 3);
    const int sld = sloc * 65;
    float yr0[16], yr1[16];
#pragma unroll
    for (int r = 0; r < 16; ++r) {
      const int dd = (r & 3) + 8 * (r >> 2) + 4 * lhi;
      const float c0 = Cs[sld + dd],      s0v = Sn[sld + dd];
      const float c1 = Cs[sld + dd + 32], s1v = Sn[sld + dd + 32];
      yr0[r] = y0[r] * c0 - y1[r] * s0v;
      yr1[r] = y1[r] * c1 + y0[r] * s1v;
    }

    unsigned Bh[4][4], Bl[4][4];
    {
      const float* src[2] = { yr0, yr1 };
#pragma unroll
      for (int st = 0; st < 2; ++st) {
#pragma unroll
        for (int half = 0; half < 2; ++half) {
          const int ks2 = st * 2 + half;
          const float* q = src[st] + half * 8;
          unsigned ph[4], pl[4];
          split8(q, ph, pl);
          {
            const unsigned t0 = lhi ? ph[0] : ph[2];
            const unsigned r0 = (unsigned)__shfl_xor((int)t0, 32);
            const unsigned t1 = lhi ? ph[1] : ph[3];
            const unsigned r1 = (unsigned)__shfl_xor((int)t1, 32);
            Bh[ks2][0] = lhi ? r0 : ph[0];
            Bh[ks2][1] = lhi ? r1 : ph[1];
            Bh[ks2][2] = lhi ? ph[2] : r0;
            Bh[ks2][3] = lhi ? ph[3] : r1;
          }
          {
            const unsigned t0 = lhi ? pl[0] : pl[2];
            const unsigned r0 = (unsigned)__shfl_xor((int)t0, 32);
            const unsigned t1 = lhi ? pl[1] : pl[3];
            const unsigned r1 = (unsigned)__shfl_xor((int)t1, 32);
            Bl[ks2][0] = lhi ? r0 : pl[0];
            Bl[ks2][1] = lhi ? r1 : pl[1];
            Bl[ks2][2] = lhi ? pl[2] : r0;
            Bl[ks2][3] = lhi ? pl[3] : r1;
          }
        }
      }
    }

    f32x16 d0, d1;
#pragma unroll
    for (int r = 0; r < 16; ++r) { d0[r] = 0.f; d1[r] = 0.f; }
    __builtin_amdgcn_s_setprio(1);
#pragma unroll
    for (int ks2 = 0; ks2 < 4; ++ks2) {
      U4B8 a0h, a1h, bh2, bl2;
      a0h.u = *(const uint4*)&FT[0][ks2][0][lane * 16];
      a1h.u = *(const uint4*)&FT[1][ks2][0][lane * 16];
      bh2.u = make_uint4(Bh[ks2][0], Bh[ks2][1], Bh[ks2][2], Bh[ks2][3]);
      bl2.u = make_uint4(Bl[ks2][0], Bl[ks2][1], Bl[ks2][2], Bl[ks2][3]);
      d0 = __builtin_amdgcn_mfma_f32_32x32x16_bf16(a0h.v, bh2.v, d0, 0, 0, 0);
      d1 = __builtin_amdgcn_mfma_f32_32x32x16_bf16(a1h.v, bh2.v, d1, 0, 0, 0);
      d0 = __builtin_amdgcn_mfma_f32_32x32x16_bf16(a0h.v, bl2.v, d0, 0, 0, 0);
      d1 = __builtin_amdgcn_mfma_f32_32x32x16_bf16(a1h.v, bl2.v, d1, 0, 0, 0);
    }
    __builtin_amdgcn_s_setprio(0);

    const float wt = Wm[sloc * 8 + (lrow & 7)];
    float oc[32], os[32];
#pragma unroll
    for (int r = 0; r < 32; ++r) {
      const float pr = (r < 16) ? d0[r] : d1[r - 16];
      float sv, cv;
      __sincosf(pr, &sv, &cv);
      oc[r] = wt * cv;
      os[r] = wt * sv;
    }
#pragma unroll
    for (int r = 0; r < 32; ++r) {
      oc[r] += __shfl_xor(oc[r], 1); os[r] += __shfl_xor(os[r], 1);
      oc[r] += __shfl_xor(oc[r], 2); os[r] += __shfl_xor(os[r], 2);
      oc[r] += __shfl_xor(oc[r], 4); os[r] += __shfl_xor(os[r], 4);
    }

    const int m = lrow & 7, srel = lrow >> 3;
#pragma unroll
    for (int rr2 = 0; rr2 < 4; ++rr2) {
      const int r = m * 4 + rr2;
      const int f = (r & 3) + 8 * ((r >> 2) & 3) + 4 * lhi + ((r >> 4) << 5);
      *(unsigned short*)(obh + srel * 256 + f * 2) =
          (unsigned short)cvt_pk_bf16(oc[r] * 0.125f, 0.f);
      *(unsigned short*)(obh + srel * 256 + 128 + f * 2) =
          (unsigned short)cvt_pk_bf16(os[r] * 0.125f, 0.f);
    }
    const uint4 vh = *(const uint4*)(obh + lane * 16);
    const int srow = sblk + t * 4 + (lane >> 4);
    if (!qk) {
      const size_t off = ((size_t)bh * S_ + srow) * 256 + (lane & 15) * 16;
      *(uint4*)(oh + off) = vh;
    } else {
      const int klr = srow & 31, ch = srow >> 5;
      const unsigned inner = (unsigned)(((klr << 8) + (lane & 15) * 16) ^ ((klr & 7) << 4));
      const size_t off = (size_t)bh * 262144 + (size_t)ch * 8192 + inner;
      *(uint4*)(oh + off) = vh;
    }
  }
}

// ---------------------------------------------------------------------------
// V projection, MFMA; hi plane only (unchanged).
// ---------------------------------------------------------------------------
__global__ __launch_bounds__(256) void k_proj_v(
    const float* __restrict__ atoms, const float* __restrict__ W,
    char* __restrict__ vthi)
{
  const int sblk = blockIdx.x * 64;
  const int h = blockIdx.y, b = blockIdx.z;
  const int tid = threadIdx.x;
  const int w = tid >> 6, lane = tid & 63;
  const int lrow = lane & 31, lhi = lane >> 5;

  __shared__ __align__(16) float T[4][8 * 520];

  unsigned wAh[2][4][4], wAl[2][4][4];
#pragma unroll
  for (int wt = 0; wt < 2; ++wt)
#pragma unroll
    for (int ks = 0; ks < 4; ++ks) {
      const float* wp = W + h * 4096 + (wt * 32 + lrow) * 64 + ks * 16 + lhi * 8;
      float v[8];
      const float4 a = *(const float4*)wp;
      const float4 b2 = *(const float4*)(wp + 4);
      v[0] = a.x; v[1] = a.y; v[2] = a.z; v[3] = a.w;
      v[4] = b2.x; v[5] = b2.y; v[6] = b2.z; v[7] = b2.w;
      split8(v, wAh[wt][ks], wAl[wt][ks]);
    }

  const int bh = b * H_ + h;
  float* Tw = &T[w][0];

  for (int p = 0; p < 2; ++p) {
#pragma unroll
    for (int half8 = 0; half8 < 2; ++half8) {
      const int t = w * 4 + p * 2 + half8;
      const float* arow = atoms + ((size_t)(b * S_ + sblk) * 8 + t * 32 + lrow) * 64;
      unsigned aBh[4][4], aBl[4][4];
#pragma unroll
      for (int ks = 0; ks < 4; ++ks) {
        float v[8];
        const float4 a = *(const float4*)(arow + ks * 16 + lhi * 8);
        const float4 b2 = *(const float4*)(arow + ks * 16 + lhi * 8 + 4);
        v[0] = a.x; v[1] = a.y; v[2] = a.z; v[3] = a.w;
        v[4] = b2.x; v[5] = b2.y; v[6] = b2.z; v[7] = b2.w;
        split8(v, aBh[ks], aBl[ks]);
      }

      f32x16 y0, y1;
#pragma unroll
      for (int r = 0; r < 16; ++r) { y0[r] = 0.f; y1[r] = 0.f; }
      __builtin_amdgcn_s_setprio(1);
#pragma unroll
      for (int ks = 0; ks < 4; ++ks) {
        U4B8 a0h, a0l, a1h, a1l, bh2, bl2;
        a0h.u = make_uint4(wAh[0][ks][0], wAh[0][ks][1], wAh[0][ks][2], wAh[0][ks][3]);
        a0l.u = make_uint4(wAl[0][ks][0], wAl[0][ks][1], wAl[0][ks][2], wAl[0][ks][3]);
        a1h.u = make_uint4(wAh[1][ks][0], wAh[1][ks][1], wAh[1][ks][2], wAh[1][ks][3]);
        a1l.u = make_uint4(wAl[1][ks][0], wAl[1][ks][1], wAl[1][ks][2], wAl[1][ks][3]);
        bh2.u = make_uint4(aBh[ks][0], aBh[ks][1], aBh[ks][2], aBh[ks][3]);
        bl2.u = make_uint4(aBl[ks][0], aBl[ks][1], aBl[ks][2], aBl[ks][3]);
        y0 = __builtin_amdgcn_mfma_f32_32x32x16_bf16(a0h.v, bh2.v, y0, 0, 0, 0);
        y1 = __builtin_amdgcn_mfma_f32_32x32x16_bf16(a1h.v, bh2.v, y1, 0, 0, 0);
        y0 = __builtin_amdgcn_mfma_f32_32x32x16_bf16(a0l.v, bh2.v, y0, 0, 0, 0);
        y1 = __builtin_amdgcn_mfma_f32_32x32x16_bf16(a1l.v, bh2.v, y1, 0, 0, 0);
        y0 = __builtin_amdgcn_mfma_f32_32x32x16_bf16(a0h.v, bl2.v, y0, 0, 0, 0);
        y1 = __builtin_amdgcn_mfma_f32_32x32x16_bf16(a1h.v, bl2.v, y1, 0, 0, 0);
      }
      __builtin_amdgcn_s_setprio(0);

      const int s_in = half8 * 4 + (lrow >> 3);
      const int m = lrow & 7;
#pragma unroll
      for (int r = 0; r < 16; ++r) {
        const int dd = (r & 3) + 8 * (r >> 2) + 4 * lhi;
        Tw[s_in * 520 + m * 64 + dd] = y0[r];
        Tw[s_in * 520 + m * 64 + dd + 32] = y1[r];
      }
    }
    const int s0 = sblk + w * 16 + p * 8;
    const int ch = s0 >> 5, half = (s0 >> 4) & 1, part2 = (s0 >> 3) & 1;
    const size_t base = (size_t)bh * 1048576 + (size_t)ch * 32768 + half * 16384;
#pragma unroll
    for (int j = 0; j < 8; ++j) {
      const int c = j * 64 + lane;
      float v[8];
#pragma unroll
      for (int s = 0; s < 8; ++s) v[s] = Tw[s * 520 + c];
      unsigned hw[4];
#pragma unroll
      for (int pq = 0; pq < 4; ++pq)
        hw[pq] = cvt_pk_bf16(v[2 * pq], v[2 * pq + 1]);
      const unsigned inner = (unsigned)(c * 32 + part2 * 16);
      *(uint4*)(vthi + base + inner) = make_uint4(hw[0], hw[1], hw[2], hw[3]);
    }
  }
}

// ---------------------------------------------------------------------------
// MFMA flash attention: 64-k phases, dual producers lookahead-2, PV 1-term.
// ---------------------------------------------------------------------------
__global__ __launch_bounds__(256, 2) void k_flash(
    const unsigned short* __restrict__ qrh,
    const char* __restrict__ krh,
    const char* __restrict__ vthi,
    float* __restrict__ ao)
{
  __shared__ __align__(16) char Ksm[32768];   // K dbuf [2][16KB]
  __shared__ float Praw[4][64][32];           // [p&3][k][q]  32KB
  __shared__ float Slv[2][32];

  const int tid = threadIdx.x;
  const int w = tid >> 6, lane = tid & 63;
  const int lrow = lane & 31, lhi = lane >> 5;

  const int phys = blockIdx.x;
  const int x = phys & 7, j = phys >> 3;
  const int bh = (x << 1) | (j >> 5);
  const int qb = j & 31;
  const int b = bh >> 3, h = bh & 7;
  const int qbase = qb * 32;
  const bool isprod = (w < 2);

  uint4 qfh[8];
  if (isprod) {
    const size_t rowb = ((size_t)bh * S_ + qbase + lrow) * 128;
#pragma unroll
    for (int fs = 0; fs < 8; ++fs)
      qfh[fs] = *(const uint4*)(qrh + rowb + fs * 16 + lhi * 8);
  }

  const char* vh_c = vthi + (size_t)bh * 1048576;
  const char* kh_c = krh + (size_t)bh * 262144;

  auto issue_k = [&](int p) {
    char* dh = Ksm + (p & 1) * 16384;
    const size_t g = (size_t)p * 16384;
#pragma unroll
    for (int i = 0; i < 4; ++i)
      __builtin_amdgcn_global_load_lds(kh_c + g + i * 4096 + tid * 16, dh + i * 4096 + (w << 10), 16, 0, 0);
  };

  const unsigned vbase = (unsigned)((w * 128 + lrow) * 32 + lhi * 16);
  uint4 v[4][4];
  auto load_v = [&](int p, int ks) {
    const size_t g = (size_t)(2 * p + (ks >> 1)) * 32768 + (size_t)(ks & 1) * 16384 + vbase;
#pragma unroll
    for (int cf = 0; cf < 4; ++cf)
      v[ks][cf] = *(const uint4*)(vh_c + g + cf * 1024);
  };

  f32x16 acc[4];
#pragma unroll
  for (int i = 0; i < 4; ++i)
#pragma unroll
    for (int r = 0; r < 16; ++r) acc[i][r] = 0.f;
  float l_run = 0.f;

  auto produce = [&](int pp) {
    const char* kb = Ksm + (pp & 1) * 16384;
    float rs = 0.f;
#pragma unroll
    for (int t = 0; t < 2; ++t) {
      const char* kt = kb + t * 8192;
      f32x16 s0, s1;
#pragma unroll
      for (int r = 0; r < 16; ++r) { s0[r] = 0.f; s1[r] = 0.f; }
      __builtin_amdgcn_s_setprio(1);
#pragma unroll
      for (int fs = 0; fs < 8; ++fs) {
        const unsigned kaddr = (unsigned)((lrow * 256 + fs * 32 + lhi * 16) ^ ((lrow & 7) << 4));
        U4B8 khf, qh;
        khf.u = *(const uint4*)(kt + kaddr);
        qh.u = qfh[fs];
        if (fs & 1) s1 = __builtin_amdgcn_mfma_f32_32x32x16_bf16(khf.v, qh.v, s1, 0, 0, 0);
        else        s0 = __builtin_amdgcn_mfma_f32_32x32x16_bf16(khf.v, qh.v, s0, 0, 0, 0);
      }
      __builtin_amdgcn_s_setprio(0);
#pragma unroll
      for (int r = 0; r < 16; ++r) {
        const float pv = __expf(s0[r] + s1[r]);
        rs += pv;
        const int k = t * 32 + (r & 3) + 8 * (r >> 2) + 4 * lhi;
        Praw[pp & 3][k][lrow] = pv;
      }
    }
    rs += __shfl_xor(rs, 32);
    l_run += rs;
  };

  // ---- prologue ----
  issue_k(0);
  issue_k(1);
#pragma unroll
  for (int ks = 0; ks < 4; ++ks) load_v(0, ks);
  asm volatile("s_waitcnt vmcnt(16)" ::: "memory");
  SBAR(); MEMFENCE();
  if (w == 0) produce(0);
  if (w == 1) produce(1);
  asm volatile("s_waitcnt lgkmcnt(0)" ::: "memory");
  SCHED0(); SBAR(); MEMFENCE();
  issue_k(2);

  for (int p = 0; p < 16; ++p) {
    if (p <= 12) { SCHED0(); issue_k(p + 3); SCHED0(); }

    if (p <= 13 && w == (p & 1)) {
      if (p == 0) { asm volatile("s_waitcnt vmcnt(4)" ::: "memory"); }
      produce(p + 2);
    }

    // ---- all waves: PV(p) from Praw[p&3], single-term bf16 P ----
#pragma unroll
    for (int ks = 0; ks < 4; ++ks) {
      float pq[8];
#pragma unroll
      for (int jj = 0; jj < 8; ++jj)
        pq[jj] = Praw[p & 3][ks * 16 + lhi * 8 + jj][lrow];
      unsigned phw[4];
#pragma unroll
      for (int p4 = 0; p4 < 4; ++p4)
        phw[p4] = cvt_pk_bf16(pq[2 * p4], pq[2 * p4 + 1]);
      U4B8 pah;
      pah.u = make_uint4(phw[0], phw[1], phw[2], phw[3]);
      __builtin_amdgcn_s_setprio(1);
#pragma unroll
      for (int cf = 0; cf < 4; ++cf) {
        U4B8 vv;
        vv.u = v[ks][cf];
        acc[cf] = __builtin_amdgcn_mfma_f32_32x32x16_bf16(pah.v, vv.v, acc[cf], 0, 0, 0);
      }
      __builtin_amdgcn_s_setprio(0);
      if (p <= 14) load_v(p + 1, ks);
    }

    SCHED0();
    asm volatile("s_waitcnt vmcnt(16)" ::: "memory");
    asm volatile("s_waitcnt lgkmcnt(0)" ::: "memory");
    SBAR(); MEMFENCE();
  }

  // ---- epilogue ----
  if (isprod && lane < 32) Slv[w][lrow] = l_run;
  asm volatile("s_waitcnt lgkmcnt(0)" ::: "memory");
  SBAR(); MEMFENCE();
  float lr[16];
#pragma unroll
  for (int r = 0; r < 16; ++r) {
    const int q = (r & 3) + 8 * (r >> 2) + 4 * lhi;
    lr[r] = 1.0f / (Slv[0][q] + Slv[1][q]);
  }
#pragma unroll
  for (int cf = 0; cf < 4; ++cf) {
    const int c = w * 128 + cf * 32 + lrow;
    const int m = c >> 6, dd = c & 63;
#pragma unroll
    for (int r = 0; r < 16; ++r) {
      const int qr = (r & 3) + 8 * (r >> 2) + 4 * lhi;
      const int srow = qbase + qr;
      const size_t off = (((size_t)(b * S_ + srow)) * 8 + m) * 512 + h * 64 + dd;
      ao[off] = acc[cf][r] * lr[r];
    }
  }
}

// ---------------------------------------------------------------------------
// k_out MFMA: 256 blocks x 64 rows (unchanged from R18).
// ---------------------------------------------------------------------------
__global__ __launch_bounds__(256) void k_out(
    const float* __restrict__ ao, const float* __restrict__ Wo,
    const float* __restrict__ Ww, const float* __restrict__ qlw,
    float* __restrict__ out)
{
  const int tid = threadIdx.x;
  const int w = tid >> 6, lane = tid & 63;
  const int lrow = lane & 31, lhi = lane >> 5;
  const int Rblk = blockIdx.x * 64;
  const int rt = w & 1, dt = w >> 1;

  __shared__ __align__(16) char WoF[4][2][2][1024];
  __shared__ __align__(16) float Os[64 * 68];

  f32x16 acc;
#pragma unroll
  for (int r = 0; r < 16; ++r) acc[r] = 0.f;

  const float* brow = ao + (size_t)(Rblk + rt * 32 + lrow) * 512;

  for (int chunk = 0; chunk < 8; ++chunk) {
    __syncthreads();
#pragma unroll
    for (int dtt = 0; dtt < 2; ++dtt) {
      const float* wp = Wo + (size_t)(dtt * 32 + lrow) * 512 + (chunk * 4 + w) * 16 + lhi * 8;
      float v[8];
      const float4 a = *(const float4*)wp;
      const float4 b2 = *(const float4*)(wp + 4);
      v[0] = a.x; v[1] = a.y; v[2] = a.z; v[3] = a.w;
      v[4] = b2.x; v[5] = b2.y; v[6] = b2.z; v[7] = b2.w;
      unsigned hw[4], lw2[4];
      split8(v, hw, lw2);
      *(uint4*)&WoF[w][dtt][0][lane * 16] = make_uint4(hw[0], hw[1], hw[2], hw[3]);
      *(uint4*)&WoF[w][dtt][1][lane * 16] = make_uint4(lw2[0], lw2[1], lw2[2], lw2[3]);
    }
    __syncthreads();

#pragma unroll
    for (int kl = 0; kl < 4; ++kl) {
      float v[8];
      const float4 a = *(const float4*)(brow + (chunk * 4 + kl) * 16 + lhi * 8);
      const float4 b2 = *(const float4*)(brow + (chunk * 4 + kl) * 16 + lhi * 8 + 4);
      v[0] = a.x; v[1] = a.y; v[2] = a.z; v[3] = a.w;
      v[4] = b2.x; v[5] = b2.y; v[6] = b2.z; v[7] = b2.w;
      unsigned bhw[4], blw[4];
      split8(v, bhw, blw);
      U4B8 bh2, bl2;
      bh2.u = make_uint4(bhw[0], bhw[1], bhw[2], bhw[3]);
      bl2.u = make_uint4(blw[0], blw[1], blw[2], blw[3]);
      U4B8 ah, al;
      ah.u = *(const uint4*)&WoF[kl][dt][0][lane * 16];
      al.u = *(const uint4*)&WoF[kl][dt][1][lane * 16];
      __builtin_amdgcn_s_setprio(1);
      acc = __builtin_amdgcn_mfma_f32_32x32x16_bf16(ah.v, bh2.v, acc, 0, 0, 0);
      acc = __builtin_amdgcn_mfma_f32_32x32x16_bf16(al.v, bh2.v, acc, 0, 0, 0);
      acc = __builtin_amdgcn_mfma_f32_32x32x16_bf16(ah.v, bl2.v, acc, 0, 0, 0);
      __builtin_amdgcn_s_setprio(0);
    }
  }

  __syncthreads();
#pragma unroll
  for (int r = 0; r < 16; ++r) {
    const int d = dt * 32 + (r & 3) + 8 * (r >> 2) + 4 * lhi;
    Os[(rt * 32 + lrow) * 68 + d] = acc[r];
  }
  __syncthreads();

#pragma unroll
  for (int jj = 0; jj < 4; ++jj) {
    const int i = tid + 256 * jj;
    const int r = i >> 4, c4 = (i & 15) * 4;
    const float4 vv = *(const float4*)&Os[r * 68 + c4];
    *(float4*)&out[(size_t)(Rblk + r) * 64 + c4] = vv;
  }

#pragma unroll
  for (int gi = 0; gi < 2; ++gi) {
    const int g = w * 2 + gi;
    float mean = 0.f;
#pragma unroll
    for (int m = 0; m < 8; ++m) mean += Os[(g * 8 + m) * 68 + lane];
    mean *= 0.125f;
    float dsel = 0.f;
#pragma unroll
    for (int mw = 0; mw < 8; ++mw) {
      float part = mean * Ww[mw * 64 + lane];
      part += __shfl_xor(part, 1);
      part += __shfl_xor(part, 2);
      part += __shfl_xor(part, 4);
      part += __shfl_xor(part, 8);
      part += __shfl_xor(part, 16);
      part += __shfl_xor(part, 32);
      if (lane == mw) dsel = part;
    }
    if (lane < 8) {
      const int idx = Rblk + g * 8 + lane;
      out[1048576 + idx] = qlw[idx] + dsel;
    }
  }
}

// ---------------------------------------------------------------------------
extern "C" void kernel_launch(void* const* d_in, const int* in_sizes, int n_in,
                              void* d_out, int out_size, void* d_ws, size_t ws_size,
                              hipStream_t stream)
{
  const float* q_atoms = (const float*)d_in[0];
  const float* q_logw  = (const float*)d_in[1];
  const float* k_atoms = (const float*)d_in[2];
  const float* k_logw  = (const float*)d_in[3];
  const float* v_atoms = (const float*)d_in[4];
  const float* cosT  = (const float*)d_in[6];
  const float* sinT  = (const float*)d_in[7];
  const float* Wq    = (const float*)d_in[8];
  const float* Wk    = (const float*)d_in[9];
  const float* Wv    = (const float*)d_in[10];
  const float* Wo    = (const float*)d_in[11];
  const float* Ww    = (const float*)d_in[12];
  const float* logbw = (const float*)d_in[13];
  const float* rffb  = (const float*)d_in[14];
  float* out = (float*)d_out;

  char* wsb = (char*)d_ws;
  char* qrh = wsb;
  char* krh = wsb + (8u << 20);
  char* vthi = wsb + (16u << 20);
  float* ao = (float*)(wsb + (48u << 20));

  const dim3 blk(256);
  k_proj_rff<<<dim3(16, 8, 4), blk, 0, stream>>>(q_atoms, q_logw, k_atoms, k_logw,
                                                 Wq, Wk, rffb, logbw, cosT, sinT,
                                                 qrh, krh);
  k_proj_v  <<<dim3(16, 8, 2), blk, 0, stream>>>(v_atoms, Wv, vthi);
  k_flash   <<<dim3(512), blk, 0, stream>>>((const unsigned short*)qrh,
                                            krh, vthi, ao);
  k_out     <<<dim3(256), blk, 0, stream>>>(ao, Wo, Ww, q_logw, out);
}

// Round 20
// 102.468 us; speedup vs baseline: 1.7359x; 1.1333x over previous
//
#include <hip/hip_runtime.h>
#include <math.h>

// KME attention. B=2 S=1024 M=8 D=64 H=8 NF=64
// Round 20 (on R19): k_proj_rff GEMM2 transposed (f in lanes, (s,m) in regs)
// -> weighted m-reduce becomes 64 in-register FMAs + 16 shfl_xor(32)
// (replaces 384 LDS-pipe shuffles per wave-iter). Other kernels unchanged.
//
// ws layout (bytes), 80 MiB total:
//   qrh  @ 0MB   4MB  ushort [bh][s][128]          (natural)
//   krh  @ 8MB   4MB  swizzled-chunk layout [bh][ch=32][8192B]
//   vthi @16MB  16MB  [bh][ch=32][half=2][c=512][32B], inner=c*32+part2*16
//   ao   @48MB  32MB  f32 [b][s][m][512]

#define B_ 2
#define S_ 1024
#define H_ 8

typedef __attribute__((ext_vector_type(8))) short short8;
typedef __attribute__((ext_vector_type(16))) float f32x16;
union U4B8 { uint4 u; short8 v; };

#define SBAR() __builtin_amdgcn_s_barrier()
#define SCHED0() __builtin_amdgcn_sched_barrier(0)
#define MEMFENCE() asm volatile("" ::: "memory")

__device__ inline unsigned cvt_pk_bf16(float a, float b) {
  unsigned r;
  asm("v_cvt_pk_bf16_f32 %0, %1, %2" : "=v"(r) : "v"(a), "v"(b));
  return r;
}
__device__ inline void split8(const float* v, unsigned* hw, unsigned* lw) {
#pragma unroll
  for (int p = 0; p < 4; ++p) {
    const float a = v[2 * p], b = v[2 * p + 1];
    const unsigned h = cvt_pk_bf16(a, b);
    const float ra = a - __uint_as_float(h << 16);
    const float rb = b - __uint_as_float(h & 0xffff0000u);
    hw[p] = h;
    lw[p] = cvt_pk_bf16(ra, rb);
  }
}

// ---------------------------------------------------------------------------
// MFMA projection + RoPE + RFF encode; hi-only outputs; 2-term split GEMMs;
// GEMM2 transposed for register-local m-reduction.
// ---------------------------------------------------------------------------
__global__ __launch_bounds__(256, 2) void k_proj_rff(
    const float* __restrict__ q_atoms, const float* __restrict__ q_logw,
    const float* __restrict__ k_atoms, const float* __restrict__ k_logw,
    const float* __restrict__ Wq, const float* __restrict__ Wk,
    const float* __restrict__ freqb, const float* __restrict__ logbw,
    const float* __restrict__ cosT, const float* __restrict__ sinT,
    char* __restrict__ qoh, char* __restrict__ koh)
{
  const int sblk = blockIdx.x * 64;
  const int h = blockIdx.y, z = blockIdx.z;
  const int qk = z >> 1, b = z & 1;
  const float* atoms = qk ? k_atoms : q_atoms;
  const float* logw  = qk ? k_logw : q_logw;
  const float* W     = qk ? Wk : Wq;
  char* oh = qk ? koh : qoh;

  const int tid = threadIdx.x;
  const int w = tid >> 6, lane = tid & 63;
  const int lrow = lane & 31, lhi = lane >> 5;

  __shared__ float Cs[64 * 65];
  __shared__ float Sn[64 * 65];
  __shared__ float Wm[64 * 8];
  __shared__ __align__(16) char FT[2][4][2][1024];
  __shared__ __align__(16) char Ob[4][1024];

  for (int i = tid; i < 4096; i += 256) {
    const int sl = i >> 6, d = i & 63;
    Cs[sl * 65 + d] = cosT[(sblk + sl) * 64 + d];
    Sn[sl * 65 + d] = sinT[(sblk + sl) * 64 + d];
  }
  if (tid < 64) {
    const float* lw = logw + (size_t)(b * S_ + sblk + tid) * 8;
    float mx = lw[0];
    for (int m = 1; m < 8; ++m) mx = fmaxf(mx, lw[m]);
    float e[8], sum = 0.f;
    for (int m = 0; m < 8; ++m) { e[m] = __expf(lw[m] - mx); sum += e[m]; }
    const float inv = 1.0f / sum;
    for (int m = 0; m < 8; ++m) Wm[tid * 8 + m] = e[m] * inv;
  }
  const float fscale = __expf(-logbw[h]);
  {
    const int ftw = w & 1;
#pragma unroll
    for (int kk = 0; kk < 2; ++kk) {
      const int ks2 = (w >> 1) + kk * 2;
      float v[8];
#pragma unroll
      for (int j = 0; j < 8; ++j)
        v[j] = freqb[h * 4096 + (ks2 * 16 + lhi * 8 + j) * 64 + ftw * 32 + lrow] * fscale;
      unsigned hw[4], lw2[4];
      split8(v, hw, lw2);
      *(uint4*)&FT[ftw][ks2][0][lane * 16] = make_uint4(hw[0], hw[1], hw[2], hw[3]);
      *(uint4*)&FT[ftw][ks2][1][lane * 16] = make_uint4(lw2[0], lw2[1], lw2[2], lw2[3]);
    }
  }
  unsigned wAh[2][4][4], wAl[2][4][4];
#pragma unroll
  for (int wt = 0; wt < 2; ++wt)
#pragma unroll
    for (int ks = 0; ks < 4; ++ks) {
      const float* wp = W + h * 4096 + (wt * 32 + lrow) * 64 + ks * 16 + lhi * 8;
      float v[8];
      const float4 a = *(const float4*)wp;
      const float4 b2 = *(const float4*)(wp + 4);
      v[0] = a.x; v[1] = a.y; v[2] = a.z; v[3] = a.w;
      v[4] = b2.x; v[5] = b2.y; v[6] = b2.z; v[7] = b2.w;
      split8(v, wAh[wt][ks], wAl[wt][ks]);
    }
  __syncthreads();

  const int bh = b * H_ + h;
  char* obh = &Ob[w][0];
  unsigned short* ob16 = (unsigned short*)obh;

  for (int it = 0; it < 4; ++it) {
    const int t = w * 4 + it;
    const float* arow = atoms + ((size_t)(b * S_ + sblk) * 8 + t * 32 + lrow) * 64;
    unsigned aBh[4][4], aBl[4][4];
#pragma unroll
    for (int ks = 0; ks < 4; ++ks) {
      float v[8];
      const float4 a = *(const float4*)(arow + ks * 16 + lhi * 8);
      const float4 b2 = *(const float4*)(arow + ks * 16 + lhi * 8 + 4);
      v[0] = a.x; v[1] = a.y; v[2] = a.z; v[3] = a.w;
      v[4] = b2.x; v[5] = b2.y; v[6] = b2.z; v[7] = b2.w;
      split8(v, aBh[ks], aBl[ks]);
    }

    f32x16 y0, y1;
#pragma unroll
    for (int r = 0; r < 16; ++r) { y0[r] = 0.f; y1[r] = 0.f; }
    __builtin_amdgcn_s_setprio(1);
#pragma unroll
    for (int ks = 0; ks < 4; ++ks) {
      U4B8 a0h, a1h, bh2, bl2;
      a0h.u = make_uint4(wAh[0][ks][0], wAh[0][ks][1], wAh[0][ks][2], wAh[0][ks][3]);
      a1h.u = make_uint4(wAh[1][ks][0], wAh[1][ks][1], wAh[1][ks][2], wAh[1][ks][3]);
      bh2.u = make_uint4(aBh[ks][0], aBh[ks][1], aBh[ks][2], aBh[ks][3]);
      bl2.u = make_uint4(aBl[ks][0], aBl[ks][1], aBl[ks][2], aBl[ks][3]);
      y0 = __builtin_amdgcn_mfma_f32_32x32x16_bf16(a0h.v, bh2.v, y0, 0, 0, 0);
      y1 = __builtin_amdgcn_mfma_f32_32x32x16_bf16(a1h.v, bh2.v, y1, 0, 0, 0);
      y0 = __builtin_amdgcn_mfma_f32_32x32x16_bf16(a0h.v, bl2.v, y0, 0, 0, 0);
      y1 = __builtin_amdgcn_mfma_f32_32x32x16_bf16(a1h.v, bl2.v, y1, 0, 0, 0);
    }
    __builtin_amdgcn_s_setprio(0);

    const int sloc = t * 4 + (lrow >> 3);
    const int sld = sloc * 65;
    float yr0[16], yr1[16];
#pragma unroll
    for (int r = 0; r < 16; ++r) {
      const int dd = (r & 3) + 8 * (r >> 2) + 4 * lhi;
      const float c0 = Cs[sld + dd],      s0v = Sn[sld + dd];
      const float c1 = Cs[sld + dd + 32], s1v = Sn[sld + dd + 32];
      yr0[r] = y0[r] * c0 - y1[r] * s0v;
      yr1[r] = y1[r] * c1 + y0[r] * s1v;
    }

    unsigned Bh[4][4], Bl[4][4];
    {
      const float* src[2] = { yr0, yr1 };
#pragma unroll
      for (int st = 0; st < 2; ++st) {
#pragma unroll
        for (int half = 0; half < 2; ++half) {
          const int ks2 = st * 2 + half;
          const float* q = src[st] + half * 8;
          unsigned ph[4], pl[4];
          split8(q, ph, pl);
          {
            const unsigned t0 = lhi ? ph[0] : ph[2];
            const unsigned r0 = (unsigned)__shfl_xor((int)t0, 32);
            const unsigned t1 = lhi ? ph[1] : ph[3];
            const unsigned r1 = (unsigned)__shfl_xor((int)t1, 32);
            Bh[ks2][0] = lhi ? r0 : ph[0];
            Bh[ks2][1] = lhi ? r1 : ph[1];
            Bh[ks2][2] = lhi ? ph[2] : r0;
            Bh[ks2][3] = lhi ? ph[3] : r1;
          }
          {
            const unsigned t0 = lhi ? pl[0] : pl[2];
            const unsigned r0 = (unsigned)__shfl_xor((int)t0, 32);
            const unsigned t1 = lhi ? pl[1] : pl[3];
            const unsigned r1 = (unsigned)__shfl_xor((int)t1, 32);
            Bl[ks2][0] = lhi ? r0 : pl[0];
            Bl[ks2][1] = lhi ? r1 : pl[1];
            Bl[ks2][2] = lhi ? pl[2] : r0;
            Bl[ks2][3] = lhi ? pl[3] : r1;
          }
        }
      }
    }

    // ---- GEMM2 TRANSPOSED: D[sm(reg)][f(lane)] = Y'[sm][d] . freq[d][f] ----
    f32x16 d0, d1;
#pragma unroll
    for (int r = 0; r < 16; ++r) { d0[r] = 0.f; d1[r] = 0.f; }
    __builtin_amdgcn_s_setprio(1);
#pragma unroll
    for (int ks2 = 0; ks2 < 4; ++ks2) {
      U4B8 f0, f1, bh2, bl2;
      f0.u = *(const uint4*)&FT[0][ks2][0][lane * 16];   // f 0..31 cols
      f1.u = *(const uint4*)&FT[1][ks2][0][lane * 16];   // f 32..63 cols
      bh2.u = make_uint4(Bh[ks2][0], Bh[ks2][1], Bh[ks2][2], Bh[ks2][3]);
      bl2.u = make_uint4(Bl[ks2][0], Bl[ks2][1], Bl[ks2][2], Bl[ks2][3]);
      d0 = __builtin_amdgcn_mfma_f32_32x32x16_bf16(bh2.v, f0.v, d0, 0, 0, 0);
      d1 = __builtin_amdgcn_mfma_f32_32x32x16_bf16(bh2.v, f1.v, d1, 0, 0, 0);
      d0 = __builtin_amdgcn_mfma_f32_32x32x16_bf16(bl2.v, f0.v, d0, 0, 0, 0);
      d1 = __builtin_amdgcn_mfma_f32_32x32x16_bf16(bl2.v, f1.v, d1, 0, 0, 0);
    }
    __builtin_amdgcn_s_setprio(0);

    // ---- sincos + weight + REGISTER m-reduce (m = (r&3)+4*lhi, s = r>>2) ----
    float c0a[4] = {0.f, 0.f, 0.f, 0.f}, s0a[4] = {0.f, 0.f, 0.f, 0.f};
    float c1a[4] = {0.f, 0.f, 0.f, 0.f}, s1a[4] = {0.f, 0.f, 0.f, 0.f};
#pragma unroll
    for (int r = 0; r < 16; ++r) {
      const int si = r >> 2;
      const int m = (r & 3) + 4 * lhi;
      const float wt = Wm[(t * 4 + si) * 8 + m];
      float sv, cv;
      __sincosf(d0[r], &sv, &cv);
      c0a[si] = fmaf(wt, cv, c0a[si]);
      s0a[si] = fmaf(wt, sv, s0a[si]);
      __sincosf(d1[r], &sv, &cv);
      c1a[si] = fmaf(wt, cv, c1a[si]);
      s1a[si] = fmaf(wt, sv, s1a[si]);
    }
    // cross-half combine (m 0-3 with m 4-7): 16 shuffles
#pragma unroll
    for (int si = 0; si < 4; ++si) {
      c0a[si] += __shfl_xor(c0a[si], 32);
      s0a[si] += __shfl_xor(s0a[si], 32);
      c1a[si] += __shfl_xor(c1a[si], 32);
      s1a[si] += __shfl_xor(s1a[si], 32);
    }

    // ---- write bounce (lhi==0 lanes): f' = lane, 32+lane, 64+lane, 96+lane ----
    if (!lhi) {
#pragma unroll
      for (int si = 0; si < 4; ++si) {
        ob16[si * 128 + lane]      = (unsigned short)cvt_pk_bf16(c0a[si] * 0.125f, 0.f);
        ob16[si * 128 + 32 + lane] = (unsigned short)cvt_pk_bf16(c1a[si] * 0.125f, 0.f);
        ob16[si * 128 + 64 + lane] = (unsigned short)cvt_pk_bf16(s0a[si] * 0.125f, 0.f);
        ob16[si * 128 + 96 + lane] = (unsigned short)cvt_pk_bf16(s1a[si] * 0.125f, 0.f);
      }
    }
    const uint4 vh = *(const uint4*)(obh + lane * 16);
    const int srow = sblk + t * 4 + (lane >> 4);
    if (!qk) {
      const size_t off = ((size_t)bh * S_ + srow) * 256 + (lane & 15) * 16;
      *(uint4*)(oh + off) = vh;
    } else {
      const int klr = srow & 31, ch = srow >> 5;
      const unsigned inner = (unsigned)(((klr << 8) + (lane & 15) * 16) ^ ((klr & 7) << 4));
      const size_t off = (size_t)bh * 262144 + (size_t)ch * 8192 + inner;
      *(uint4*)(oh + off) = vh;
    }
  }
}

// ---------------------------------------------------------------------------
// V projection, MFMA; hi plane only (unchanged).
// ---------------------------------------------------------------------------
__global__ __launch_bounds__(256) void k_proj_v(
    const float* __restrict__ atoms, const float* __restrict__ W,
    char* __restrict__ vthi)
{
  const int sblk = blockIdx.x * 64;
  const int h = blockIdx.y, b = blockIdx.z;
  const int tid = threadIdx.x;
  const int w = tid >> 6, lane = tid & 63;
  const int lrow = lane & 31, lhi = lane >> 5;

  __shared__ __align__(16) float T[4][8 * 520];

  unsigned wAh[2][4][4], wAl[2][4][4];
#pragma unroll
  for (int wt = 0; wt < 2; ++wt)
#pragma unroll
    for (int ks = 0; ks < 4; ++ks) {
      const float* wp = W + h * 4096 + (wt * 32 + lrow) * 64 + ks * 16 + lhi * 8;
      float v[8];
      const float4 a = *(const float4*)wp;
      const float4 b2 = *(const float4*)(wp + 4);
      v[0] = a.x; v[1] = a.y; v[2] = a.z; v[3] = a.w;
      v[4] = b2.x; v[5] = b2.y; v[6] = b2.z; v[7] = b2.w;
      split8(v, wAh[wt][ks], wAl[wt][ks]);
    }

  const int bh = b * H_ + h;
  float* Tw = &T[w][0];

  for (int p = 0; p < 2; ++p) {
#pragma unroll
    for (int half8 = 0; half8 < 2; ++half8) {
      const int t = w * 4 + p * 2 + half8;
      const float* arow = atoms + ((size_t)(b * S_ + sblk) * 8 + t * 32 + lrow) * 64;
      unsigned aBh[4][4], aBl[4][4];
#pragma unroll
      for (int ks = 0; ks < 4; ++ks) {
        float v[8];
        const float4 a = *(const float4*)(arow + ks * 16 + lhi * 8);
        const float4 b2 = *(const float4*)(arow + ks * 16 + lhi * 8 + 4);
        v[0] = a.x; v[1] = a.y; v[2] = a.z; v[3] = a.w;
        v[4] = b2.x; v[5] = b2.y; v[6] = b2.z; v[7] = b2.w;
        split8(v, aBh[ks], aBl[ks]);
      }

      f32x16 y0, y1;
#pragma unroll
      for (int r = 0; r < 16; ++r) { y0[r] = 0.f; y1[r] = 0.f; }
      __builtin_amdgcn_s_setprio(1);
#pragma unroll
      for (int ks = 0; ks < 4; ++ks) {
        U4B8 a0h, a0l, a1h, a1l, bh2, bl2;
        a0h.u = make_uint4(wAh[0][ks][0], wAh[0][ks][1], wAh[0][ks][2], wAh[0][ks][3]);
        a0l.u = make_uint4(wAl[0][ks][0], wAl[0][ks][1], wAl[0][ks][2], wAl[0][ks][3]);
        a1h.u = make_uint4(wAh[1][ks][0], wAh[1][ks][1], wAh[1][ks][2], wAh[1][ks][3]);
        a1l.u = make_uint4(wAl[1][ks][0], wAl[1][ks][1], wAl[1][ks][2], wAl[1][ks][3]);
        bh2.u = make_uint4(aBh[ks][0], aBh[ks][1], aBh[ks][2], aBh[ks][3]);
        bl2.u = make_uint4(aBl[ks][0], aBl[ks][1], aBl[ks][2], aBl[ks][3]);
        y0 = __builtin_amdgcn_mfma_f32_32x32x16_bf16(a0h.v, bh2.v, y0, 0, 0, 0);
        y1 = __builtin_amdgcn_mfma_f32_32x32x16_bf16(a1h.v, bh2.v, y1, 0, 0, 0);
        y0 = __builtin_amdgcn_mfma_f32_32x32x16_bf16(a0l.v, bh2.v, y0, 0, 0, 0);
        y1 = __builtin_amdgcn_mfma_f32_32x32x16_bf16(a1l.v, bh2.v, y1, 0, 0, 0);
        y0 = __builtin_amdgcn_mfma_f32_32x32x16_bf16(a0h.v, bl2.v, y0, 0, 0, 0);
        y1 = __builtin_amdgcn_mfma_f32_32x32x16_bf16(a1h.v, bl2.v, y1, 0, 0, 0);
      }
      __builtin_amdgcn_s_setprio(0);

      const int s_in = half8 * 4 + (lrow >> 3);
      const int m = lrow & 7;
#pragma unroll
      for (int r = 0; r < 16; ++r) {
        const int dd = (r & 3) + 8 * (r >> 2) + 4 * lhi;
        Tw[s_in * 520 + m * 64 + dd] = y0[r];
        Tw[s_in * 520 + m * 64 + dd + 32] = y1[r];
      }
    }
    const int s0 = sblk + w * 16 + p * 8;
    const int ch = s0 >> 5, half = (s0 >> 4) & 1, part2 = (s0 >> 3) & 1;
    const size_t base = (size_t)bh * 1048576 + (size_t)ch * 32768 + half * 16384;
#pragma unroll
    for (int j = 0; j < 8; ++j) {
      const int c = j * 64 + lane;
      float v[8];
#pragma unroll
      for (int s = 0; s < 8; ++s) v[s] = Tw[s * 520 + c];
      unsigned hw[4];
#pragma unroll
      for (int pq = 0; pq < 4; ++pq)
        hw[pq] = cvt_pk_bf16(v[2 * pq], v[2 * pq + 1]);
      const unsigned inner = (unsigned)(c * 32 + part2 * 16);
      *(uint4*)(vthi + base + inner) = make_uint4(hw[0], hw[1], hw[2], hw[3]);
    }
  }
}

// ---------------------------------------------------------------------------
// MFMA flash attention: 64-k phases, dual producers lookahead-2, PV 1-term.
// (unchanged from R19)
// ---------------------------------------------------------------------------
__global__ __launch_bounds__(256, 2) void k_flash(
    const unsigned short* __restrict__ qrh,
    const char* __restrict__ krh,
    const char* __restrict__ vthi,
    float* __restrict__ ao)
{
  __shared__ __align__(16) char Ksm[32768];
  __shared__ float Praw[4][64][32];
  __shared__ float Slv[2][32];

  const int tid = threadIdx.x;
  const int w = tid >> 6, lane = tid & 63;
  const int lrow = lane & 31, lhi = lane >> 5;

  const int phys = blockIdx.x;
  const int x = phys & 7, j = phys >> 3;
  const int bh = (x << 1) | (j >> 5);
  const int qb = j & 31;
  const int b = bh >> 3, h = bh & 7;
  const int qbase = qb * 32;
  const bool isprod = (w < 2);

  uint4 qfh[8];
  if (isprod) {
    const size_t rowb = ((size_t)bh * S_ + qbase + lrow) * 128;
#pragma unroll
    for (int fs = 0; fs < 8; ++fs)
      qfh[fs] = *(const uint4*)(qrh + rowb + fs * 16 + lhi * 8);
  }

  const char* vh_c = vthi + (size_t)bh * 1048576;
  const char* kh_c = krh + (size_t)bh * 262144;

  auto issue_k = [&](int p) {
    char* dh = Ksm + (p & 1) * 16384;
    const size_t g = (size_t)p * 16384;
#pragma unroll
    for (int i = 0; i < 4; ++i)
      __builtin_amdgcn_global_load_lds(kh_c + g + i * 4096 + tid * 16, dh + i * 4096 + (w << 10), 16, 0, 0);
  };

  const unsigned vbase = (unsigned)((w * 128 + lrow) * 32 + lhi * 16);
  uint4 v[4][4];
  auto load_v = [&](int p, int ks) {
    const size_t g = (size_t)(2 * p + (ks >> 1)) * 32768 + (size_t)(ks & 1) * 16384 + vbase;
#pragma unroll
    for (int cf = 0; cf < 4; ++cf)
      v[ks][cf] = *(const uint4*)(vh_c + g + cf * 1024);
  };

  f32x16 acc[4];
#pragma unroll
  for (int i = 0; i < 4; ++i)
#pragma unroll
    for (int r = 0; r < 16; ++r) acc[i][r] = 0.f;
  float l_run = 0.f;

  auto produce = [&](int pp) {
    const char* kb = Ksm + (pp & 1) * 16384;
    float rs = 0.f;
#pragma unroll
    for (int t = 0; t < 2; ++t) {
      const char* kt = kb + t * 8192;
      f32x16 s0, s1;
#pragma unroll
      for (int r = 0; r < 16; ++r) { s0[r] = 0.f; s1[r] = 0.f; }
      __builtin_amdgcn_s_setprio(1);
#pragma unroll
      for (int fs = 0; fs < 8; ++fs) {
        const unsigned kaddr = (unsigned)((lrow * 256 + fs * 32 + lhi * 16) ^ ((lrow & 7) << 4));
        U4B8 khf, qh;
        khf.u = *(const uint4*)(kt + kaddr);
        qh.u = qfh[fs];
        if (fs & 1) s1 = __builtin_amdgcn_mfma_f32_32x32x16_bf16(khf.v, qh.v, s1, 0, 0, 0);
        else        s0 = __builtin_amdgcn_mfma_f32_32x32x16_bf16(khf.v, qh.v, s0, 0, 0, 0);
      }
      __builtin_amdgcn_s_setprio(0);
#pragma unroll
      for (int r = 0; r < 16; ++r) {
        const float pv = __expf(s0[r] + s1[r]);
        rs += pv;
        const int k = t * 32 + (r & 3) + 8 * (r >> 2) + 4 * lhi;
        Praw[pp & 3][k][lrow] = pv;
      }
    }
    rs += __shfl_xor(rs, 32);
    l_run += rs;
  };

  // ---- prologue ----
  issue_k(0);
  issue_k(1);
#pragma unroll
  for (int ks = 0; ks < 4; ++ks) load_v(0, ks);
  asm volatile("s_waitcnt vmcnt(16)" ::: "memory");
  SBAR(); MEMFENCE();
  if (w == 0) produce(0);
  if (w == 1) produce(1);
  asm volatile("s_waitcnt lgkmcnt(0)" ::: "memory");
  SCHED0(); SBAR(); MEMFENCE();
  issue_k(2);

  for (int p = 0; p < 16; ++p) {
    if (p <= 12) { SCHED0(); issue_k(p + 3); SCHED0(); }

    if (p <= 13 && w == (p & 1)) {
      if (p == 0) { asm volatile("s_waitcnt vmcnt(4)" ::: "memory"); }
      produce(p + 2);
    }

#pragma unroll
    for (int ks = 0; ks < 4; ++ks) {
      float pq[8];
#pragma unroll
      for (int jj = 0; jj < 8; ++jj)
        pq[jj] = Praw[p & 3][ks * 16 + lhi * 8 + jj][lrow];
      unsigned phw[4];
#pragma unroll
      for (int p4 = 0; p4 < 4; ++p4)
        phw[p4] = cvt_pk_bf16(pq[2 * p4], pq[2 * p4 + 1]);
      U4B8 pah;
      pah.u = make_uint4(phw[0], phw[1], phw[2], phw[3]);
      __builtin_amdgcn_s_setprio(1);
#pragma unroll
      for (int cf = 0; cf < 4; ++cf) {
        U4B8 vv;
        vv.u = v[ks][cf];
        acc[cf] = __builtin_amdgcn_mfma_f32_32x32x16_bf16(pah.v, vv.v, acc[cf], 0, 0, 0);
      }
      __builtin_amdgcn_s_setprio(0);
      if (p <= 14) load_v(p + 1, ks);
    }

    SCHED0();
    asm volatile("s_waitcnt vmcnt(16)" ::: "memory");
    asm volatile("s_waitcnt lgkmcnt(0)" ::: "memory");
    SBAR(); MEMFENCE();
  }

  // ---- epilogue ----
  if (isprod && lane < 32) Slv[w][lrow] = l_run;
  asm volatile("s_waitcnt lgkmcnt(0)" ::: "memory");
  SBAR(); MEMFENCE();
  float lr[16];
#pragma unroll
  for (int r = 0; r < 16; ++r) {
    const int q = (r & 3) + 8 * (r >> 2) + 4 * lhi;
    lr[r] = 1.0f / (Slv[0][q] + Slv[1][q]);
  }
#pragma unroll
  for (int cf = 0; cf < 4; ++cf) {
    const int c = w * 128 + cf * 32 + lrow;
    const int m = c >> 6, dd = c & 63;
#pragma unroll
    for (int r = 0; r < 16; ++r) {
      const int qr = (r & 3) + 8 * (r >> 2) + 4 * lhi;
      const int srow = qbase + qr;
      const size_t off = (((size_t)(b * S_ + srow)) * 8 + m) * 512 + h * 64 + dd;
      ao[off] = acc[cf][r] * lr[r];
    }
  }
}

// ---------------------------------------------------------------------------
// k_out MFMA: 256 blocks x 64 rows (unchanged from R18/R19).
// ---------------------------------------------------------------------------
__global__ __launch_bounds__(256) void k_out(
    const float* __restrict__ ao, const float* __restrict__ Wo,
    const float* __restrict__ Ww, const float* __restrict__ qlw,
    float* __restrict__ out)
{
  const int tid = threadIdx.x;
  const int w = tid >> 6, lane = tid & 63;
  const int lrow = lane & 31, lhi = lane >> 5;
  const int Rblk = blockIdx.x * 64;
  const int rt = w & 1, dt = w >> 1;

  __shared__ __align__(16) char WoF[4][2][2][1024];
  __shared__ __align__(16) float Os[64 * 68];

  f32x16 acc;
#pragma unroll
  for (int r = 0; r < 16; ++r) acc[r] = 0.f;

  const float* brow = ao + (size_t)(Rblk + rt * 32 + lrow) * 512;

  for (int chunk = 0; chunk < 8; ++chunk) {
    __syncthreads();
#pragma unroll
    for (int dtt = 0; dtt < 2; ++dtt) {
      const float* wp = Wo + (size_t)(dtt * 32 + lrow) * 512 + (chunk * 4 + w) * 16 + lhi * 8;
      float v[8];
      const float4 a = *(const float4*)wp;
      const float4 b2 = *(const float4*)(wp + 4);
      v[0] = a.x; v[1] = a.y; v[2] = a.z; v[3] = a.w;
      v[4] = b2.x; v[5] = b2.y; v[6] = b2.z; v[7] = b2.w;
      unsigned hw[4], lw2[4];
      split8(v, hw, lw2);
      *(uint4*)&WoF[w][dtt][0][lane * 16] = make_uint4(hw[0], hw[1], hw[2], hw[3]);
      *(uint4*)&WoF[w][dtt][1][lane * 16] = make_uint4(lw2[0], lw2[1], lw2[2], lw2[3]);
    }
    __syncthreads();

#pragma unroll
    for (int kl = 0; kl < 4; ++kl) {
      float v[8];
      const float4 a = *(const float4*)(brow + (chunk * 4 + kl) * 16 + lhi * 8);
      const float4 b2 = *(const float4*)(brow + (chunk * 4 + kl) * 16 + lhi * 8 + 4);
      v[0] = a.x; v[1] = a.y; v[2] = a.z; v[3] = a.w;
      v[4] = b2.x; v[5] = b2.y; v[6] = b2.z; v[7] = b2.w;
      unsigned bhw[4], blw[4];
      split8(v, bhw, blw);
      U4B8 bh2, bl2;
      bh2.u = make_uint4(bhw[0], bhw[1], bhw[2], bhw[3]);
      bl2.u = make_uint4(blw[0], blw[1], blw[2], blw[3]);
      U4B8 ah, al;
      ah.u = *(const uint4*)&WoF[kl][dt][0][lane * 16];
      al.u = *(const uint4*)&WoF[kl][dt][1][lane * 16];
      __builtin_amdgcn_s_setprio(1);
      acc = __builtin_amdgcn_mfma_f32_32x32x16_bf16(ah.v, bh2.v, acc, 0, 0, 0);
      acc = __builtin_amdgcn_mfma_f32_32x32x16_bf16(al.v, bh2.v, acc, 0, 0, 0);
      acc = __builtin_amdgcn_mfma_f32_32x32x16_bf16(ah.v, bl2.v, acc, 0, 0, 0);
      __builtin_amdgcn_s_setprio(0);
    }
  }

  __syncthreads();
#pragma unroll
  for (int r = 0; r < 16; ++r) {
    const int d = dt * 32 + (r & 3) + 8 * (r >> 2) + 4 * lhi;
    Os[(rt * 32 + lrow) * 68 + d] = acc[r];
  }
  __syncthreads();

#pragma unroll
  for (int jj = 0; jj < 4; ++jj) {
    const int i = tid + 256 * jj;
    const int r = i >> 4, c4 = (i & 15) * 4;
    const float4 vv = *(const float4*)&Os[r * 68 + c4];
    *(float4*)&out[(size_t)(Rblk + r) * 64 + c4] = vv;
  }

#pragma unroll
  for (int gi = 0; gi < 2; ++gi) {
    const int g = w * 2 + gi;
    float mean = 0.f;
#pragma unroll
    for (int m = 0; m < 8; ++m) mean += Os[(g * 8 + m) * 68 + lane];
    mean *= 0.125f;
    float dsel = 0.f;
#pragma unroll
    for (int mw = 0; mw < 8; ++mw) {
      float part = mean * Ww[mw * 64 + lane];
      part += __shfl_xor(part, 1);
      part += __shfl_xor(part, 2);
      part += __shfl_xor(part, 4);
      part += __shfl_xor(part, 8);
      part += __shfl_xor(part, 16);
      part += __shfl_xor(part, 32);
      if (lane == mw) dsel = part;
    }
    if (lane < 8) {
      const int idx = Rblk + g * 8 + lane;
      out[1048576 + idx] = qlw[idx] + dsel;
    }
  }
}

// ---------------------------------------------------------------------------
extern "C" void kernel_launch(void* const* d_in, const int* in_sizes, int n_in,
                              void* d_out, int out_size, void* d_ws, size_t ws_size,
                              hipStream_t stream)
{
  const float* q_atoms = (const float*)d_in[0];
  const float* q_logw  = (const float*)d_in[1];
  const float* k_atoms = (const float*)d_in[2];
  const float* k_logw  = (const float*)d_in[3];
  const float* v_atoms = (const float*)d_in[4];
  const float* cosT  = (const float*)d_in[6];
  const float* sinT  = (const float*)d_in[7];
  const float* Wq    = (const float*)d_in[8];
  const float* Wk    = (const float*)d_in[9];
  const float* Wv    = (const float*)d_in[10];
  const float* Wo    = (const float*)d_in[11];
  const float* Ww    = (const float*)d_in[12];
  const float* logbw = (const float*)d_in[13];
  const float* rffb  = (const float*)d_in[14];
  float* out = (float*)d_out;

  char* wsb = (char*)d_ws;
  char* qrh = wsb;
  char* krh = wsb + (8u << 20);
  char* vthi = wsb + (16u << 20);
  float* ao = (float*)(wsb + (48u << 20));

  const dim3 blk(256);
  k_proj_rff<<<dim3(16, 8, 4), blk, 0, stream>>>(q_atoms, q_logw, k_atoms, k_logw,
                                                 Wq, Wk, rffb, logbw, cosT, sinT,
                                                 qrh, krh);
  k_proj_v  <<<dim3(16, 8, 2), blk, 0, stream>>>(v_atoms, Wv, vthi);
  k_flash   <<<dim3(512), blk, 0, stream>>>((const unsigned short*)qrh,
                                            krh, vthi, ao);
  k_out     <<<dim3(256), blk, 0, stream>>>(ao, Wo, Ww, q_logw, out);
}